// Round 8
// baseline (519.770 us; speedup 1.0000x reference)
//
#include <hip/hip_runtime.h>
#include <hip/hip_bf16.h>

#define N_NODES 100000
#define N_EDGES 1600000
#define NGRAPH 64
#define F_IN 16
#define LATENT 128
#define STEPS 3
#define OUTG 10
#define LN_EPS 1e-6f

// graph-build partition params
#define NBLK_P 256
#define CHUNK (N_EDGES / NBLK_P)  // 6250
#define NBUCK 98                  // ceil(100000/1024)
#define RPB 1024
#define OFFN (NBUCK * NBLK_P)     // 25088

typedef __attribute__((ext_vector_type(8))) short short8;
typedef __attribute__((ext_vector_type(4))) float f32x4;
typedef __attribute__((ext_vector_type(4))) unsigned int u32x4;

// ---- ws layout (float indices) ----
#define WS_FLAG 0
#define WS_GSUM 16
#define WS_GCNT (WS_GSUM + NGRAPH * LATENT)
#define WS_INVS (WS_GCNT + 64)
#define WS_INVR (WS_INVS + N_NODES)
#define WS_NODES (WS_INVR + N_NODES)
#define WS_EW (WS_NODES + N_NODES * F_IN)
#define WS_EB (WS_EW + F_IN * LATENT)
#define WS_MW (WS_EB + LATENT)
#define WS_MB (WS_MW + STEPS * 2 * LATENT * LATENT)
#define WS_LNS (WS_MB + STEPS * 2 * LATENT)
#define WS_LNB (WS_LNS + STEPS * LATENT)
#define WS_DW (WS_LNB + STEPS * LATENT)
#define WS_DB (WS_DW + LATENT * OUTG)
#define WS_WF (WS_DB + 16)
#define WS_H (WS_WF + 49152)
#define WS_HB (WS_H + (size_t)N_NODES * LATENT)
#define WS_T1 (WS_HB + (size_t)N_NODES * 64)   // part (int2) during prep only
#define WS_MBUF (WS_T1 + (size_t)N_NODES * 64)
#define WS_INT (WS_MBUF + (size_t)N_NODES * 64)
// ints (offsets within int region)
#define WI_ROWPTR 0
#define WI_CNTS (WI_ROWPTR + 100016)
#define WI_OFFC (WI_CNTS + 100016)
#define WI_OFF (WI_OFFC + 25120)
#define WI_CSR 400064
#define WI_END (WI_CSR + N_EDGES)
#define WS_REQ_BYTES (((size_t)WS_INT + WI_END) * 4)

// cvt_all segment offsets
#define CV0 0
#define CV1 1600000
#define CV2 1602048
#define CV3 1602176
#define CV4 1700480
#define CV5 1701248
#define CV6 1701632
#define CV7 1702016
#define CV8 1703296
#define CVT_TOTAL 1703306

__device__ __forceinline__ float bf2f(unsigned short u) {
    unsigned int i = ((unsigned int)u) << 16;
    float f;
    __builtin_memcpy(&f, &i, 4);
    return f;
}
__device__ __forceinline__ unsigned short f2bfbits(float f) {
    __hip_bfloat16 b = __float2bfloat16(f);
    unsigned short u;
    __builtin_memcpy(&u, &b, 2);
    return u;
}
__device__ __forceinline__ float lof(unsigned int u) {
    unsigned int v = u << 16;
    float f;
    __builtin_memcpy(&f, &v, 4);
    return f;
}
__device__ __forceinline__ float hif(unsigned int u) {
    unsigned int v = u & 0xffff0000u;
    float f;
    __builtin_memcpy(&f, &v, 4);
    return f;
}
__device__ __forceinline__ void acc8_fma(float* acc, u32x4 v, float m) {
    acc[0] = fmaf(lof(v.x), m, acc[0]);
    acc[1] = fmaf(hif(v.x), m, acc[1]);
    acc[2] = fmaf(lof(v.y), m, acc[2]);
    acc[3] = fmaf(hif(v.y), m, acc[3]);
    acc[4] = fmaf(lof(v.z), m, acc[4]);
    acc[5] = fmaf(hif(v.z), m, acc[5]);
    acc[6] = fmaf(lof(v.w), m, acc[6]);
    acc[7] = fmaf(hif(v.w), m, acc[7]);
}

// ---------------- dtype detect ----------------
__global__ void detect_kernel(const unsigned short* __restrict__ lns_raw, int* __restrict__ flag) {
    if (threadIdx.x == 0) flag[0] = (lns_raw[0] == 0) ? 1 : 0;
}

// ---------------- fused conversion of all float inputs ----------------
__global__ void __launch_bounds__(256) cvt_all_kernel(
    const void* s0, const void* s1, const void* s2, const void* s3, const void* s4,
    const void* s5, const void* s6, const void* s7, const void* s8,
    float* d0, float* d1, float* d2, float* d3, float* d4,
    float* d5, float* d6, float* d7, float* d8, const int* __restrict__ flag) {
    int i = blockIdx.x * 256 + threadIdx.x;
    if (i >= CVT_TOTAL) return;
    const void* src;
    float* dst;
    int j;
    if (i < CV1) { src = s0; dst = d0; j = i - CV0; }
    else if (i < CV2) { src = s1; dst = d1; j = i - CV1; }
    else if (i < CV3) { src = s2; dst = d2; j = i - CV2; }
    else if (i < CV4) { src = s3; dst = d3; j = i - CV3; }
    else if (i < CV5) { src = s4; dst = d4; j = i - CV4; }
    else if (i < CV6) { src = s5; dst = d5; j = i - CV5; }
    else if (i < CV7) { src = s6; dst = d6; j = i - CV6; }
    else if (i < CV8) { src = s7; dst = d7; j = i - CV7; }
    else { src = s8; dst = d8; j = i - CV8; }
    if (flag[0]) dst[j] = ((const float*)src)[j];
    else dst[j] = bf2f(((const unsigned short*)src)[j]);
}

// ------- Wf: fragment-layout bf16 weights -------
__global__ void __launch_bounds__(256) wfgen_kernel(const float* __restrict__ mW,
                                                    unsigned short* __restrict__ Wf) {
    int tid = blockIdx.x * 256 + threadIdx.x;
    if (tid >= 6 * 2048) return;
    int L = tid >> 11;
    int rem = tid & 2047;
    int ct = rem >> 8;
    int kt = (rem >> 6) & 3;
    int lane = rem & 63;
    const float* Ws = mW + L * 16384;
    int col = ct * 16 + (lane & 15);
    int k0 = kt * 32 + ((lane >> 4) << 3);
    short8 v;
#pragma unroll
    for (int i = 0; i < 8; i++) v[i] = (short)f2bfbits(Ws[(k0 + i) * 128 + col]);
    *(short8*)(Wf + (size_t)tid * 8) = v;
}

// ---------------- phase A ----------------
__global__ void __launch_bounds__(256) histA_kernel(const int* __restrict__ snd,
                                                    const int* __restrict__ rcv,
                                                    int* __restrict__ cnts,
                                                    int* __restrict__ offc) {
    __shared__ int lh[NBUCK];
    for (int i = threadIdx.x; i < NBUCK; i += 256) lh[i] = 0;
    __syncthreads();
    int base = blockIdx.x * CHUNK;
    for (int i = threadIdx.x; i < CHUNK; i += 256) {
        int e = base + i;
        atomicAdd(&cnts[snd[e]], 1);
        atomicAdd(&lh[rcv[e] >> 10], 1);
    }
    __syncthreads();
    for (int i = threadIdx.x; i < NBUCK; i += 256) offc[i * NBLK_P + blockIdx.x] = lh[i];
}

__global__ void __launch_bounds__(256) inv_kernel(const int* __restrict__ cnts,
                                                  float* __restrict__ invs) {
    int i = blockIdx.x * 256 + threadIdx.x;
    if (i < N_NODES) invs[i] = rsqrtf((float)cnts[i] + 1.0f);
}

// ---------------- exclusive scan ----------------
__global__ void __launch_bounds__(1024) scan_kernel(const int* __restrict__ src,
                                                    int* __restrict__ dst, int n) {
    __shared__ int wsum[16];
    __shared__ int chunk_total;
    int tid = threadIdx.x;
    int lane = tid & 63, wid = tid >> 6;
    int carry = 0;
    for (int base = 0; base < n; base += 4096) {
        int i0 = base + tid * 4;
        int v0 = (i0 + 0 < n) ? src[i0 + 0] : 0;
        int v1 = (i0 + 1 < n) ? src[i0 + 1] : 0;
        int v2 = (i0 + 2 < n) ? src[i0 + 2] : 0;
        int v3 = (i0 + 3 < n) ? src[i0 + 3] : 0;
        int s = v0 + v1 + v2 + v3;
        int sc = s;
#pragma unroll
        for (int off = 1; off < 64; off <<= 1) {
            int t = __shfl_up(sc, off);
            if (lane >= off) sc += t;
        }
        if (lane == 63) wsum[wid] = sc;
        __syncthreads();
        if (wid == 0) {
            int w = (lane < 16) ? wsum[lane] : 0;
#pragma unroll
            for (int off = 1; off < 16; off <<= 1) {
                int t = __shfl_up(w, off);
                if (lane >= off) w += t;
            }
            if (lane < 16) wsum[lane] = w;
            if (lane == 15) chunk_total = w;
        }
        __syncthreads();
        int waveoff = (wid == 0) ? 0 : wsum[wid - 1];
        int p0 = carry + waveoff + (sc - s);
        int p1 = p0 + v0, p2 = p1 + v1, p3 = p2 + v2;
        if (i0 + 0 < n) dst[i0 + 0] = p0;
        if (i0 + 1 < n) dst[i0 + 1] = p1;
        if (i0 + 2 < n) dst[i0 + 2] = p2;
        if (i0 + 3 < n) dst[i0 + 3] = p3;
        carry += chunk_total;
        __syncthreads();
    }
    if (tid == 0) dst[n] = carry;
}

// ---------------- phase C ----------------
__global__ void __launch_bounds__(256) partC_kernel(const int* __restrict__ snd,
                                                    const int* __restrict__ rcv,
                                                    const int* __restrict__ off,
                                                    int2* __restrict__ part) {
    __shared__ int lcur[NBUCK];
    for (int i = threadIdx.x; i < NBUCK; i += 256) lcur[i] = off[i * NBLK_P + blockIdx.x];
    __syncthreads();
    int base = blockIdx.x * CHUNK;
    for (int i = threadIdx.x; i < CHUNK; i += 256) {
        int e = base + i;
        int r = rcv[e];
        int pos = atomicAdd(&lcur[r >> 10], 1);
        part[pos] = make_int2(snd[e], r);
    }
}

// ---------------- phase D ----------------
__global__ void __launch_bounds__(1024) buildD_kernel(const int2* __restrict__ part,
                                                      const int* __restrict__ off,
                                                      int* __restrict__ rowptr,
                                                      float* __restrict__ invr,
                                                      int* __restrict__ csr) {
    __shared__ int lcnt[RPB];
    __shared__ int lscan[RPB];
    __shared__ int ltmp[RPB];
    int b = blockIdx.x;
    int tid = threadIdx.x;
    int beg = off[b * NBLK_P];
    int end = off[(b + 1) * NBLK_P];
    int rbase = b * RPB;
    lcnt[tid] = 0;
    __syncthreads();
    for (int i = beg + tid; i < end; i += 1024) atomicAdd(&lcnt[part[i].y - rbase], 1);
    __syncthreads();
    lscan[tid] = lcnt[tid];
    __syncthreads();
    int* sp = lscan;
    int* dp = ltmp;
    for (int st = 1; st < RPB; st <<= 1) {
        dp[tid] = sp[tid] + ((tid >= st) ? sp[tid - st] : 0);
        __syncthreads();
        int* t = sp; sp = dp; dp = t;
    }
    {
        int c = lcnt[tid];
        int cur = beg + sp[tid] - c;
        int gr = rbase + tid;
        if (gr < N_NODES) {
            rowptr[gr] = cur;
            invr[gr] = rsqrtf((float)c + 1.0f);
        }
        lcnt[tid] = cur;
    }
    __syncthreads();
    for (int i = beg + tid; i < end; i += 1024) {
        int2 e = part[i];
        int pos = atomicAdd(&lcnt[e.y - rbase], 1);
        csr[pos] = e.x;
    }
    if (b == NBUCK - 1 && tid == 0) rowptr[N_NODES] = N_EDGES;
}

// ---------------- embed ----------------
__global__ void __launch_bounds__(256) embed_kernel(const float* __restrict__ nodes,
                                                    const float* __restrict__ eW,
                                                    const float* __restrict__ eb,
                                                    float* __restrict__ h,
                                                    unsigned short* __restrict__ hb) {
    __shared__ float xs[16][F_IN];
    int row0 = blockIdx.x * 16;
    int t = threadIdx.x;
    {
        int r = t >> 4, c = t & 15;
        xs[r][c] = nodes[(row0 + r) * F_IN + c];
    }
    __syncthreads();
    int col = t & 127;
    int rh = t >> 7;
    float acc[8];
    float bb = eb[col];
#pragma unroll
    for (int j = 0; j < 8; j++) acc[j] = bb;
#pragma unroll
    for (int k = 0; k < F_IN; k++) {
        float w = eW[k * LATENT + col];
#pragma unroll
        for (int j = 0; j < 8; j++) acc[j] += xs[rh * 8 + j][k] * w;
    }
    int rbase = row0 + rh * 8;
#pragma unroll
    for (int j = 0; j < 8; j++) {
        h[(size_t)(rbase + j) * LATENT + col] = acc[j];
        hb[(size_t)(rbase + j) * LATENT + col] = f2bfbits(acc[j]);
    }
}

// ------- fused 2-layer MLP -------
#define LPAD 136
__global__ void __launch_bounds__(256) fused_mlp_kernel(const unsigned short* __restrict__ xb,
                                                        const unsigned short* __restrict__ Wf0,
                                                        const float* __restrict__ b0,
                                                        const unsigned short* __restrict__ Wf1,
                                                        const float* __restrict__ b1,
                                                        unsigned short* __restrict__ yb,
                                                        const float* __restrict__ scale) {
    __shared__ unsigned short ls[4][16][LPAD];
    int lane = threadIdx.x & 63;
    int wid = threadIdx.x >> 6;
    int rows0 = blockIdx.x * 64 + wid * 16;
    int l15 = lane & 15;
    int l4 = lane >> 4;

    f32x4 acc[8];
#pragma unroll
    for (int ct = 0; ct < 8; ct++) {
        float bb = b0[ct * 16 + l15];
        acc[ct] = (f32x4){bb, bb, bb, bb};
    }
    {
        int arow_c = min(rows0 + l15, N_NODES - 1);
        const short8* xrow = (const short8*)(xb + (size_t)arow_c * LATENT);
#pragma unroll
        for (int kt = 0; kt < 4; kt++) {
            short8 a = xrow[kt * 4 + l4];
#pragma unroll
            for (int ct = 0; ct < 8; ct++) {
                short8 bf = *(const short8*)(Wf0 + (size_t)(((ct * 4 + kt) * 64 + lane)) * 8);
                acc[ct] = __builtin_amdgcn_mfma_f32_16x16x32_bf16(a, bf, acc[ct], 0, 0, 0);
            }
        }
    }
    {
        int lrow = l4 << 2;
#pragma unroll
        for (int ct = 0; ct < 8; ct++)
#pragma unroll
            for (int j = 0; j < 4; j++)
                ls[wid][lrow + j][ct * 16 + l15] = f2bfbits(fmaxf(acc[ct][j], 0.0f));
    }
    __syncthreads();

#pragma unroll
    for (int ct = 0; ct < 8; ct++) {
        float bb = b1[ct * 16 + l15];
        acc[ct] = (f32x4){bb, bb, bb, bb};
    }
#pragma unroll
    for (int kt = 0; kt < 4; kt++) {
        short8 a = *(const short8*)&ls[wid][l15][kt * 32 + (l4 << 3)];
#pragma unroll
        for (int ct = 0; ct < 8; ct++) {
            short8 bf = *(const short8*)(Wf1 + (size_t)(((ct * 4 + kt) * 64 + lane)) * 8);
            acc[ct] = __builtin_amdgcn_mfma_f32_16x16x32_bf16(a, bf, acc[ct], 0, 0, 0);
        }
    }
    __syncthreads();
    {
        int lrow = l4 << 2;
#pragma unroll
        for (int j = 0; j < 4; j++) {
            int r = min(rows0 + lrow + j, N_NODES - 1);
            float sc = scale[r];
#pragma unroll
            for (int ct = 0; ct < 8; ct++)
                ls[wid][lrow + j][ct * 16 + l15] = f2bfbits(fmaxf(acc[ct][j], 0.0f) * sc);
        }
    }
    __syncthreads();
#pragma unroll
    for (int p = 0; p < 4; p++) {
        int row = p * 4 + l4;
        short8 v = *(const short8*)&ls[wid][row][l15 * 8];
        int r = rows0 + row;
        if (r < N_NODES) *(short8*)(yb + (size_t)r * LATENT + l15 * 8) = v;
    }
}

// ------- gather v2: 4 edge-rows per load instr (16 lanes x 16B each) + skip + LN -------
__global__ void __launch_bounds__(256) gather_ln_kernel(const int* __restrict__ rowptr,
                                                        const int* __restrict__ csr,
                                                        const u32x4* __restrict__ mb4,
                                                        const float* __restrict__ invr,
                                                        float* __restrict__ h,
                                                        u32x4* __restrict__ hb4,
                                                        const float* __restrict__ lnsc,
                                                        const float* __restrict__ lnbi,
                                                        int write_hb) {
    int node = (blockIdx.x * 256 + threadIdx.x) >> 6;
    int lane = threadIdx.x & 63;
    if (node >= N_NODES) return;
    int grp = lane >> 4;
    int c16 = lane & 15;  // which 16B chunk of the 256B row

    int beg = rowptr[node];
    int end = rowptr[node + 1];

    // prefetch skip-connection h chunk (float cols c16*8 .. +7)
    float* hrow = h + (size_t)node * LATENT + c16 * 8;
    f32x4 h0 = *(const f32x4*)hrow;
    f32x4 h1 = *(const f32x4*)(hrow + 4);

    float acc[8];
#pragma unroll
    for (int k = 0; k < 8; k++) acc[k] = 0.0f;
    // self edge (m already * inv_s): only group 0 contributes
    acc8_fma(acc, mb4[(size_t)node * 16 + c16], (grp == 0) ? 1.0f : 0.0f);

    for (int base = beg; base < end; base += 64) {
        int rem = end - base;
        int eidx = (lane < rem) ? __builtin_nontemporal_load(csr + base + lane) : 0;
        int lim = min(rem, 64);
        int nit = (lim + 3) >> 2;
#pragma unroll 4
        for (int it = 0; it < nit; ++it) {
            int j = (it << 2) + grp;
            int s = __shfl(eidx, j);
            float m = (j < lim) ? 1.0f : 0.0f;
            u32x4 v = mb4[(size_t)s * 16 + c16];
            acc8_fma(acc, v, m);
        }
    }

    // reduce partial sums across the 4 groups (lanes differ in bits 4,5)
#pragma unroll
    for (int k = 0; k < 8; k++) {
        acc[k] += __shfl_xor(acc[k], 16);
        acc[k] += __shfl_xor(acc[k], 32);
    }

    float ir = invr[node];
    float t[8];
    t[0] = acc[0] * ir + h0.x;
    t[1] = acc[1] * ir + h0.y;
    t[2] = acc[2] * ir + h0.z;
    t[3] = acc[3] * ir + h0.w;
    t[4] = acc[4] * ir + h1.x;
    t[5] = acc[5] * ir + h1.y;
    t[6] = acc[6] * ir + h1.z;
    t[7] = acc[7] * ir + h1.w;

    float s = 0.0f, s2 = 0.0f;
#pragma unroll
    for (int k = 0; k < 8; k++) {
        s += t[k];
        s2 += t[k] * t[k];
    }
#pragma unroll
    for (int o = 1; o < 16; o <<= 1) {
        s += __shfl_xor(s, o);
        s2 += __shfl_xor(s2, o);
    }
    float mu = s * (1.0f / 128.0f);
    float var = s2 * (1.0f / 128.0f) - mu * mu;
    float rstd = rsqrtf(var + LN_EPS);

    const float* scp = lnsc + c16 * 8;
    const float* bip = lnbi + c16 * 8;
    f32x4 sc0 = *(const f32x4*)scp;
    f32x4 sc1 = *(const f32x4*)(scp + 4);
    f32x4 bi0 = *(const f32x4*)bip;
    f32x4 bi1 = *(const f32x4*)(bip + 4);
    float o0 = (t[0] - mu) * rstd * sc0.x + bi0.x;
    float o1 = (t[1] - mu) * rstd * sc0.y + bi0.y;
    float o2 = (t[2] - mu) * rstd * sc0.z + bi0.z;
    float o3 = (t[3] - mu) * rstd * sc0.w + bi0.w;
    float o4 = (t[4] - mu) * rstd * sc1.x + bi1.x;
    float o5 = (t[5] - mu) * rstd * sc1.y + bi1.y;
    float o6 = (t[6] - mu) * rstd * sc1.z + bi1.z;
    float o7 = (t[7] - mu) * rstd * sc1.w + bi1.w;

    if (grp == 0) {  // lanes 0..15 store the row
        f32x4 w0 = {o0, o1, o2, o3};
        f32x4 w1 = {o4, o5, o6, o7};
        __builtin_nontemporal_store(w0, (f32x4*)hrow);
        __builtin_nontemporal_store(w1, (f32x4*)(hrow + 4));
        if (write_hb) {
            u32x4 pk;
            pk.x = (unsigned int)f2bfbits(o0) | ((unsigned int)f2bfbits(o1) << 16);
            pk.y = (unsigned int)f2bfbits(o2) | ((unsigned int)f2bfbits(o3) << 16);
            pk.z = (unsigned int)f2bfbits(o4) | ((unsigned int)f2bfbits(o5) << 16);
            pk.w = (unsigned int)f2bfbits(o6) | ((unsigned int)f2bfbits(o7) << 16);
            __builtin_nontemporal_store(pk, hb4 + (size_t)node * 16 + c16);
        }
    }
}

// ---------------- pooling ----------------
__global__ void __launch_bounds__(128) pool_kernel(const float* __restrict__ h,
                                                   const int* __restrict__ gid,
                                                   float* __restrict__ gsum,
                                                   float* __restrict__ gcnt) {
    int col = threadIdx.x;
    int n0 = blockIdx.x * 64;
    int nend = min(n0 + 64, N_NODES);
    if (n0 >= N_NODES) return;
    int cur = gid[n0];
    float acc = 0.0f, cacc = 0.0f;
    for (int n = n0; n < nend; ++n) {
        int g = gid[n];
        if (g != cur) {
            atomicAdd(&gsum[cur * LATENT + col], acc);
            if (col == 0) atomicAdd(&gcnt[cur], cacc);
            acc = 0.0f;
            cacc = 0.0f;
            cur = g;
        }
        acc += h[(size_t)n * LATENT + col];
        cacc += 1.0f;
    }
    atomicAdd(&gsum[cur * LATENT + col], acc);
    if (col == 0) atomicAdd(&gcnt[cur], cacc);
}

// ---------------- decoder ----------------
__global__ void __launch_bounds__(640) dec_kernel(const float* __restrict__ gsum,
                                                  const float* __restrict__ gcnt,
                                                  const float* __restrict__ dW,
                                                  const float* __restrict__ db,
                                                  void* __restrict__ out,
                                                  const int* __restrict__ flag) {
    int t = threadIdx.x;
    if (t >= NGRAPH * OUTG) return;
    int g = t / OUTG, o = t % OUTG;
    float inv = 1.0f / fmaxf(gcnt[g], 1.0f);
    float acc = 0.0f;
    for (int k = 0; k < LATENT; k++) acc += gsum[g * LATENT + k] * dW[k * OUTG + o];
    acc = acc * inv + db[o];
    if (flag[0]) ((float*)out)[t] = acc;
    else ((__hip_bfloat16*)out)[t] = __float2bfloat16(acc);
}

__global__ void diag_kernel(float* out, float val) {
    if (threadIdx.x == 0) out[0] = val;
}

extern "C" void kernel_launch(void* const* d_in, const int* in_sizes, int n_in,
                              void* d_out, int out_size, void* d_ws, size_t ws_size,
                              hipStream_t stream) {
    (void)in_sizes; (void)n_in; (void)out_size;
    const int* snd = (const int*)d_in[1];
    const int* rcv = (const int*)d_in[2];
    const int* gid = (const int*)d_in[3];

    if (ws_size < (size_t)WS_REQ_BYTES) {
        diag_kernel<<<1, 64, 0, stream>>>((float*)d_out, 1.0e6f + (float)(ws_size >> 20));
        return;
    }

    float* ws = (float*)d_ws;
    int* flag = (int*)ws;
    float* gsum = ws + WS_GSUM;
    float* invs = ws + WS_INVS;
    float* invr = ws + WS_INVR;
    float* nodesf = ws + WS_NODES;
    float* eW = ws + WS_EW;
    float* eb = ws + WS_EB;
    float* mW = ws + WS_MW;
    float* mb = ws + WS_MB;
    float* lns = ws + WS_LNS;
    float* lnb = ws + WS_LNB;
    float* dW = ws + WS_DW;
    float* db = ws + WS_DB;
    unsigned short* Wf = (unsigned short*)(ws + WS_WF);
    float* h = ws + WS_H;
    unsigned short* hb = (unsigned short*)(ws + WS_HB);
    unsigned short* mbuf = (unsigned short*)(ws + WS_MBUF);
    int2* part = (int2*)(ws + WS_T1);  // prep-time alias
    int* ibase = (int*)(ws + WS_INT);
    int* rowptr = ibase + WI_ROWPTR;
    int* cnts = ibase + WI_CNTS;
    int* offc = ibase + WI_OFFC;
    int* off = ibase + WI_OFF;
    int* csr = ibase + WI_CSR;

    detect_kernel<<<1, 64, 0, stream>>>((const unsigned short*)d_in[8], flag);

    cvt_all_kernel<<<(CVT_TOTAL + 255) / 256, 256, 0, stream>>>(
        d_in[0], d_in[4], d_in[5], d_in[6], d_in[7], d_in[8], d_in[9], d_in[10], d_in[11],
        nodesf, eW, eb, mW, mb, lns, lnb, dW, db, flag);

    wfgen_kernel<<<48, 256, 0, stream>>>(mW, Wf);

    hipMemsetAsync(cnts, 0, 100016 * sizeof(int), stream);
    hipMemsetAsync(gsum, 0, (NGRAPH * LATENT + 64) * sizeof(float), stream);

    histA_kernel<<<NBLK_P, 256, 0, stream>>>(snd, rcv, cnts, offc);
    scan_kernel<<<1, 1024, 0, stream>>>(offc, off, OFFN);
    inv_kernel<<<(N_NODES + 255) / 256, 256, 0, stream>>>(cnts, invs);
    partC_kernel<<<NBLK_P, 256, 0, stream>>>(snd, rcv, off, part);
    buildD_kernel<<<NBUCK, 1024, 0, stream>>>(part, off, rowptr, invr, csr);

    embed_kernel<<<N_NODES / 16, 256, 0, stream>>>(nodesf, eW, eb, h, hb);

    for (int step = 0; step < STEPS; ++step) {
        const unsigned short* Wf0 = Wf + (size_t)(step * 2 + 0) * 16384;
        const unsigned short* Wf1 = Wf + (size_t)(step * 2 + 1) * 16384;
        const float* b0 = mb + (step * 2 + 0) * LATENT;
        const float* b1 = mb + (step * 2 + 1) * LATENT;
        fused_mlp_kernel<<<(N_NODES + 63) / 64, 256, 0, stream>>>(hb, Wf0, b0, Wf1, b1, mbuf, invs);
        gather_ln_kernel<<<(N_NODES + 3) / 4, 256, 0, stream>>>(rowptr, csr, (const u32x4*)mbuf,
                                                                invr, h, (u32x4*)hb,
                                                                lns + step * LATENT,
                                                                lnb + step * LATENT,
                                                                (step < STEPS - 1) ? 1 : 0);
    }

    pool_kernel<<<(N_NODES + 63) / 64, 128, 0, stream>>>(h, gid, gsum, ws + WS_GCNT);
    dec_kernel<<<1, 640, 0, stream>>>(gsum, ws + WS_GCNT, dW, db, d_out, flag);
}

// Round 9
// 494.692 us; speedup vs baseline: 1.0507x; 1.0507x over previous
//
#include <hip/hip_runtime.h>
#include <hip/hip_bf16.h>

#define N_NODES 100000
#define N_EDGES 1600000
#define NGRAPH 64
#define F_IN 16
#define LATENT 128
#define STEPS 3
#define OUTG 10
#define LN_EPS 1e-6f

// graph-build partition params
#define NBLK_P 256
#define CHUNK (N_EDGES / NBLK_P)  // 6250
#define NBUCK 98                  // ceil(100000/1024)
#define RPB 1024
#define OFFN (NBUCK * NBLK_P)     // 25088

typedef __attribute__((ext_vector_type(8))) short short8;
typedef __attribute__((ext_vector_type(4))) float f32x4;

// ---- ws layout (float indices) ----
#define WS_GSUM 16
#define WS_GCNT (WS_GSUM + NGRAPH * LATENT)
#define WS_INVS (WS_GCNT + 64)
#define WS_INVR (WS_INVS + N_NODES)
#define WS_MB (WS_INVR + N_NODES)
#define WS_LNS (WS_MB + STEPS * 2 * LATENT)
#define WS_LNB (WS_LNS + STEPS * LATENT)
#define WS_DW (WS_LNB + STEPS * LATENT)
#define WS_DB (WS_DW + LATENT * OUTG)
#define WS_WF (WS_DB + 16)                           // 6*16384 bf16 = 49152 floats
#define WS_PART (WS_WF + 49152)                      // u32 x N_EDGES
#define WS_HB (WS_PART + N_EDGES)                    // bf16 h, N*64 floats
#define WS_MBUF (WS_HB + (size_t)N_NODES * 64)
#define WS_INT (WS_MBUF + (size_t)N_NODES * 64)
// ints (offsets within int region)
#define WI_ROWPTR 0
#define WI_CNTS (WI_ROWPTR + 100016)
#define WI_OFFC (WI_CNTS + 100016)
#define WI_OFF (WI_OFFC + 25120)
#define WI_CSR 400064
#define WI_END (WI_CSR + N_EDGES)
#define WS_REQ_BYTES (((size_t)WS_INT + WI_END) * 4)

// prologue block ranges
#define PRO_EMBED 6250
#define PRO_WF (PRO_EMBED + 48)
#define PRO_CVT_N 2826
#define PRO_GRID (PRO_WF + 12)

__device__ __forceinline__ float bf2f(unsigned short u) {
    unsigned int i = ((unsigned int)u) << 16;
    float f;
    __builtin_memcpy(&f, &i, 4);
    return f;
}
__device__ __forceinline__ unsigned short f2bfbits(float f) {
    __hip_bfloat16 b = __float2bfloat16(f);
    unsigned short u;
    __builtin_memcpy(&u, &b, 2);
    return u;
}
__device__ __forceinline__ float lof(unsigned int u) {
    unsigned int v = u << 16;
    float f;
    __builtin_memcpy(&f, &v, 4);
    return f;
}
__device__ __forceinline__ float hif(unsigned int u) {
    unsigned int v = u & 0xffff0000u;
    float f;
    __builtin_memcpy(&f, &v, 4);
    return f;
}
__device__ __forceinline__ float rawf(const void* p, size_t i, bool f32m) {
    return f32m ? ((const float*)p)[i] : bf2f(((const unsigned short*)p)[i]);
}

// ------- prologue: embed (raw inputs) | wfgen (raw mW) | cvt small params -------
__global__ void __launch_bounds__(256) prologue_kernel(
    const void* __restrict__ nodes_raw, const void* __restrict__ eW_raw,
    const void* __restrict__ eb_raw, const void* __restrict__ mW_raw,
    const void* __restrict__ mb_raw, const void* __restrict__ lns_raw,
    const void* __restrict__ lnb_raw, const void* __restrict__ dW_raw,
    const void* __restrict__ db_raw,
    unsigned short* __restrict__ hb, unsigned short* __restrict__ Wf,
    float* __restrict__ mb, float* __restrict__ lns, float* __restrict__ lnb,
    float* __restrict__ dW, float* __restrict__ db) {
    __shared__ float xs[16][F_IN];
    bool f32m = (((const unsigned short*)lns_raw)[0] == 0);
    int bid = blockIdx.x;
    int t = threadIdx.x;
    if (bid < PRO_EMBED) {
        // ---- embed: hb = bf16(nodes @ eW + eb) ----
        int row0 = bid * 16;
        {
            int r = t >> 4, c = t & 15;
            xs[r][c] = rawf(nodes_raw, (size_t)(row0 + r) * F_IN + c, f32m);
        }
        __syncthreads();
        int col = t & 127;
        int rh = t >> 7;
        float acc[8];
        float bb = rawf(eb_raw, col, f32m);
#pragma unroll
        for (int j = 0; j < 8; j++) acc[j] = bb;
#pragma unroll
        for (int k = 0; k < F_IN; k++) {
            float w = rawf(eW_raw, k * LATENT + col, f32m);
#pragma unroll
            for (int j = 0; j < 8; j++) acc[j] += xs[rh * 8 + j][k] * w;
        }
        int rbase = row0 + rh * 8;
#pragma unroll
        for (int j = 0; j < 8; j++)
            hb[(size_t)(rbase + j) * LATENT + col] = f2bfbits(acc[j]);
    } else if (bid < PRO_WF) {
        // ---- Wf: fragment-layout bf16 weights from raw mW ----
        int tid = (bid - PRO_EMBED) * 256 + t;
        int L = tid >> 11;
        int rem = tid & 2047;
        int ct = rem >> 8;
        int kt = (rem >> 6) & 3;
        int lane = rem & 63;
        size_t Wsoff = (size_t)L * 16384;
        int col = ct * 16 + (lane & 15);
        int k0 = kt * 32 + ((lane >> 4) << 3);
        short8 v;
#pragma unroll
        for (int i = 0; i < 8; i++)
            v[i] = (short)f2bfbits(rawf(mW_raw, Wsoff + (size_t)(k0 + i) * 128 + col, f32m));
        *(short8*)(Wf + (size_t)tid * 8) = v;
    } else {
        // ---- cvt small params to f32: mb(768) lns(384) lnb(384) dW(1280) db(10) ----
        int i = (bid - PRO_WF) * 256 + t;
        if (i >= PRO_CVT_N) return;
        const void* src;
        float* dst;
        int j;
        if (i < 768) { src = mb_raw; dst = mb; j = i; }
        else if (i < 1152) { src = lns_raw; dst = lns; j = i - 768; }
        else if (i < 1536) { src = lnb_raw; dst = lnb; j = i - 1152; }
        else if (i < 2816) { src = dW_raw; dst = dW; j = i - 1536; }
        else { src = db_raw; dst = db; j = i - 2816; }
        dst[j] = rawf(src, j, f32m);
    }
}

// ---------------- phase A: sender-degree atomics + per-block bucket histogram ----------------
__global__ void __launch_bounds__(256) histA_kernel(const int* __restrict__ snd,
                                                    const int* __restrict__ rcv,
                                                    int* __restrict__ cnts,
                                                    int* __restrict__ offc) {
    __shared__ int lh[NBUCK];
    for (int i = threadIdx.x; i < NBUCK; i += 256) lh[i] = 0;
    __syncthreads();
    int base = blockIdx.x * CHUNK;
    for (int i = threadIdx.x; i < CHUNK; i += 256) {
        int e = base + i;
        atomicAdd(&cnts[snd[e]], 1);
        atomicAdd(&lh[rcv[e] >> 10], 1);
    }
    __syncthreads();
    for (int i = threadIdx.x; i < NBUCK; i += 256) offc[i * NBLK_P + blockIdx.x] = lh[i];
}

// ---------------- exclusive scan ----------------
__global__ void __launch_bounds__(1024) scan_kernel(const int* __restrict__ src,
                                                    int* __restrict__ dst, int n) {
    __shared__ int wsum[16];
    __shared__ int chunk_total;
    int tid = threadIdx.x;
    int lane = tid & 63, wid = tid >> 6;
    int carry = 0;
    for (int base = 0; base < n; base += 4096) {
        int i0 = base + tid * 4;
        int v0 = (i0 + 0 < n) ? src[i0 + 0] : 0;
        int v1 = (i0 + 1 < n) ? src[i0 + 1] : 0;
        int v2 = (i0 + 2 < n) ? src[i0 + 2] : 0;
        int v3 = (i0 + 3 < n) ? src[i0 + 3] : 0;
        int s = v0 + v1 + v2 + v3;
        int sc = s;
#pragma unroll
        for (int off = 1; off < 64; off <<= 1) {
            int t = __shfl_up(sc, off);
            if (lane >= off) sc += t;
        }
        if (lane == 63) wsum[wid] = sc;
        __syncthreads();
        if (wid == 0) {
            int w = (lane < 16) ? wsum[lane] : 0;
#pragma unroll
            for (int off = 1; off < 16; off <<= 1) {
                int t = __shfl_up(w, off);
                if (lane >= off) w += t;
            }
            if (lane < 16) wsum[lane] = w;
            if (lane == 15) chunk_total = w;
        }
        __syncthreads();
        int waveoff = (wid == 0) ? 0 : wsum[wid - 1];
        int p0 = carry + waveoff + (sc - s);
        int p1 = p0 + v0, p2 = p1 + v1, p3 = p2 + v2;
        if (i0 + 0 < n) dst[i0 + 0] = p0;
        if (i0 + 1 < n) dst[i0 + 1] = p1;
        if (i0 + 2 < n) dst[i0 + 2] = p2;
        if (i0 + 3 < n) dst[i0 + 3] = p3;
        carry += chunk_total;
        __syncthreads();
    }
    if (tid == 0) dst[n] = carry;
}

// ------- phase C: partition edges into receiver buckets (packed u32) + invs tail -------
__global__ void __launch_bounds__(256) partC_kernel(const int* __restrict__ snd,
                                                    const int* __restrict__ rcv,
                                                    const int* __restrict__ off,
                                                    unsigned int* __restrict__ part,
                                                    const int* __restrict__ cnts,
                                                    float* __restrict__ invs) {
    __shared__ int lcur[NBUCK];
    for (int i = threadIdx.x; i < NBUCK; i += 256) lcur[i] = off[i * NBLK_P + blockIdx.x];
    __syncthreads();
    int base = blockIdx.x * CHUNK;
    for (int i = threadIdx.x; i < CHUNK; i += 256) {
        int e = base + i;
        int r = rcv[e];
        int pos = atomicAdd(&lcur[r >> 10], 1);
        part[pos] = ((unsigned int)snd[e] << 10) | (unsigned int)(r & 1023);
    }
    // fused invs = rsqrt(deg_s + 1)
    for (int i = blockIdx.x * 256 + threadIdx.x; i < N_NODES; i += 256 * NBLK_P)
        invs[i] = rsqrtf((float)cnts[i] + 1.0f);
}

// ---------------- phase D: per-bucket CSR build ----------------
__global__ void __launch_bounds__(1024) buildD_kernel(const unsigned int* __restrict__ part,
                                                      const int* __restrict__ off,
                                                      int* __restrict__ rowptr,
                                                      float* __restrict__ invr,
                                                      int* __restrict__ csr) {
    __shared__ int lcnt[RPB];
    __shared__ int lscan[RPB];
    __shared__ int ltmp[RPB];
    int b = blockIdx.x;
    int tid = threadIdx.x;
    int beg = off[b * NBLK_P];
    int end = off[(b + 1) * NBLK_P];
    lcnt[tid] = 0;
    __syncthreads();
    for (int i = beg + tid; i < end; i += 1024) atomicAdd(&lcnt[part[i] & 1023], 1);
    __syncthreads();
    lscan[tid] = lcnt[tid];
    __syncthreads();
    int* sp = lscan;
    int* dp = ltmp;
    for (int st = 1; st < RPB; st <<= 1) {
        dp[tid] = sp[tid] + ((tid >= st) ? sp[tid - st] : 0);
        __syncthreads();
        int* t = sp; sp = dp; dp = t;
    }
    {
        int c = lcnt[tid];
        int cur = beg + sp[tid] - c;
        int gr = b * RPB + tid;
        if (gr < N_NODES) {
            rowptr[gr] = cur;
            invr[gr] = rsqrtf((float)c + 1.0f);
        }
        lcnt[tid] = cur;
    }
    __syncthreads();
    for (int i = beg + tid; i < end; i += 1024) {
        unsigned int e = part[i];
        int pos = atomicAdd(&lcnt[e & 1023], 1);
        csr[pos] = (int)(e >> 10);
    }
    if (b == NBUCK - 1 && tid == 0) rowptr[N_NODES] = N_EDGES;
}

// ------- fused 2-layer MLP: 512 thr / 8 waves / 128 rows per block -------
#define LPAD 136
__global__ void __launch_bounds__(512) fused_mlp_kernel(const unsigned short* __restrict__ xb,
                                                        const unsigned short* __restrict__ Wf0,
                                                        const float* __restrict__ b0,
                                                        const unsigned short* __restrict__ Wf1,
                                                        const float* __restrict__ b1,
                                                        unsigned short* __restrict__ yb,
                                                        const float* __restrict__ scale) {
    __shared__ unsigned short ls[8][16][LPAD];
    int lane = threadIdx.x & 63;
    int wid = threadIdx.x >> 6;
    int rows0 = blockIdx.x * 128 + wid * 16;
    int l15 = lane & 15;
    int l4 = lane >> 4;

    f32x4 acc[8];
#pragma unroll
    for (int ct = 0; ct < 8; ct++) {
        float bb = b0[ct * 16 + l15];
        acc[ct] = (f32x4){bb, bb, bb, bb};
    }
    {
        int arow_c = min(rows0 + l15, N_NODES - 1);
        const short8* xrow = (const short8*)(xb + (size_t)arow_c * LATENT);
#pragma unroll
        for (int kt = 0; kt < 4; kt++) {
            short8 a = xrow[kt * 4 + l4];
#pragma unroll
            for (int ct = 0; ct < 8; ct++) {
                short8 bf = *(const short8*)(Wf0 + (size_t)(((ct * 4 + kt) * 64 + lane)) * 8);
                acc[ct] = __builtin_amdgcn_mfma_f32_16x16x32_bf16(a, bf, acc[ct], 0, 0, 0);
            }
        }
    }
    {
        int lrow = l4 << 2;
#pragma unroll
        for (int ct = 0; ct < 8; ct++)
#pragma unroll
            for (int j = 0; j < 4; j++)
                ls[wid][lrow + j][ct * 16 + l15] = f2bfbits(fmaxf(acc[ct][j], 0.0f));
    }
    __syncthreads();

#pragma unroll
    for (int ct = 0; ct < 8; ct++) {
        float bb = b1[ct * 16 + l15];
        acc[ct] = (f32x4){bb, bb, bb, bb};
    }
#pragma unroll
    for (int kt = 0; kt < 4; kt++) {
        short8 a = *(const short8*)&ls[wid][l15][kt * 32 + (l4 << 3)];
#pragma unroll
        for (int ct = 0; ct < 8; ct++) {
            short8 bf = *(const short8*)(Wf1 + (size_t)(((ct * 4 + kt) * 64 + lane)) * 8);
            acc[ct] = __builtin_amdgcn_mfma_f32_16x16x32_bf16(a, bf, acc[ct], 0, 0, 0);
        }
    }
    __syncthreads();
    {
        int lrow = l4 << 2;
#pragma unroll
        for (int j = 0; j < 4; j++) {
            int r = min(rows0 + lrow + j, N_NODES - 1);
            float sc = scale[r];
#pragma unroll
            for (int ct = 0; ct < 8; ct++)
                ls[wid][lrow + j][ct * 16 + l15] = f2bfbits(fmaxf(acc[ct][j], 0.0f) * sc);
        }
    }
    __syncthreads();
#pragma unroll
    for (int p = 0; p < 4; p++) {
        int row = p * 4 + l4;
        short8 v = *(const short8*)&ls[wid][row][l15 * 8];
        int r = rows0 + row;
        if (r < N_NODES) *(short8*)(yb + (size_t)r * LATENT + l15 * 8) = v;
    }
}

// ------- gather (CSR) + inv_r + skip + LayerNorm, all-bf16 residual stream -------
__global__ void __launch_bounds__(256) gather_ln_kernel(const int* __restrict__ rowptr,
                                                        const int* __restrict__ csr,
                                                        const unsigned int* __restrict__ mb2,
                                                        const float* __restrict__ invr,
                                                        unsigned int* __restrict__ hb2,
                                                        const float* __restrict__ lnsc,
                                                        const float* __restrict__ lnbi) {
    int node = (blockIdx.x * 256 + threadIdx.x) >> 6;
    int lane = threadIdx.x & 63;
    if (node >= N_NODES) return;
    int beg = rowptr[node];
    int end = rowptr[node + 1];
    unsigned int sv = mb2[(size_t)node * 64 + lane];  // self edge (m already *inv_s)
    float ax = lof(sv);
    float ay = hif(sv);
    for (int base = beg; base < end; base += 64) {
        int cnt = min(64, end - base);
        int idx = (lane < cnt) ? __builtin_nontemporal_load(csr + base + lane) : 0;
        int j = 0;
        for (; j + 3 < cnt; j += 4) {
            int s0 = __shfl(idx, j);
            int s1 = __shfl(idx, j + 1);
            int s2 = __shfl(idx, j + 2);
            int s3 = __shfl(idx, j + 3);
            unsigned int va = mb2[(size_t)s0 * 64 + lane];
            unsigned int vb = mb2[(size_t)s1 * 64 + lane];
            unsigned int vc = mb2[(size_t)s2 * 64 + lane];
            unsigned int vd = mb2[(size_t)s3 * 64 + lane];
            ax += (lof(va) + lof(vb)) + (lof(vc) + lof(vd));
            ay += (hif(va) + hif(vb)) + (hif(vc) + hif(vd));
        }
        for (; j < cnt; ++j) {
            int s0 = __shfl(idx, j);
            unsigned int va = mb2[(size_t)s0 * 64 + lane];
            ax += lof(va);
            ay += hif(va);
        }
    }
    float ir = invr[node];
    unsigned int hu = __builtin_nontemporal_load(hb2 + (size_t)node * 64 + lane);
    float tx = ax * ir + lof(hu);
    float ty = ay * ir + hif(hu);
    float s = tx + ty, s2 = tx * tx + ty * ty;
#pragma unroll
    for (int o = 1; o < 64; o <<= 1) {
        s += __shfl_xor(s, o);
        s2 += __shfl_xor(s2, o);
    }
    float mu = s * (1.0f / 128.0f);
    float var = s2 * (1.0f / 128.0f) - mu * mu;
    float rstd = rsqrtf(var + LN_EPS);
    float ox = (tx - mu) * rstd * lnsc[lane * 2] + lnbi[lane * 2];
    float oy = (ty - mu) * rstd * lnsc[lane * 2 + 1] + lnbi[lane * 2 + 1];
    unsigned int pk = (unsigned int)f2bfbits(ox) | ((unsigned int)f2bfbits(oy) << 16);
    __builtin_nontemporal_store(pk, hb2 + (size_t)node * 64 + lane);
}

// ---------------- pooling: run-length over sorted graph_ids (bf16 h) ----------------
__global__ void __launch_bounds__(128) pool_kernel(const unsigned short* __restrict__ hb,
                                                   const int* __restrict__ gid,
                                                   float* __restrict__ gsum,
                                                   float* __restrict__ gcnt) {
    int col = threadIdx.x;
    int n0 = blockIdx.x * 64;
    int nend = min(n0 + 64, N_NODES);
    if (n0 >= N_NODES) return;
    int cur = gid[n0];
    float acc = 0.0f, cacc = 0.0f;
    for (int n = n0; n < nend; ++n) {
        int g = gid[n];
        if (g != cur) {
            atomicAdd(&gsum[cur * LATENT + col], acc);
            if (col == 0) atomicAdd(&gcnt[cur], cacc);
            acc = 0.0f;
            cacc = 0.0f;
            cur = g;
        }
        acc += bf2f(hb[(size_t)n * LATENT + col]);
        cacc += 1.0f;
    }
    atomicAdd(&gsum[cur * LATENT + col], acc);
    if (col == 0) atomicAdd(&gcnt[cur], cacc);
}

// ---------------- decoder (dual-dtype output, inline flag) ----------------
__global__ void __launch_bounds__(640) dec_kernel(const float* __restrict__ gsum,
                                                  const float* __restrict__ gcnt,
                                                  const float* __restrict__ dW,
                                                  const float* __restrict__ db,
                                                  void* __restrict__ out,
                                                  const unsigned short* __restrict__ lns_raw) {
    int t = threadIdx.x;
    if (t >= NGRAPH * OUTG) return;
    int g = t / OUTG, o = t % OUTG;
    float inv = 1.0f / fmaxf(gcnt[g], 1.0f);
    float acc = 0.0f;
    for (int k = 0; k < LATENT; k++) acc += gsum[g * LATENT + k] * dW[k * OUTG + o];
    acc = acc * inv + db[o];
    if (lns_raw[0] == 0) ((float*)out)[t] = acc;
    else ((__hip_bfloat16*)out)[t] = __float2bfloat16(acc);
}

__global__ void diag_kernel(float* out, float val) {
    if (threadIdx.x == 0) out[0] = val;
}

extern "C" void kernel_launch(void* const* d_in, const int* in_sizes, int n_in,
                              void* d_out, int out_size, void* d_ws, size_t ws_size,
                              hipStream_t stream) {
    (void)in_sizes; (void)n_in; (void)out_size;
    const int* snd = (const int*)d_in[1];
    const int* rcv = (const int*)d_in[2];
    const int* gid = (const int*)d_in[3];

    if (ws_size < (size_t)WS_REQ_BYTES) {
        diag_kernel<<<1, 64, 0, stream>>>((float*)d_out, 1.0e6f + (float)(ws_size >> 20));
        return;
    }

    float* ws = (float*)d_ws;
    float* gsum = ws + WS_GSUM;
    float* invs = ws + WS_INVS;
    float* invr = ws + WS_INVR;
    float* mb = ws + WS_MB;
    float* lns = ws + WS_LNS;
    float* lnb = ws + WS_LNB;
    float* dW = ws + WS_DW;
    float* db = ws + WS_DB;
    unsigned short* Wf = (unsigned short*)(ws + WS_WF);
    unsigned int* part = (unsigned int*)(ws + WS_PART);
    unsigned short* hb = (unsigned short*)(ws + WS_HB);
    unsigned short* mbuf = (unsigned short*)(ws + WS_MBUF);
    int* ibase = (int*)(ws + WS_INT);
    int* rowptr = ibase + WI_ROWPTR;
    int* cnts = ibase + WI_CNTS;
    int* offc = ibase + WI_OFFC;
    int* off = ibase + WI_OFF;
    int* csr = ibase + WI_CSR;

    hipMemsetAsync(cnts, 0, 100016 * sizeof(int), stream);
    hipMemsetAsync(gsum, 0, (NGRAPH * LATENT + 64) * sizeof(float), stream);

    prologue_kernel<<<PRO_GRID, 256, 0, stream>>>(
        d_in[0], d_in[4], d_in[5], d_in[6], d_in[7], d_in[8], d_in[9], d_in[10], d_in[11],
        hb, Wf, mb, lns, lnb, dW, db);

    histA_kernel<<<NBLK_P, 256, 0, stream>>>(snd, rcv, cnts, offc);
    scan_kernel<<<1, 1024, 0, stream>>>(offc, off, OFFN);
    partC_kernel<<<NBLK_P, 256, 0, stream>>>(snd, rcv, off, part, cnts, invs);
    buildD_kernel<<<NBUCK, 1024, 0, stream>>>(part, off, rowptr, invr, csr);

    for (int step = 0; step < STEPS; ++step) {
        const unsigned short* Wf0 = Wf + (size_t)(step * 2 + 0) * 16384;
        const unsigned short* Wf1 = Wf + (size_t)(step * 2 + 1) * 16384;
        const float* b0 = mb + (step * 2 + 0) * LATENT;
        const float* b1 = mb + (step * 2 + 1) * LATENT;
        fused_mlp_kernel<<<(N_NODES + 127) / 128, 512, 0, stream>>>(hb, Wf0, b0, Wf1, b1, mbuf, invs);
        gather_ln_kernel<<<N_NODES / 4, 256, 0, stream>>>(rowptr, csr, (const unsigned int*)mbuf,
                                                          invr, (unsigned int*)hb,
                                                          lns + step * LATENT,
                                                          lnb + step * LATENT);
    }

    pool_kernel<<<(N_NODES + 63) / 64, 128, 0, stream>>>(hb, gid, gsum, ws + WS_GCNT);
    dec_kernel<<<1, 640, 0, stream>>>(gsum, ws + WS_GCNT, dW, db, d_out,
                                      (const unsigned short*)d_in[8]);
}

// Round 11
// 490.273 us; speedup vs baseline: 1.0602x; 1.0090x over previous
//
#include <hip/hip_runtime.h>
#include <hip/hip_bf16.h>

#define N_NODES 100000
#define N_EDGES 1600000
#define NGRAPH 64
#define F_IN 16
#define LATENT 128
#define STEPS 3
#define OUTG 10
#define LN_EPS 1e-6f

// graph-build partition params
#define NBLK_P 256
#define CHUNK (N_EDGES / NBLK_P)  // 6250
#define NBUCK 98                  // ceil(100000/1024)
#define RPB 1024
#define OFFN (NBUCK * NBLK_P)     // 25088

typedef __attribute__((ext_vector_type(8))) short short8;
typedef __attribute__((ext_vector_type(4))) float f32x4;

// ---- ws layout (float indices) ----
#define WS_GSUM 16
#define WS_GCNT (WS_GSUM + NGRAPH * LATENT)
#define WS_INVS (WS_GCNT + 64)
#define WS_INVR (WS_INVS + N_NODES)
#define WS_MB (WS_INVR + N_NODES)
#define WS_LNS (WS_MB + STEPS * 2 * LATENT)
#define WS_LNB (WS_LNS + STEPS * LATENT)
#define WS_DW (WS_LNB + STEPS * LATENT)
#define WS_DB (WS_DW + LATENT * OUTG)
#define WS_WF (WS_DB + 16)                           // 6*16384 bf16 = 49152 floats
#define WS_PART (WS_WF + 49152)                      // u32 x N_EDGES
#define WS_HB (WS_PART + N_EDGES)                    // bf16 h, N*64 floats
#define WS_MSCALE (WS_HB + (size_t)N_NODES * 64)     // N floats
#define WS_MBUF (WS_MSCALE + N_NODES)                // fp8 m, N*128 bytes = N*32 floats
#define WS_INT (WS_MBUF + (size_t)N_NODES * 32)
// ints (offsets within int region)
#define WI_ROWPTR 0
#define WI_CNTS (WI_ROWPTR + 100016)
#define WI_OFFC (WI_CNTS + 100016)
#define WI_OFF (WI_OFFC + 25120)
#define WI_CSR 400064
#define WI_END (WI_CSR + N_EDGES)
#define WS_REQ_BYTES (((size_t)WS_INT + WI_END) * 4)

// prologue block ranges
#define PRO_EMBED 6250
#define PRO_WF (PRO_EMBED + 48)
#define PRO_CVT_N 2826
#define PRO_GRID (PRO_WF + 12)

__device__ __forceinline__ float bf2f(unsigned short u) {
    unsigned int i = ((unsigned int)u) << 16;
    float f;
    __builtin_memcpy(&f, &i, 4);
    return f;
}
__device__ __forceinline__ unsigned short f2bfbits(float f) {
    __hip_bfloat16 b = __float2bfloat16(f);
    unsigned short u;
    __builtin_memcpy(&u, &b, 2);
    return u;
}
__device__ __forceinline__ float lof(unsigned int u) {
    unsigned int v = u << 16;
    float f;
    __builtin_memcpy(&f, &v, 4);
    return f;
}
__device__ __forceinline__ float hif(unsigned int u) {
    unsigned int v = u & 0xffff0000u;
    float f;
    __builtin_memcpy(&f, &v, 4);
    return f;
}
__device__ __forceinline__ float rawf(const void* p, size_t i, bool f32m) {
    return f32m ? ((const float*)p)[i] : bf2f(((const unsigned short*)p)[i]);
}

// ---- fp8 e4m3 (OCP) encode/decode, non-negative values only ----
template <int SEL>
__device__ __forceinline__ float fp8dec(unsigned int u) {
#if __has_builtin(__builtin_amdgcn_cvt_f32_fp8)
    return __builtin_amdgcn_cvt_f32_fp8(u, SEL);
#else
    unsigned int b = (u >> (SEL * 8)) & 0xff;
    if (b >= 8) {  // normal: f32 bits = (b + 960) << 20  (exp rebias 7->127)
        unsigned int fb = (b + 960u) << 20;
        float f;
        __builtin_memcpy(&f, &fb, 4);
        return f;
    }
    return (float)b * (1.0f / 512.0f);  // denormal: m * 2^-9
#endif
}
__device__ __forceinline__ unsigned char fp8enc(float v) {  // v in [0, 240]
#if __has_builtin(__builtin_amdgcn_cvt_pk_fp8_f32)
    return (unsigned char)(__builtin_amdgcn_cvt_pk_fp8_f32(v, 0.0f, 0u, false) & 0xff);
#else
    if (v < 0.015625f) return (unsigned char)__float2int_rn(v * 512.0f);
    unsigned int u;
    __builtin_memcpy(&u, &v, 4);
    u += 0x7FFFFu + ((u >> 20) & 1u);  // RTNE to 3-bit mantissa
    return (unsigned char)((u >> 20) - 960u);
#endif
}

// ------- prologue: embed (raw inputs) | wfgen (raw mW) | cvt small params -------
__global__ void __launch_bounds__(256) prologue_kernel(
    const void* __restrict__ nodes_raw, const void* __restrict__ eW_raw,
    const void* __restrict__ eb_raw, const void* __restrict__ mW_raw,
    const void* __restrict__ mb_raw, const void* __restrict__ lns_raw,
    const void* __restrict__ lnb_raw, const void* __restrict__ dW_raw,
    const void* __restrict__ db_raw,
    unsigned short* __restrict__ hb, unsigned short* __restrict__ Wf,
    float* __restrict__ mb, float* __restrict__ lns, float* __restrict__ lnb,
    float* __restrict__ dW, float* __restrict__ db) {
    __shared__ float xs[16][F_IN];
    bool f32m = (((const unsigned short*)lns_raw)[0] == 0);
    int bid = blockIdx.x;
    int t = threadIdx.x;
    if (bid < PRO_EMBED) {
        int row0 = bid * 16;
        {
            int r = t >> 4, c = t & 15;
            xs[r][c] = rawf(nodes_raw, (size_t)(row0 + r) * F_IN + c, f32m);
        }
        __syncthreads();
        int col = t & 127;
        int rh = t >> 7;
        float acc[8];
        float bb = rawf(eb_raw, col, f32m);
#pragma unroll
        for (int j = 0; j < 8; j++) acc[j] = bb;
#pragma unroll
        for (int k = 0; k < F_IN; k++) {
            float w = rawf(eW_raw, k * LATENT + col, f32m);
#pragma unroll
            for (int j = 0; j < 8; j++) acc[j] += xs[rh * 8 + j][k] * w;
        }
        int rbase = row0 + rh * 8;
#pragma unroll
        for (int j = 0; j < 8; j++)
            hb[(size_t)(rbase + j) * LATENT + col] = f2bfbits(acc[j]);
    } else if (bid < PRO_WF) {
        int tid = (bid - PRO_EMBED) * 256 + t;
        int L = tid >> 11;
        int rem = tid & 2047;
        int ct = rem >> 8;
        int kt = (rem >> 6) & 3;
        int lane = rem & 63;
        size_t Wsoff = (size_t)L * 16384;
        int col = ct * 16 + (lane & 15);
        int k0 = kt * 32 + ((lane >> 4) << 3);
        short8 v;
#pragma unroll
        for (int i = 0; i < 8; i++)
            v[i] = (short)f2bfbits(rawf(mW_raw, Wsoff + (size_t)(k0 + i) * 128 + col, f32m));
        *(short8*)(Wf + (size_t)tid * 8) = v;
    } else {
        int i = (bid - PRO_WF) * 256 + t;
        if (i >= PRO_CVT_N) return;
        const void* src;
        float* dst;
        int j;
        if (i < 768) { src = mb_raw; dst = mb; j = i; }
        else if (i < 1152) { src = lns_raw; dst = lns; j = i - 768; }
        else if (i < 1536) { src = lnb_raw; dst = lnb; j = i - 1152; }
        else if (i < 2816) { src = dW_raw; dst = dW; j = i - 1536; }
        else { src = db_raw; dst = db; j = i - 2816; }
        dst[j] = rawf(src, j, f32m);
    }
}

// ---------------- phase A: sender-degree atomics + per-block bucket histogram ----------------
__global__ void __launch_bounds__(256) histA_kernel(const int* __restrict__ snd,
                                                    const int* __restrict__ rcv,
                                                    int* __restrict__ cnts,
                                                    int* __restrict__ offc) {
    __shared__ int lh[NBUCK];
    for (int i = threadIdx.x; i < NBUCK; i += 256) lh[i] = 0;
    __syncthreads();
    int base = blockIdx.x * CHUNK;
    for (int i = threadIdx.x; i < CHUNK; i += 256) {
        int e = base + i;
        atomicAdd(&cnts[snd[e]], 1);
        atomicAdd(&lh[rcv[e] >> 10], 1);
    }
    __syncthreads();
    for (int i = threadIdx.x; i < NBUCK; i += 256) offc[i * NBLK_P + blockIdx.x] = lh[i];
}

// ---------------- exclusive scan ----------------
__global__ void __launch_bounds__(1024) scan_kernel(const int* __restrict__ src,
                                                    int* __restrict__ dst, int n) {
    __shared__ int wsum[16];
    __shared__ int chunk_total;
    int tid = threadIdx.x;
    int lane = tid & 63, wid = tid >> 6;
    int carry = 0;
    for (int base = 0; base < n; base += 4096) {
        int i0 = base + tid * 4;
        int v0 = (i0 + 0 < n) ? src[i0 + 0] : 0;
        int v1 = (i0 + 1 < n) ? src[i0 + 1] : 0;
        int v2 = (i0 + 2 < n) ? src[i0 + 2] : 0;
        int v3 = (i0 + 3 < n) ? src[i0 + 3] : 0;
        int s = v0 + v1 + v2 + v3;
        int sc = s;
#pragma unroll
        for (int off = 1; off < 64; off <<= 1) {
            int t = __shfl_up(sc, off);
            if (lane >= off) sc += t;
        }
        if (lane == 63) wsum[wid] = sc;
        __syncthreads();
        if (wid == 0) {
            int w = (lane < 16) ? wsum[lane] : 0;
#pragma unroll
            for (int off = 1; off < 16; off <<= 1) {
                int t = __shfl_up(w, off);
                if (lane >= off) w += t;
            }
            if (lane < 16) wsum[lane] = w;
            if (lane == 15) chunk_total = w;
        }
        __syncthreads();
        int waveoff = (wid == 0) ? 0 : wsum[wid - 1];
        int p0 = carry + waveoff + (sc - s);
        int p1 = p0 + v0, p2 = p1 + v1, p3 = p2 + v2;
        if (i0 + 0 < n) dst[i0 + 0] = p0;
        if (i0 + 1 < n) dst[i0 + 1] = p1;
        if (i0 + 2 < n) dst[i0 + 2] = p2;
        if (i0 + 3 < n) dst[i0 + 3] = p3;
        carry += chunk_total;
        __syncthreads();
    }
    if (tid == 0) dst[n] = carry;
}

// ------- phase C: partition edges into receiver buckets (packed u32) + invs tail -------
__global__ void __launch_bounds__(256) partC_kernel(const int* __restrict__ snd,
                                                    const int* __restrict__ rcv,
                                                    const int* __restrict__ off,
                                                    unsigned int* __restrict__ part,
                                                    const int* __restrict__ cnts,
                                                    float* __restrict__ invs) {
    __shared__ int lcur[NBUCK];
    for (int i = threadIdx.x; i < NBUCK; i += 256) lcur[i] = off[i * NBLK_P + blockIdx.x];
    __syncthreads();
    int base = blockIdx.x * CHUNK;
    for (int i = threadIdx.x; i < CHUNK; i += 256) {
        int e = base + i;
        int r = rcv[e];
        int pos = atomicAdd(&lcur[r >> 10], 1);
        part[pos] = ((unsigned int)snd[e] << 10) | (unsigned int)(r & 1023);
    }
    for (int i = blockIdx.x * 256 + threadIdx.x; i < N_NODES; i += 256 * NBLK_P)
        invs[i] = rsqrtf((float)cnts[i] + 1.0f);
}

// ---------------- phase D: per-bucket CSR build ----------------
__global__ void __launch_bounds__(1024) buildD_kernel(const unsigned int* __restrict__ part,
                                                      const int* __restrict__ off,
                                                      int* __restrict__ rowptr,
                                                      float* __restrict__ invr,
                                                      int* __restrict__ csr) {
    __shared__ int lcnt[RPB];
    __shared__ int lscan[RPB];
    __shared__ int ltmp[RPB];
    int b = blockIdx.x;
    int tid = threadIdx.x;
    int beg = off[b * NBLK_P];
    int end = off[(b + 1) * NBLK_P];
    lcnt[tid] = 0;
    __syncthreads();
    for (int i = beg + tid; i < end; i += 1024) atomicAdd(&lcnt[part[i] & 1023], 1);
    __syncthreads();
    lscan[tid] = lcnt[tid];
    __syncthreads();
    int* sp = lscan;
    int* dp = ltmp;
    for (int st = 1; st < RPB; st <<= 1) {
        dp[tid] = sp[tid] + ((tid >= st) ? sp[tid - st] : 0);
        __syncthreads();
        int* t = sp; sp = dp; dp = t;
    }
    {
        int c = lcnt[tid];
        int cur = beg + sp[tid] - c;
        int gr = b * RPB + tid;
        if (gr < N_NODES) {
            rowptr[gr] = cur;
            invr[gr] = rsqrtf((float)c + 1.0f);
        }
        lcnt[tid] = cur;
    }
    __syncthreads();
    for (int i = beg + tid; i < end; i += 1024) {
        unsigned int e = part[i];
        int pos = atomicAdd(&lcnt[e & 1023], 1);
        csr[pos] = (int)(e >> 10);
    }
    if (b == NBUCK - 1 && tid == 0) rowptr[N_NODES] = N_EDGES;
}

// ------- fused 2-layer MLP: 512 thr / 8 waves / 128 rows; fp8 output + per-row scale -------
#define LPAD 136
__global__ void __launch_bounds__(512) fused_mlp_kernel(const unsigned short* __restrict__ xb,
                                                        const unsigned short* __restrict__ Wf0,
                                                        const float* __restrict__ b0,
                                                        const unsigned short* __restrict__ Wf1,
                                                        const float* __restrict__ b1,
                                                        unsigned char* __restrict__ yb8,
                                                        float* __restrict__ mscale,
                                                        const float* __restrict__ scale) {
    __shared__ unsigned short ls[8][16][LPAD];
    int lane = threadIdx.x & 63;
    int wid = threadIdx.x >> 6;
    int rows0 = blockIdx.x * 128 + wid * 16;
    int l15 = lane & 15;
    int l4 = lane >> 4;

    f32x4 acc[8];
#pragma unroll
    for (int ct = 0; ct < 8; ct++) {
        float bb = b0[ct * 16 + l15];
        acc[ct] = (f32x4){bb, bb, bb, bb};
    }
    {
        int arow_c = min(rows0 + l15, N_NODES - 1);
        const short8* xrow = (const short8*)(xb + (size_t)arow_c * LATENT);
#pragma unroll
        for (int kt = 0; kt < 4; kt++) {
            short8 a = xrow[kt * 4 + l4];
#pragma unroll
            for (int ct = 0; ct < 8; ct++) {
                short8 bf = *(const short8*)(Wf0 + (size_t)(((ct * 4 + kt) * 64 + lane)) * 8);
                acc[ct] = __builtin_amdgcn_mfma_f32_16x16x32_bf16(a, bf, acc[ct], 0, 0, 0);
            }
        }
    }
    {
        int lrow = l4 << 2;
#pragma unroll
        for (int ct = 0; ct < 8; ct++)
#pragma unroll
            for (int j = 0; j < 4; j++)
                ls[wid][lrow + j][ct * 16 + l15] = f2bfbits(fmaxf(acc[ct][j], 0.0f));
    }
    __syncthreads();

#pragma unroll
    for (int ct = 0; ct < 8; ct++) {
        float bb = b1[ct * 16 + l15];
        acc[ct] = (f32x4){bb, bb, bb, bb};
    }
#pragma unroll
    for (int kt = 0; kt < 4; kt++) {
        short8 a = *(const short8*)&ls[wid][l15][kt * 32 + (l4 << 3)];
#pragma unroll
        for (int ct = 0; ct < 8; ct++) {
            short8 bf = *(const short8*)(Wf1 + (size_t)(((ct * 4 + kt) * 64 + lane)) * 8);
            acc[ct] = __builtin_amdgcn_mfma_f32_16x16x32_bf16(a, bf, acc[ct], 0, 0, 0);
        }
    }
    __syncthreads();
    // ---- epilogue: per-row max -> scale -> fp8 quantize into LDS bytes ----
    unsigned char* lsb = (unsigned char*)&ls[wid][0][0];  // per-wave region, stride 136 B
    {
        int lrow = l4 << 2;
#pragma unroll
        for (int j = 0; j < 4; j++) {
            int rr = rows0 + lrow + j;
            int r = min(rr, N_NODES - 1);
            float sc = scale[r];
            float v[8];
            float mx = 0.0f;
#pragma unroll
            for (int ct = 0; ct < 8; ct++) {
                v[ct] = fmaxf(acc[ct][j], 0.0f) * sc;
                mx = fmaxf(mx, v[ct]);
            }
#pragma unroll
            for (int off = 1; off < 16; off <<= 1) mx = fmaxf(mx, __shfl_xor(mx, off));
            float qm = (mx > 0.0f) ? (240.0f / mx) : 0.0f;
            if (l15 == 0 && rr < N_NODES) mscale[rr] = mx * (1.0f / 240.0f);
#pragma unroll
            for (int ct = 0; ct < 8; ct++)
                lsb[(lrow + j) * 136 + ct * 16 + l15] = fp8enc(v[ct] * qm);
        }
    }
    __syncthreads();
    // coalesced store: 128B row = 16 lanes x 8B; 4 rows (l4) per pass
#pragma unroll
    for (int p = 0; p < 4; p++) {
        int row = p * 4 + l4;
        unsigned long long v8;
        __builtin_memcpy(&v8, &lsb[row * 136 + l15 * 8], 8);
        int r = rows0 + row;
        if (r < N_NODES) *(unsigned long long*)(yb8 + (size_t)r * 128 + l15 * 8) = v8;
    }
}

// ------- gather (CSR, fp8 m + per-row scale) + inv_r + skip + LayerNorm (bf16 residual) -------
__global__ void __launch_bounds__(256) gather_ln_kernel(const int* __restrict__ rowptr,
                                                        const int* __restrict__ csr,
                                                        const unsigned short* __restrict__ mb8,
                                                        const float* __restrict__ mscale,
                                                        const float* __restrict__ invr,
                                                        unsigned int* __restrict__ hb2,
                                                        const float* __restrict__ lnsc,
                                                        const float* __restrict__ lnbi) {
    int node = (blockIdx.x * 256 + threadIdx.x) >> 6;
    int lane = threadIdx.x & 63;
    if (node >= N_NODES) return;
    int beg = rowptr[node];
    int end = rowptr[node + 1];
    // self edge (m already *inv_s)
    unsigned int sv = mb8[(size_t)node * 64 + lane];
    float scn = mscale[node];
    float ax = fp8dec<0>(sv) * scn;
    float ay = fp8dec<1>(sv) * scn;
    for (int base = beg; base < end; base += 64) {
        int cnt = min(64, end - base);
        int idx = (lane < cnt) ? __builtin_nontemporal_load(csr + base + lane) : 0;
        int j = 0;
        for (; j + 3 < cnt; j += 4) {
            int s0 = __shfl(idx, j);
            int s1 = __shfl(idx, j + 1);
            int s2 = __shfl(idx, j + 2);
            int s3 = __shfl(idx, j + 3);
            unsigned int ua = mb8[(size_t)s0 * 64 + lane];
            unsigned int ub = mb8[(size_t)s1 * 64 + lane];
            unsigned int uc = mb8[(size_t)s2 * 64 + lane];
            unsigned int ud = mb8[(size_t)s3 * 64 + lane];
            float ka = mscale[s0];
            float kb = mscale[s1];
            float kc = mscale[s2];
            float kd = mscale[s3];
            ax = fmaf(fp8dec<0>(ua), ka, ax);
            ay = fmaf(fp8dec<1>(ua), ka, ay);
            ax = fmaf(fp8dec<0>(ub), kb, ax);
            ay = fmaf(fp8dec<1>(ub), kb, ay);
            ax = fmaf(fp8dec<0>(uc), kc, ax);
            ay = fmaf(fp8dec<1>(uc), kc, ay);
            ax = fmaf(fp8dec<0>(ud), kd, ax);
            ay = fmaf(fp8dec<1>(ud), kd, ay);
        }
        for (; j < cnt; ++j) {
            int s0 = __shfl(idx, j);
            unsigned int ua = mb8[(size_t)s0 * 64 + lane];
            float ka = mscale[s0];
            ax = fmaf(fp8dec<0>(ua), ka, ax);
            ay = fmaf(fp8dec<1>(ua), ka, ay);
        }
    }
    float ir = invr[node];
    unsigned int hu = __builtin_nontemporal_load(hb2 + (size_t)node * 64 + lane);
    float tx = ax * ir + lof(hu);
    float ty = ay * ir + hif(hu);
    float s = tx + ty, s2 = tx * tx + ty * ty;
#pragma unroll
    for (int o = 1; o < 64; o <<= 1) {
        s += __shfl_xor(s, o);
        s2 += __shfl_xor(s2, o);
    }
    float mu = s * (1.0f / 128.0f);
    float var = s2 * (1.0f / 128.0f) - mu * mu;
    float rstd = rsqrtf(var + LN_EPS);
    float ox = (tx - mu) * rstd * lnsc[lane * 2] + lnbi[lane * 2];
    float oy = (ty - mu) * rstd * lnsc[lane * 2 + 1] + lnbi[lane * 2 + 1];
    unsigned int pk = (unsigned int)f2bfbits(ox) | ((unsigned int)f2bfbits(oy) << 16);
    __builtin_nontemporal_store(pk, hb2 + (size_t)node * 64 + lane);
}

// ---------------- pooling: run-length over sorted graph_ids (bf16 h) ----------------
__global__ void __launch_bounds__(128) pool_kernel(const unsigned short* __restrict__ hb,
                                                   const int* __restrict__ gid,
                                                   float* __restrict__ gsum,
                                                   float* __restrict__ gcnt) {
    int col = threadIdx.x;
    int n0 = blockIdx.x * 64;
    int nend = min(n0 + 64, N_NODES);
    if (n0 >= N_NODES) return;
    int cur = gid[n0];
    float acc = 0.0f, cacc = 0.0f;
    for (int n = n0; n < nend; ++n) {
        int g = gid[n];
        if (g != cur) {
            atomicAdd(&gsum[cur * LATENT + col], acc);
            if (col == 0) atomicAdd(&gcnt[cur], cacc);
            acc = 0.0f;
            cacc = 0.0f;
            cur = g;
        }
        acc += bf2f(hb[(size_t)n * LATENT + col]);
        cacc += 1.0f;
    }
    atomicAdd(&gsum[cur * LATENT + col], acc);
    if (col == 0) atomicAdd(&gcnt[cur], cacc);
}

// ---------------- decoder (dual-dtype output, inline flag) ----------------
__global__ void __launch_bounds__(640) dec_kernel(const float* __restrict__ gsum,
                                                  const float* __restrict__ gcnt,
                                                  const float* __restrict__ dW,
                                                  const float* __restrict__ db,
                                                  void* __restrict__ out,
                                                  const unsigned short* __restrict__ lns_raw) {
    int t = threadIdx.x;
    if (t >= NGRAPH * OUTG) return;
    int g = t / OUTG, o = t % OUTG;
    float inv = 1.0f / fmaxf(gcnt[g], 1.0f);
    float acc = 0.0f;
    for (int k = 0; k < LATENT; k++) acc += gsum[g * LATENT + k] * dW[k * OUTG + o];
    acc = acc * inv + db[o];
    if (lns_raw[0] == 0) ((float*)out)[t] = acc;
    else ((__hip_bfloat16*)out)[t] = __float2bfloat16(acc);
}

__global__ void diag_kernel(float* out, float val) {
    if (threadIdx.x == 0) out[0] = val;
}

extern "C" void kernel_launch(void* const* d_in, const int* in_sizes, int n_in,
                              void* d_out, int out_size, void* d_ws, size_t ws_size,
                              hipStream_t stream) {
    (void)in_sizes; (void)n_in; (void)out_size;
    const int* snd = (const int*)d_in[1];
    const int* rcv = (const int*)d_in[2];
    const int* gid = (const int*)d_in[3];

    if (ws_size < (size_t)WS_REQ_BYTES) {
        diag_kernel<<<1, 64, 0, stream>>>((float*)d_out, 1.0e6f + (float)(ws_size >> 20));
        return;
    }

    float* ws = (float*)d_ws;
    float* gsum = ws + WS_GSUM;
    float* invs = ws + WS_INVS;
    float* invr = ws + WS_INVR;
    float* mb = ws + WS_MB;
    float* lns = ws + WS_LNS;
    float* lnb = ws + WS_LNB;
    float* dW = ws + WS_DW;
    float* db = ws + WS_DB;
    unsigned short* Wf = (unsigned short*)(ws + WS_WF);
    unsigned int* part = (unsigned int*)(ws + WS_PART);
    unsigned short* hb = (unsigned short*)(ws + WS_HB);
    float* mscale = ws + WS_MSCALE;
    unsigned char* mbuf8 = (unsigned char*)(ws + WS_MBUF);
    int* ibase = (int*)(ws + WS_INT);
    int* rowptr = ibase + WI_ROWPTR;
    int* cnts = ibase + WI_CNTS;
    int* offc = ibase + WI_OFFC;
    int* off = ibase + WI_OFF;
    int* csr = ibase + WI_CSR;

    hipMemsetAsync(cnts, 0, 100016 * sizeof(int), stream);
    hipMemsetAsync(gsum, 0, (NGRAPH * LATENT + 64) * sizeof(float), stream);

    prologue_kernel<<<PRO_GRID, 256, 0, stream>>>(
        d_in[0], d_in[4], d_in[5], d_in[6], d_in[7], d_in[8], d_in[9], d_in[10], d_in[11],
        hb, Wf, mb, lns, lnb, dW, db);

    histA_kernel<<<NBLK_P, 256, 0, stream>>>(snd, rcv, cnts, offc);
    scan_kernel<<<1, 1024, 0, stream>>>(offc, off, OFFN);
    partC_kernel<<<NBLK_P, 256, 0, stream>>>(snd, rcv, off, part, cnts, invs);
    buildD_kernel<<<NBUCK, 1024, 0, stream>>>(part, off, rowptr, invr, csr);

    for (int step = 0; step < STEPS; ++step) {
        const unsigned short* Wf0 = Wf + (size_t)(step * 2 + 0) * 16384;
        const unsigned short* Wf1 = Wf + (size_t)(step * 2 + 1) * 16384;
        const float* b0 = mb + (step * 2 + 0) * LATENT;
        const float* b1 = mb + (step * 2 + 1) * LATENT;
        fused_mlp_kernel<<<(N_NODES + 127) / 128, 512, 0, stream>>>(hb, Wf0, b0, Wf1, b1,
                                                                    mbuf8, mscale, invs);
        gather_ln_kernel<<<N_NODES / 4, 256, 0, stream>>>(rowptr, csr, (const unsigned short*)mbuf8,
                                                          mscale, invr, (unsigned int*)hb,
                                                          lns + step * LATENT,
                                                          lnb + step * LATENT);
    }

    pool_kernel<<<(N_NODES + 63) / 64, 128, 0, stream>>>(hb, gid, gsum, ws + WS_GCNT);
    dec_kernel<<<1, 640, 0, stream>>>(gsum, ws + WS_GCNT, dW, db, d_out,
                                      (const unsigned short*)d_in[8]);
}

// Round 12
// 462.456 us; speedup vs baseline: 1.1239x; 1.0601x over previous
//
#include <hip/hip_runtime.h>
#include <hip/hip_bf16.h>

#define N_NODES 100000
#define N_EDGES 1600000
#define NGRAPH 64
#define F_IN 16
#define LATENT 128
#define STEPS 3
#define OUTG 10
#define LN_EPS 1e-6f

// graph-build partition params
#define NBLK_P 256
#define CHUNK (N_EDGES / NBLK_P)  // 6250
#define NBUCK 98                  // ceil(100000/1024)
#define RPB 1024
#define OFFN (NBUCK * NBLK_P)     // 25088

typedef __attribute__((ext_vector_type(8))) short short8;
typedef __attribute__((ext_vector_type(4))) float f32x4;

// ---- ws layout (float indices) ----
#define WS_GSUM 16
#define WS_GCNT (WS_GSUM + NGRAPH * LATENT)
#define WS_INVS (WS_GCNT + 64)
#define WS_INVR (WS_INVS + N_NODES)
#define WS_MB (WS_INVR + N_NODES)
#define WS_LNS (WS_MB + STEPS * 2 * LATENT)
#define WS_LNB (WS_LNS + STEPS * LATENT)
#define WS_DW (WS_LNB + STEPS * LATENT)
#define WS_DB (WS_DW + LATENT * OUTG)
#define WS_WF (WS_DB + 16)                           // 6*16384 bf16 = 49152 floats
#define WS_PART (WS_WF + 49152)                      // u32 x N_EDGES
#define WS_HB (WS_PART + N_EDGES)                    // bf16 h, N*64 floats
#define WS_MSCALE (WS_HB + (size_t)N_NODES * 64)     // N floats
#define WS_MBUF (WS_MSCALE + N_NODES)                // fp8 m, N*128 bytes = N*32 floats
#define WS_INT (WS_MBUF + (size_t)N_NODES * 32)
// ints (offsets within int region)
#define WI_ROWPTR 0
#define WI_CNTS (WI_ROWPTR + 100016)
#define WI_OFFC (WI_CNTS + 100016)
#define WI_OFF (WI_OFFC + 25120)
#define WI_CSR 400064
#define WI_END (WI_CSR + N_EDGES)
#define WS_REQ_BYTES (((size_t)WS_INT + WI_END) * 4)

// prologue block ranges
#define PRO_EMBED 6250
#define PRO_WF (PRO_EMBED + 48)
#define PRO_CVT_N 2826
#define PRO_GRID (PRO_WF + 12)

__device__ __forceinline__ float bf2f(unsigned short u) {
    unsigned int i = ((unsigned int)u) << 16;
    float f;
    __builtin_memcpy(&f, &i, 4);
    return f;
}
__device__ __forceinline__ unsigned short f2bfbits(float f) {
    __hip_bfloat16 b = __float2bfloat16(f);
    unsigned short u;
    __builtin_memcpy(&u, &b, 2);
    return u;
}
__device__ __forceinline__ float lof(unsigned int u) {
    unsigned int v = u << 16;
    float f;
    __builtin_memcpy(&f, &v, 4);
    return f;
}
__device__ __forceinline__ float hif(unsigned int u) {
    unsigned int v = u & 0xffff0000u;
    float f;
    __builtin_memcpy(&f, &v, 4);
    return f;
}
__device__ __forceinline__ float rawf(const void* p, size_t i, bool f32m) {
    return f32m ? ((const float*)p)[i] : bf2f(((const unsigned short*)p)[i]);
}

// ---- fp8 e4m3 (OCP) encode/decode, non-negative values only ----
template <int SEL>
__device__ __forceinline__ float fp8dec(unsigned int u) {
#if __has_builtin(__builtin_amdgcn_cvt_f32_fp8)
    return __builtin_amdgcn_cvt_f32_fp8(u, SEL);
#else
    unsigned int b = (u >> (SEL * 8)) & 0xff;
    if (b >= 8) {
        unsigned int fb = (b + 960u) << 20;
        float f;
        __builtin_memcpy(&f, &fb, 4);
        return f;
    }
    return (float)b * (1.0f / 512.0f);
#endif
}
__device__ __forceinline__ unsigned char fp8enc(float v) {  // v in [0, 240]
#if __has_builtin(__builtin_amdgcn_cvt_pk_fp8_f32)
    return (unsigned char)(__builtin_amdgcn_cvt_pk_fp8_f32(v, 0.0f, 0u, false) & 0xff);
#else
    if (v < 0.015625f) return (unsigned char)__float2int_rn(v * 512.0f);
    unsigned int u;
    __builtin_memcpy(&u, &v, 4);
    u += 0x7FFFFu + ((u >> 20) & 1u);
    return (unsigned char)((u >> 20) - 960u);
#endif
}

// ------- prologue: embed (raw inputs) | wfgen (raw mW) | cvt small params -------
__global__ void __launch_bounds__(256) prologue_kernel(
    const void* __restrict__ nodes_raw, const void* __restrict__ eW_raw,
    const void* __restrict__ eb_raw, const void* __restrict__ mW_raw,
    const void* __restrict__ mb_raw, const void* __restrict__ lns_raw,
    const void* __restrict__ lnb_raw, const void* __restrict__ dW_raw,
    const void* __restrict__ db_raw,
    unsigned short* __restrict__ hb, unsigned short* __restrict__ Wf,
    float* __restrict__ mb, float* __restrict__ lns, float* __restrict__ lnb,
    float* __restrict__ dW, float* __restrict__ db) {
    __shared__ float xs[16][F_IN];
    bool f32m = (((const unsigned short*)lns_raw)[0] == 0);
    int bid = blockIdx.x;
    int t = threadIdx.x;
    if (bid < PRO_EMBED) {
        int row0 = bid * 16;
        {
            int r = t >> 4, c = t & 15;
            xs[r][c] = rawf(nodes_raw, (size_t)(row0 + r) * F_IN + c, f32m);
        }
        __syncthreads();
        int col = t & 127;
        int rh = t >> 7;
        float acc[8];
        float bb = rawf(eb_raw, col, f32m);
#pragma unroll
        for (int j = 0; j < 8; j++) acc[j] = bb;
#pragma unroll
        for (int k = 0; k < F_IN; k++) {
            float w = rawf(eW_raw, k * LATENT + col, f32m);
#pragma unroll
            for (int j = 0; j < 8; j++) acc[j] += xs[rh * 8 + j][k] * w;
        }
        int rbase = row0 + rh * 8;
#pragma unroll
        for (int j = 0; j < 8; j++)
            hb[(size_t)(rbase + j) * LATENT + col] = f2bfbits(acc[j]);
    } else if (bid < PRO_WF) {
        int tid = (bid - PRO_EMBED) * 256 + t;
        int L = tid >> 11;
        int rem = tid & 2047;
        int ct = rem >> 8;
        int kt = (rem >> 6) & 3;
        int lane = rem & 63;
        size_t Wsoff = (size_t)L * 16384;
        int col = ct * 16 + (lane & 15);
        int k0 = kt * 32 + ((lane >> 4) << 3);
        short8 v;
#pragma unroll
        for (int i = 0; i < 8; i++)
            v[i] = (short)f2bfbits(rawf(mW_raw, Wsoff + (size_t)(k0 + i) * 128 + col, f32m));
        *(short8*)(Wf + (size_t)tid * 8) = v;
    } else {
        int i = (bid - PRO_WF) * 256 + t;
        if (i >= PRO_CVT_N) return;
        const void* src;
        float* dst;
        int j;
        if (i < 768) { src = mb_raw; dst = mb; j = i; }
        else if (i < 1152) { src = lns_raw; dst = lns; j = i - 768; }
        else if (i < 1536) { src = lnb_raw; dst = lnb; j = i - 1152; }
        else if (i < 2816) { src = dW_raw; dst = dW; j = i - 1536; }
        else { src = db_raw; dst = db; j = i - 2816; }
        dst[j] = rawf(src, j, f32m);
    }
}

// ---------------- phase A: sender-degree atomics + per-block bucket histogram ----------------
__global__ void __launch_bounds__(256) histA_kernel(const int* __restrict__ snd,
                                                    const int* __restrict__ rcv,
                                                    int* __restrict__ cnts,
                                                    int* __restrict__ offc) {
    __shared__ int lh[NBUCK];
    for (int i = threadIdx.x; i < NBUCK; i += 256) lh[i] = 0;
    __syncthreads();
    int base = blockIdx.x * CHUNK;
    for (int i = threadIdx.x; i < CHUNK; i += 256) {
        int e = base + i;
        atomicAdd(&cnts[snd[e]], 1);
        atomicAdd(&lh[rcv[e] >> 10], 1);
    }
    __syncthreads();
    for (int i = threadIdx.x; i < NBUCK; i += 256) offc[i * NBLK_P + blockIdx.x] = lh[i];
}

// ---------------- exclusive scan ----------------
__global__ void __launch_bounds__(1024) scan_kernel(const int* __restrict__ src,
                                                    int* __restrict__ dst, int n) {
    __shared__ int wsum[16];
    __shared__ int chunk_total;
    int tid = threadIdx.x;
    int lane = tid & 63, wid = tid >> 6;
    int carry = 0;
    for (int base = 0; base < n; base += 4096) {
        int i0 = base + tid * 4;
        int v0 = (i0 + 0 < n) ? src[i0 + 0] : 0;
        int v1 = (i0 + 1 < n) ? src[i0 + 1] : 0;
        int v2 = (i0 + 2 < n) ? src[i0 + 2] : 0;
        int v3 = (i0 + 3 < n) ? src[i0 + 3] : 0;
        int s = v0 + v1 + v2 + v3;
        int sc = s;
#pragma unroll
        for (int off = 1; off < 64; off <<= 1) {
            int t = __shfl_up(sc, off);
            if (lane >= off) sc += t;
        }
        if (lane == 63) wsum[wid] = sc;
        __syncthreads();
        if (wid == 0) {
            int w = (lane < 16) ? wsum[lane] : 0;
#pragma unroll
            for (int off = 1; off < 16; off <<= 1) {
                int t = __shfl_up(w, off);
                if (lane >= off) w += t;
            }
            if (lane < 16) wsum[lane] = w;
            if (lane == 15) chunk_total = w;
        }
        __syncthreads();
        int waveoff = (wid == 0) ? 0 : wsum[wid - 1];
        int p0 = carry + waveoff + (sc - s);
        int p1 = p0 + v0, p2 = p1 + v1, p3 = p2 + v2;
        if (i0 + 0 < n) dst[i0 + 0] = p0;
        if (i0 + 1 < n) dst[i0 + 1] = p1;
        if (i0 + 2 < n) dst[i0 + 2] = p2;
        if (i0 + 3 < n) dst[i0 + 3] = p3;
        carry += chunk_total;
        __syncthreads();
    }
    if (tid == 0) dst[n] = carry;
}

// ------- phase C: partition edges into receiver buckets (packed u32) + invs tail -------
__global__ void __launch_bounds__(256) partC_kernel(const int* __restrict__ snd,
                                                    const int* __restrict__ rcv,
                                                    const int* __restrict__ off,
                                                    unsigned int* __restrict__ part,
                                                    const int* __restrict__ cnts,
                                                    float* __restrict__ invs) {
    __shared__ int lcur[NBUCK];
    for (int i = threadIdx.x; i < NBUCK; i += 256) lcur[i] = off[i * NBLK_P + blockIdx.x];
    __syncthreads();
    int base = blockIdx.x * CHUNK;
    for (int i = threadIdx.x; i < CHUNK; i += 256) {
        int e = base + i;
        int r = rcv[e];
        int pos = atomicAdd(&lcur[r >> 10], 1);
        part[pos] = ((unsigned int)snd[e] << 10) | (unsigned int)(r & 1023);
    }
    for (int i = blockIdx.x * 256 + threadIdx.x; i < N_NODES; i += 256 * NBLK_P)
        invs[i] = rsqrtf((float)cnts[i] + 1.0f);
}

// ---------------- phase D: per-bucket CSR build ----------------
__global__ void __launch_bounds__(1024) buildD_kernel(const unsigned int* __restrict__ part,
                                                      const int* __restrict__ off,
                                                      int* __restrict__ rowptr,
                                                      float* __restrict__ invr,
                                                      int* __restrict__ csr) {
    __shared__ int lcnt[RPB];
    __shared__ int lscan[RPB];
    __shared__ int ltmp[RPB];
    int b = blockIdx.x;
    int tid = threadIdx.x;
    int beg = off[b * NBLK_P];
    int end = off[(b + 1) * NBLK_P];
    lcnt[tid] = 0;
    __syncthreads();
    for (int i = beg + tid; i < end; i += 1024) atomicAdd(&lcnt[part[i] & 1023], 1);
    __syncthreads();
    lscan[tid] = lcnt[tid];
    __syncthreads();
    int* sp = lscan;
    int* dp = ltmp;
    for (int st = 1; st < RPB; st <<= 1) {
        dp[tid] = sp[tid] + ((tid >= st) ? sp[tid - st] : 0);
        __syncthreads();
        int* t = sp; sp = dp; dp = t;
    }
    {
        int c = lcnt[tid];
        int cur = beg + sp[tid] - c;
        int gr = b * RPB + tid;
        if (gr < N_NODES) {
            rowptr[gr] = cur;
            invr[gr] = rsqrtf((float)c + 1.0f);
        }
        lcnt[tid] = cur;
    }
    __syncthreads();
    for (int i = beg + tid; i < end; i += 1024) {
        unsigned int e = part[i];
        int pos = atomicAdd(&lcnt[e & 1023], 1);
        csr[pos] = (int)(e >> 10);
    }
    if (b == NBUCK - 1 && tid == 0) rowptr[N_NODES] = N_EDGES;
}

// ------- fused 2-layer MLP: 512 thr / 8 waves / 128 rows; fp8 output + per-row scale -------
#define LPAD 136
__global__ void __launch_bounds__(512) fused_mlp_kernel(const unsigned short* __restrict__ xb,
                                                        const unsigned short* __restrict__ Wf0,
                                                        const float* __restrict__ b0,
                                                        const unsigned short* __restrict__ Wf1,
                                                        const float* __restrict__ b1,
                                                        unsigned char* __restrict__ yb8,
                                                        float* __restrict__ mscale,
                                                        const float* __restrict__ scale) {
    __shared__ unsigned short ls[8][16][LPAD];
    int lane = threadIdx.x & 63;
    int wid = threadIdx.x >> 6;
    int rows0 = blockIdx.x * 128 + wid * 16;
    int l15 = lane & 15;
    int l4 = lane >> 4;

    f32x4 acc[8];
#pragma unroll
    for (int ct = 0; ct < 8; ct++) {
        float bb = b0[ct * 16 + l15];
        acc[ct] = (f32x4){bb, bb, bb, bb};
    }
    {
        int arow_c = min(rows0 + l15, N_NODES - 1);
        const short8* xrow = (const short8*)(xb + (size_t)arow_c * LATENT);
#pragma unroll
        for (int kt = 0; kt < 4; kt++) {
            short8 a = xrow[kt * 4 + l4];
#pragma unroll
            for (int ct = 0; ct < 8; ct++) {
                short8 bf = *(const short8*)(Wf0 + (size_t)(((ct * 4 + kt) * 64 + lane)) * 8);
                acc[ct] = __builtin_amdgcn_mfma_f32_16x16x32_bf16(a, bf, acc[ct], 0, 0, 0);
            }
        }
    }
    {
        int lrow = l4 << 2;
#pragma unroll
        for (int ct = 0; ct < 8; ct++)
#pragma unroll
            for (int j = 0; j < 4; j++)
                ls[wid][lrow + j][ct * 16 + l15] = f2bfbits(fmaxf(acc[ct][j], 0.0f));
    }
    __syncthreads();

#pragma unroll
    for (int ct = 0; ct < 8; ct++) {
        float bb = b1[ct * 16 + l15];
        acc[ct] = (f32x4){bb, bb, bb, bb};
    }
#pragma unroll
    for (int kt = 0; kt < 4; kt++) {
        short8 a = *(const short8*)&ls[wid][l15][kt * 32 + (l4 << 3)];
#pragma unroll
        for (int ct = 0; ct < 8; ct++) {
            short8 bf = *(const short8*)(Wf1 + (size_t)(((ct * 4 + kt) * 64 + lane)) * 8);
            acc[ct] = __builtin_amdgcn_mfma_f32_16x16x32_bf16(a, bf, acc[ct], 0, 0, 0);
        }
    }
    __syncthreads();
    unsigned char* lsb = (unsigned char*)&ls[wid][0][0];
    {
        int lrow = l4 << 2;
#pragma unroll
        for (int j = 0; j < 4; j++) {
            int rr = rows0 + lrow + j;
            int r = min(rr, N_NODES - 1);
            float sc = scale[r];
            float v[8];
            float mx = 0.0f;
#pragma unroll
            for (int ct = 0; ct < 8; ct++) {
                v[ct] = fmaxf(acc[ct][j], 0.0f) * sc;
                mx = fmaxf(mx, v[ct]);
            }
#pragma unroll
            for (int off = 1; off < 16; off <<= 1) mx = fmaxf(mx, __shfl_xor(mx, off));
            float qm = (mx > 0.0f) ? (240.0f / mx) : 0.0f;
            if (l15 == 0 && rr < N_NODES) mscale[rr] = mx * (1.0f / 240.0f);
#pragma unroll
            for (int ct = 0; ct < 8; ct++)
                lsb[(lrow + j) * 136 + ct * 16 + l15] = fp8enc(v[ct] * qm);
        }
    }
    __syncthreads();
#pragma unroll
    for (int p = 0; p < 4; p++) {
        int row = p * 4 + l4;
        unsigned long long v8;
        __builtin_memcpy(&v8, &lsb[row * 136 + l15 * 8], 8);
        int r = rows0 + row;
        if (r < N_NODES) *(unsigned long long*)(yb8 + (size_t)r * 128 + l15 * 8) = v8;
    }
}

// ------- gather v3: 2 edges per VMEM inst (two 32-lane halves), fp8 rows, + skip + LN -------
__global__ void __launch_bounds__(256) gather_ln_kernel(const int* __restrict__ rowptr,
                                                        const int* __restrict__ csr,
                                                        const unsigned int* __restrict__ mb32,
                                                        const float* __restrict__ mscale,
                                                        const float* __restrict__ invr,
                                                        unsigned int* __restrict__ hb2,
                                                        const float* __restrict__ lnsc,
                                                        const float* __restrict__ lnbi) {
    int node = (blockIdx.x * 256 + threadIdx.x) >> 6;
    int lane = threadIdx.x & 63;
    if (node >= N_NODES) return;
    int half = lane >> 5;  // 0/1: which edge of each pair
    int c = lane & 31;     // u32 column: feature cols 4c..4c+3

    int beg = rowptr[node];
    int end = rowptr[node + 1];

    float a0 = 0.0f, a1 = 0.0f, a2 = 0.0f, a3 = 0.0f;
    if (half == 0) {  // self edge (m already *inv_s)
        unsigned int v = mb32[(size_t)node * 32 + c];
        float k = mscale[node];
        a0 = fp8dec<0>(v) * k;
        a1 = fp8dec<1>(v) * k;
        a2 = fp8dec<2>(v) * k;
        a3 = fp8dec<3>(v) * k;
    }

    for (int base = beg; base < end; base += 64) {
        int cnt = min(64, end - base);
        int idx = (lane < cnt) ? __builtin_nontemporal_load(csr + base + lane) : 0;
        int nfull = cnt >> 1;  // pairs where both halves have a valid edge
        int i = 0;
        for (; i + 3 < nfull; i += 4) {
            int j0 = 2 * i + half;
            int s0 = __shfl(idx, j0);
            int s1 = __shfl(idx, j0 + 2);
            int s2 = __shfl(idx, j0 + 4);
            int s3 = __shfl(idx, j0 + 6);
            unsigned int v0 = mb32[(size_t)s0 * 32 + c];
            unsigned int v1 = mb32[(size_t)s1 * 32 + c];
            unsigned int v2 = mb32[(size_t)s2 * 32 + c];
            unsigned int v3 = mb32[(size_t)s3 * 32 + c];
            float k0 = mscale[s0];
            float k1 = mscale[s1];
            float k2 = mscale[s2];
            float k3 = mscale[s3];
            a0 = fmaf(fp8dec<0>(v0), k0, a0);
            a1 = fmaf(fp8dec<1>(v0), k0, a1);
            a2 = fmaf(fp8dec<2>(v0), k0, a2);
            a3 = fmaf(fp8dec<3>(v0), k0, a3);
            a0 = fmaf(fp8dec<0>(v1), k1, a0);
            a1 = fmaf(fp8dec<1>(v1), k1, a1);
            a2 = fmaf(fp8dec<2>(v1), k1, a2);
            a3 = fmaf(fp8dec<3>(v1), k1, a3);
            a0 = fmaf(fp8dec<0>(v2), k2, a0);
            a1 = fmaf(fp8dec<1>(v2), k2, a1);
            a2 = fmaf(fp8dec<2>(v2), k2, a2);
            a3 = fmaf(fp8dec<3>(v2), k2, a3);
            a0 = fmaf(fp8dec<0>(v3), k3, a0);
            a1 = fmaf(fp8dec<1>(v3), k3, a1);
            a2 = fmaf(fp8dec<2>(v3), k3, a2);
            a3 = fmaf(fp8dec<3>(v3), k3, a3);
        }
        for (; i < nfull; ++i) {
            int s0 = __shfl(idx, 2 * i + half);
            unsigned int v0 = mb32[(size_t)s0 * 32 + c];
            float k0 = mscale[s0];
            a0 = fmaf(fp8dec<0>(v0), k0, a0);
            a1 = fmaf(fp8dec<1>(v0), k0, a1);
            a2 = fmaf(fp8dec<2>(v0), k0, a2);
            a3 = fmaf(fp8dec<3>(v0), k0, a3);
        }
        if ((cnt & 1) && half == 0) {  // odd tail edge -> half 0
            int s0 = __shfl(idx, cnt - 1);
            unsigned int v0 = mb32[(size_t)s0 * 32 + c];
            float k0 = mscale[s0];
            a0 = fmaf(fp8dec<0>(v0), k0, a0);
            a1 = fmaf(fp8dec<1>(v0), k0, a1);
            a2 = fmaf(fp8dec<2>(v0), k0, a2);
            a3 = fmaf(fp8dec<3>(v0), k0, a3);
        }
    }

    // combine halves (lanes differ in bit 5)
    a0 += __shfl_xor(a0, 32);
    a1 += __shfl_xor(a1, 32);
    a2 += __shfl_xor(a2, 32);
    a3 += __shfl_xor(a3, 32);

    float ir = invr[node];
    unsigned long long hu =
        *(const unsigned long long*)(hb2 + (size_t)node * 64 + 2 * c);
    unsigned int hlo = (unsigned int)hu;
    unsigned int hhi = (unsigned int)(hu >> 32);
    float t0 = a0 * ir + lof(hlo);
    float t1 = a1 * ir + hif(hlo);
    float t2 = a2 * ir + lof(hhi);
    float t3 = a3 * ir + hif(hhi);

    float s = t0 + t1 + t2 + t3;
    float s2 = t0 * t0 + t1 * t1 + t2 * t2 + t3 * t3;
#pragma unroll
    for (int o = 1; o < 32; o <<= 1) {
        s += __shfl_xor(s, o);
        s2 += __shfl_xor(s2, o);
    }
    float mu = s * (1.0f / 128.0f);
    float var = s2 * (1.0f / 128.0f) - mu * mu;
    float rstd = rsqrtf(var + LN_EPS);

    f32x4 sc = *(const f32x4*)(lnsc + 4 * c);
    f32x4 bi = *(const f32x4*)(lnbi + 4 * c);
    float o0 = (t0 - mu) * rstd * sc.x + bi.x;
    float o1 = (t1 - mu) * rstd * sc.y + bi.y;
    float o2 = (t2 - mu) * rstd * sc.z + bi.z;
    float o3 = (t3 - mu) * rstd * sc.w + bi.w;

    if (half == 0) {
        unsigned int p0 = (unsigned int)f2bfbits(o0) | ((unsigned int)f2bfbits(o1) << 16);
        unsigned int p1 = (unsigned int)f2bfbits(o2) | ((unsigned int)f2bfbits(o3) << 16);
        unsigned long long pk = (unsigned long long)p0 | ((unsigned long long)p1 << 32);
        __builtin_nontemporal_store(pk, (unsigned long long*)(hb2 + (size_t)node * 64 + 2 * c));
    }
}

// ---------------- pooling: run-length over sorted graph_ids (bf16 h) ----------------
__global__ void __launch_bounds__(128) pool_kernel(const unsigned short* __restrict__ hb,
                                                   const int* __restrict__ gid,
                                                   float* __restrict__ gsum,
                                                   float* __restrict__ gcnt) {
    int col = threadIdx.x;
    int n0 = blockIdx.x * 64;
    int nend = min(n0 + 64, N_NODES);
    if (n0 >= N_NODES) return;
    int cur = gid[n0];
    float acc = 0.0f, cacc = 0.0f;
    for (int n = n0; n < nend; ++n) {
        int g = gid[n];
        if (g != cur) {
            atomicAdd(&gsum[cur * LATENT + col], acc);
            if (col == 0) atomicAdd(&gcnt[cur], cacc);
            acc = 0.0f;
            cacc = 0.0f;
            cur = g;
        }
        acc += bf2f(hb[(size_t)n * LATENT + col]);
        cacc += 1.0f;
    }
    atomicAdd(&gsum[cur * LATENT + col], acc);
    if (col == 0) atomicAdd(&gcnt[cur], cacc);
}

// ---------------- decoder (dual-dtype output, inline flag) ----------------
__global__ void __launch_bounds__(640) dec_kernel(const float* __restrict__ gsum,
                                                  const float* __restrict__ gcnt,
                                                  const float* __restrict__ dW,
                                                  const float* __restrict__ db,
                                                  void* __restrict__ out,
                                                  const unsigned short* __restrict__ lns_raw) {
    int t = threadIdx.x;
    if (t >= NGRAPH * OUTG) return;
    int g = t / OUTG, o = t % OUTG;
    float inv = 1.0f / fmaxf(gcnt[g], 1.0f);
    float acc = 0.0f;
    for (int k = 0; k < LATENT; k++) acc += gsum[g * LATENT + k] * dW[k * OUTG + o];
    acc = acc * inv + db[o];
    if (lns_raw[0] == 0) ((float*)out)[t] = acc;
    else ((__hip_bfloat16*)out)[t] = __float2bfloat16(acc);
}

__global__ void diag_kernel(float* out, float val) {
    if (threadIdx.x == 0) out[0] = val;
}

extern "C" void kernel_launch(void* const* d_in, const int* in_sizes, int n_in,
                              void* d_out, int out_size, void* d_ws, size_t ws_size,
                              hipStream_t stream) {
    (void)in_sizes; (void)n_in; (void)out_size;
    const int* snd = (const int*)d_in[1];
    const int* rcv = (const int*)d_in[2];
    const int* gid = (const int*)d_in[3];

    if (ws_size < (size_t)WS_REQ_BYTES) {
        diag_kernel<<<1, 64, 0, stream>>>((float*)d_out, 1.0e6f + (float)(ws_size >> 20));
        return;
    }

    float* ws = (float*)d_ws;
    float* gsum = ws + WS_GSUM;
    float* invs = ws + WS_INVS;
    float* invr = ws + WS_INVR;
    float* mb = ws + WS_MB;
    float* lns = ws + WS_LNS;
    float* lnb = ws + WS_LNB;
    float* dW = ws + WS_DW;
    float* db = ws + WS_DB;
    unsigned short* Wf = (unsigned short*)(ws + WS_WF);
    unsigned int* part = (unsigned int*)(ws + WS_PART);
    unsigned short* hb = (unsigned short*)(ws + WS_HB);
    float* mscale = ws + WS_MSCALE;
    unsigned char* mbuf8 = (unsigned char*)(ws + WS_MBUF);
    int* ibase = (int*)(ws + WS_INT);
    int* rowptr = ibase + WI_ROWPTR;
    int* cnts = ibase + WI_CNTS;
    int* offc = ibase + WI_OFFC;
    int* off = ibase + WI_OFF;
    int* csr = ibase + WI_CSR;

    hipMemsetAsync(cnts, 0, 100016 * sizeof(int), stream);
    hipMemsetAsync(gsum, 0, (NGRAPH * LATENT + 64) * sizeof(float), stream);

    prologue_kernel<<<PRO_GRID, 256, 0, stream>>>(
        d_in[0], d_in[4], d_in[5], d_in[6], d_in[7], d_in[8], d_in[9], d_in[10], d_in[11],
        hb, Wf, mb, lns, lnb, dW, db);

    histA_kernel<<<NBLK_P, 256, 0, stream>>>(snd, rcv, cnts, offc);
    scan_kernel<<<1, 1024, 0, stream>>>(offc, off, OFFN);
    partC_kernel<<<NBLK_P, 256, 0, stream>>>(snd, rcv, off, part, cnts, invs);
    buildD_kernel<<<NBUCK, 1024, 0, stream>>>(part, off, rowptr, invr, csr);

    for (int step = 0; step < STEPS; ++step) {
        const unsigned short* Wf0 = Wf + (size_t)(step * 2 + 0) * 16384;
        const unsigned short* Wf1 = Wf + (size_t)(step * 2 + 1) * 16384;
        const float* b0 = mb + (step * 2 + 0) * LATENT;
        const float* b1 = mb + (step * 2 + 1) * LATENT;
        fused_mlp_kernel<<<(N_NODES + 127) / 128, 512, 0, stream>>>(hb, Wf0, b0, Wf1, b1,
                                                                    mbuf8, mscale, invs);
        gather_ln_kernel<<<N_NODES / 4, 256, 0, stream>>>(rowptr, csr, (const unsigned int*)mbuf8,
                                                          mscale, invr, (unsigned int*)hb,
                                                          lns + step * LATENT,
                                                          lnb + step * LATENT);
    }

    pool_kernel<<<(N_NODES + 63) / 64, 128, 0, stream>>>(hb, gid, gsum, ws + WS_GCNT);
    dec_kernel<<<1, 640, 0, stream>>>(gsum, ws + WS_GCNT, dW, db, d_out,
                                      (const unsigned short*)d_in[8]);
}

// Round 13
// 423.000 us; speedup vs baseline: 1.2288x; 1.0933x over previous
//
#include <hip/hip_runtime.h>
#include <hip/hip_bf16.h>

#define N_NODES 100000
#define N_EDGES 1600000
#define NGRAPH 64
#define F_IN 16
#define LATENT 128
#define STEPS 3
#define OUTG 10
#define LN_EPS 1e-6f

// graph-build partition params
#define NBLK_P 256
#define CHUNK (N_EDGES / NBLK_P)  // 6250
#define NBUCK 98                  // ceil(100000/1024)
#define RPB 1024
#define OFFN (NBUCK * NBLK_P)     // 25088

typedef __attribute__((ext_vector_type(8))) short short8;
typedef __attribute__((ext_vector_type(4))) float f32x4;

// ---- ws layout (float indices) ----
#define WS_GSUM 16
#define WS_GCNT (WS_GSUM + NGRAPH * LATENT)
#define WS_INVS (WS_GCNT + 64)
#define WS_INVR (WS_INVS + N_NODES)
#define WS_MB (WS_INVR + N_NODES)
#define WS_LNS (WS_MB + STEPS * 2 * LATENT)
#define WS_LNB (WS_LNS + STEPS * LATENT)
#define WS_DW (WS_LNB + STEPS * LATENT)
#define WS_DB (WS_DW + LATENT * OUTG)
#define WS_WF (WS_DB + 16)                           // 6*16384 bf16 = 49152 floats
#define WS_PART (WS_WF + 49152)                      // u32 x N_EDGES
#define WS_HB (WS_PART + N_EDGES)                    // bf16 h, N*64 floats
#define WS_MSCALE (WS_HB + (size_t)N_NODES * 64)     // N floats
#define WS_MBUF (WS_MSCALE + N_NODES)                // fp8 m, N*128 bytes = N*32 floats
#define WS_INT (WS_MBUF + (size_t)N_NODES * 32)
// ints (offsets within int region)
#define WI_ROWPTR 0
#define WI_OFFC (WI_ROWPTR + 100016)   // 2*OFFN = 50176 counts (rcv plane | snd plane)
#define WI_OFF (WI_OFFC + 50208)       // 2*OFFN+1 offsets
#define WI_CSR 400064
#define WI_PARTS (WI_CSR + N_EDGES)    // u16 x N_EDGES = 800000 ints
#define WI_END (WI_PARTS + 800000)
#define WS_REQ_BYTES (((size_t)WS_INT + WI_END) * 4)

// prologue block ranges
#define PRO_EMBED 6250
#define PRO_WF (PRO_EMBED + 48)
#define PRO_CVT_N 2826
#define PRO_GRID (PRO_WF + 12)

__device__ __forceinline__ float bf2f(unsigned short u) {
    unsigned int i = ((unsigned int)u) << 16;
    float f;
    __builtin_memcpy(&f, &i, 4);
    return f;
}
__device__ __forceinline__ unsigned short f2bfbits(float f) {
    __hip_bfloat16 b = __float2bfloat16(f);
    unsigned short u;
    __builtin_memcpy(&u, &b, 2);
    return u;
}
__device__ __forceinline__ float lof(unsigned int u) {
    unsigned int v = u << 16;
    float f;
    __builtin_memcpy(&f, &v, 4);
    return f;
}
__device__ __forceinline__ float hif(unsigned int u) {
    unsigned int v = u & 0xffff0000u;
    float f;
    __builtin_memcpy(&f, &v, 4);
    return f;
}
__device__ __forceinline__ float rawf(const void* p, size_t i, bool f32m) {
    return f32m ? ((const float*)p)[i] : bf2f(((const unsigned short*)p)[i]);
}

// ---- fp8 e4m3 (OCP) encode/decode, non-negative values only ----
template <int SEL>
__device__ __forceinline__ float fp8dec(unsigned int u) {
#if __has_builtin(__builtin_amdgcn_cvt_f32_fp8)
    return __builtin_amdgcn_cvt_f32_fp8(u, SEL);
#else
    unsigned int b = (u >> (SEL * 8)) & 0xff;
    if (b >= 8) {
        unsigned int fb = (b + 960u) << 20;
        float f;
        __builtin_memcpy(&f, &fb, 4);
        return f;
    }
    return (float)b * (1.0f / 512.0f);
#endif
}
__device__ __forceinline__ unsigned char fp8enc(float v) {  // v in [0, 240]
#if __has_builtin(__builtin_amdgcn_cvt_pk_fp8_f32)
    return (unsigned char)(__builtin_amdgcn_cvt_pk_fp8_f32(v, 0.0f, 0u, false) & 0xff);
#else
    if (v < 0.015625f) return (unsigned char)__float2int_rn(v * 512.0f);
    unsigned int u;
    __builtin_memcpy(&u, &v, 4);
    u += 0x7FFFFu + ((u >> 20) & 1u);
    return (unsigned char)((u >> 20) - 960u);
#endif
}

// ------- prologue: embed (raw inputs) | wfgen (raw mW) | cvt small params -------
__global__ void __launch_bounds__(256) prologue_kernel(
    const void* __restrict__ nodes_raw, const void* __restrict__ eW_raw,
    const void* __restrict__ eb_raw, const void* __restrict__ mW_raw,
    const void* __restrict__ mb_raw, const void* __restrict__ lns_raw,
    const void* __restrict__ lnb_raw, const void* __restrict__ dW_raw,
    const void* __restrict__ db_raw,
    unsigned short* __restrict__ hb, unsigned short* __restrict__ Wf,
    float* __restrict__ mb, float* __restrict__ lns, float* __restrict__ lnb,
    float* __restrict__ dW, float* __restrict__ db) {
    __shared__ float xs[16][F_IN];
    bool f32m = (((const unsigned short*)lns_raw)[0] == 0);
    int bid = blockIdx.x;
    int t = threadIdx.x;
    if (bid < PRO_EMBED) {
        int row0 = bid * 16;
        {
            int r = t >> 4, c = t & 15;
            xs[r][c] = rawf(nodes_raw, (size_t)(row0 + r) * F_IN + c, f32m);
        }
        __syncthreads();
        int col = t & 127;
        int rh = t >> 7;
        float acc[8];
        float bb = rawf(eb_raw, col, f32m);
#pragma unroll
        for (int j = 0; j < 8; j++) acc[j] = bb;
#pragma unroll
        for (int k = 0; k < F_IN; k++) {
            float w = rawf(eW_raw, k * LATENT + col, f32m);
#pragma unroll
            for (int j = 0; j < 8; j++) acc[j] += xs[rh * 8 + j][k] * w;
        }
        int rbase = row0 + rh * 8;
#pragma unroll
        for (int j = 0; j < 8; j++)
            hb[(size_t)(rbase + j) * LATENT + col] = f2bfbits(acc[j]);
    } else if (bid < PRO_WF) {
        int tid = (bid - PRO_EMBED) * 256 + t;
        int L = tid >> 11;
        int rem = tid & 2047;
        int ct = rem >> 8;
        int kt = (rem >> 6) & 3;
        int lane = rem & 63;
        size_t Wsoff = (size_t)L * 16384;
        int col = ct * 16 + (lane & 15);
        int k0 = kt * 32 + ((lane >> 4) << 3);
        short8 v;
#pragma unroll
        for (int i = 0; i < 8; i++)
            v[i] = (short)f2bfbits(rawf(mW_raw, Wsoff + (size_t)(k0 + i) * 128 + col, f32m));
        *(short8*)(Wf + (size_t)tid * 8) = v;
    } else {
        int i = (bid - PRO_WF) * 256 + t;
        if (i >= PRO_CVT_N) return;
        const void* src;
        float* dst;
        int j;
        if (i < 768) { src = mb_raw; dst = mb; j = i; }
        else if (i < 1152) { src = lns_raw; dst = lns; j = i - 768; }
        else if (i < 1536) { src = lnb_raw; dst = lnb; j = i - 1152; }
        else if (i < 2816) { src = dW_raw; dst = dW; j = i - 1536; }
        else { src = db_raw; dst = db; j = i - 2816; }
        dst[j] = rawf(src, j, f32m);
    }
}

// ------- phase A: dual LDS bucket histograms (rcv plane + snd plane), no global atomics -------
__global__ void __launch_bounds__(1024) histA_kernel(const int* __restrict__ snd,
                                                     const int* __restrict__ rcv,
                                                     int* __restrict__ offc) {
    __shared__ int lh[NBUCK];
    __shared__ int lhS[NBUCK];
    for (int i = threadIdx.x; i < NBUCK; i += 1024) {
        lh[i] = 0;
        lhS[i] = 0;
    }
    __syncthreads();
    int base = blockIdx.x * CHUNK;
    for (int i = threadIdx.x; i < CHUNK; i += 1024) {
        int e = base + i;
        atomicAdd(&lhS[snd[e] >> 10], 1);
        atomicAdd(&lh[rcv[e] >> 10], 1);
    }
    __syncthreads();
    for (int i = threadIdx.x; i < NBUCK; i += 1024) {
        offc[i * NBLK_P + blockIdx.x] = lh[i];
        offc[OFFN + i * NBLK_P + blockIdx.x] = lhS[i];
    }
}

// ---------------- exclusive scan over both planes (n = 2*OFFN) ----------------
__global__ void __launch_bounds__(1024) scan_kernel(const int* __restrict__ src,
                                                    int* __restrict__ dst, int n) {
    __shared__ int wsum[16];
    __shared__ int chunk_total;
    int tid = threadIdx.x;
    int lane = tid & 63, wid = tid >> 6;
    int carry = 0;
    for (int base = 0; base < n; base += 4096) {
        int i0 = base + tid * 4;
        int v0 = (i0 + 0 < n) ? src[i0 + 0] : 0;
        int v1 = (i0 + 1 < n) ? src[i0 + 1] : 0;
        int v2 = (i0 + 2 < n) ? src[i0 + 2] : 0;
        int v3 = (i0 + 3 < n) ? src[i0 + 3] : 0;
        int s = v0 + v1 + v2 + v3;
        int sc = s;
#pragma unroll
        for (int off = 1; off < 64; off <<= 1) {
            int t = __shfl_up(sc, off);
            if (lane >= off) sc += t;
        }
        if (lane == 63) wsum[wid] = sc;
        __syncthreads();
        if (wid == 0) {
            int w = (lane < 16) ? wsum[lane] : 0;
#pragma unroll
            for (int off = 1; off < 16; off <<= 1) {
                int t = __shfl_up(w, off);
                if (lane >= off) w += t;
            }
            if (lane < 16) wsum[lane] = w;
            if (lane == 15) chunk_total = w;
        }
        __syncthreads();
        int waveoff = (wid == 0) ? 0 : wsum[wid - 1];
        int p0 = carry + waveoff + (sc - s);
        int p1 = p0 + v0, p2 = p1 + v1, p3 = p2 + v2;
        if (i0 + 0 < n) dst[i0 + 0] = p0;
        if (i0 + 1 < n) dst[i0 + 1] = p1;
        if (i0 + 2 < n) dst[i0 + 2] = p2;
        if (i0 + 3 < n) dst[i0 + 3] = p3;
        carry += chunk_total;
        __syncthreads();
    }
    if (tid == 0) dst[n] = carry;
}

// ------- phase C: dual partition — rcv-keyed u32 part + snd-keyed u16 partS -------
__global__ void __launch_bounds__(1024) partC_kernel(const int* __restrict__ snd,
                                                     const int* __restrict__ rcv,
                                                     const int* __restrict__ off,
                                                     unsigned int* __restrict__ part,
                                                     unsigned short* __restrict__ partS) {
    __shared__ int lcur[NBUCK];
    __shared__ int lcurS[NBUCK];
    for (int i = threadIdx.x; i < NBUCK; i += 1024) {
        lcur[i] = off[i * NBLK_P + blockIdx.x];
        lcurS[i] = off[OFFN + i * NBLK_P + blockIdx.x] - N_EDGES;
    }
    __syncthreads();
    int base = blockIdx.x * CHUNK;
    for (int i = threadIdx.x; i < CHUNK; i += 1024) {
        int e = base + i;
        int r = rcv[e];
        int s = snd[e];
        int pos = atomicAdd(&lcur[r >> 10], 1);
        part[pos] = ((unsigned int)s << 10) | (unsigned int)(r & 1023);
        int posS = atomicAdd(&lcurS[s >> 10], 1);
        partS[posS] = (unsigned short)(s & 1023);
    }
}

// ---------------- phase D: per-bucket CSR build (receiver side) ----------------
__global__ void __launch_bounds__(1024) buildD_kernel(const unsigned int* __restrict__ part,
                                                      const int* __restrict__ off,
                                                      int* __restrict__ rowptr,
                                                      float* __restrict__ invr,
                                                      int* __restrict__ csr) {
    __shared__ int lcnt[RPB];
    __shared__ int lscan[RPB];
    __shared__ int ltmp[RPB];
    int b = blockIdx.x;
    int tid = threadIdx.x;
    int beg = off[b * NBLK_P];
    int end = off[(b + 1) * NBLK_P];
    lcnt[tid] = 0;
    __syncthreads();
    for (int i = beg + tid; i < end; i += 1024) atomicAdd(&lcnt[part[i] & 1023], 1);
    __syncthreads();
    lscan[tid] = lcnt[tid];
    __syncthreads();
    int* sp = lscan;
    int* dp = ltmp;
    for (int st = 1; st < RPB; st <<= 1) {
        dp[tid] = sp[tid] + ((tid >= st) ? sp[tid - st] : 0);
        __syncthreads();
        int* t = sp; sp = dp; dp = t;
    }
    {
        int c = lcnt[tid];
        int cur = beg + sp[tid] - c;
        int gr = b * RPB + tid;
        if (gr < N_NODES) {
            rowptr[gr] = cur;
            invr[gr] = rsqrtf((float)c + 1.0f);
        }
        lcnt[tid] = cur;
    }
    __syncthreads();
    for (int i = beg + tid; i < end; i += 1024) {
        unsigned int e = part[i];
        int pos = atomicAdd(&lcnt[e & 1023], 1);
        csr[pos] = (int)(e >> 10);
    }
    if (b == NBUCK - 1 && tid == 0) rowptr[N_NODES] = N_EDGES;
}

// ------- phase S: per-bucket sender-degree count -> invs (LDS only) -------
__global__ void __launch_bounds__(1024) buildS_kernel(const unsigned short* __restrict__ partS,
                                                      const int* __restrict__ off,
                                                      float* __restrict__ invs) {
    __shared__ int lcnt[RPB];
    int b = blockIdx.x;
    int tid = threadIdx.x;
    int beg = off[OFFN + b * NBLK_P] - N_EDGES;
    int end = off[OFFN + (b + 1) * NBLK_P] - N_EDGES;
    lcnt[tid] = 0;
    __syncthreads();
    for (int i = beg + tid; i < end; i += 1024) atomicAdd(&lcnt[partS[i]], 1);
    __syncthreads();
    int gr = b * RPB + tid;
    if (gr < N_NODES) invs[gr] = rsqrtf((float)lcnt[tid] + 1.0f);
}

// ------- fused 2-layer MLP: 512 thr / 8 waves / 128 rows; fp8 output + per-row scale -------
#define LPAD 136
__global__ void __launch_bounds__(512) fused_mlp_kernel(const unsigned short* __restrict__ xb,
                                                        const unsigned short* __restrict__ Wf0,
                                                        const float* __restrict__ b0,
                                                        const unsigned short* __restrict__ Wf1,
                                                        const float* __restrict__ b1,
                                                        unsigned char* __restrict__ yb8,
                                                        float* __restrict__ mscale,
                                                        const float* __restrict__ scale) {
    __shared__ unsigned short ls[8][16][LPAD];
    int lane = threadIdx.x & 63;
    int wid = threadIdx.x >> 6;
    int rows0 = blockIdx.x * 128 + wid * 16;
    int l15 = lane & 15;
    int l4 = lane >> 4;

    f32x4 acc[8];
#pragma unroll
    for (int ct = 0; ct < 8; ct++) {
        float bb = b0[ct * 16 + l15];
        acc[ct] = (f32x4){bb, bb, bb, bb};
    }
    {
        int arow_c = min(rows0 + l15, N_NODES - 1);
        const short8* xrow = (const short8*)(xb + (size_t)arow_c * LATENT);
#pragma unroll
        for (int kt = 0; kt < 4; kt++) {
            short8 a = xrow[kt * 4 + l4];
#pragma unroll
            for (int ct = 0; ct < 8; ct++) {
                short8 bf = *(const short8*)(Wf0 + (size_t)(((ct * 4 + kt) * 64 + lane)) * 8);
                acc[ct] = __builtin_amdgcn_mfma_f32_16x16x32_bf16(a, bf, acc[ct], 0, 0, 0);
            }
        }
    }
    {
        int lrow = l4 << 2;
#pragma unroll
        for (int ct = 0; ct < 8; ct++)
#pragma unroll
            for (int j = 0; j < 4; j++)
                ls[wid][lrow + j][ct * 16 + l15] = f2bfbits(fmaxf(acc[ct][j], 0.0f));
    }
    __syncthreads();

#pragma unroll
    for (int ct = 0; ct < 8; ct++) {
        float bb = b1[ct * 16 + l15];
        acc[ct] = (f32x4){bb, bb, bb, bb};
    }
#pragma unroll
    for (int kt = 0; kt < 4; kt++) {
        short8 a = *(const short8*)&ls[wid][l15][kt * 32 + (l4 << 3)];
#pragma unroll
        for (int ct = 0; ct < 8; ct++) {
            short8 bf = *(const short8*)(Wf1 + (size_t)(((ct * 4 + kt) * 64 + lane)) * 8);
            acc[ct] = __builtin_amdgcn_mfma_f32_16x16x32_bf16(a, bf, acc[ct], 0, 0, 0);
        }
    }
    __syncthreads();
    unsigned char* lsb = (unsigned char*)&ls[wid][0][0];
    {
        int lrow = l4 << 2;
#pragma unroll
        for (int j = 0; j < 4; j++) {
            int rr = rows0 + lrow + j;
            int r = min(rr, N_NODES - 1);
            float sc = scale[r];
            float v[8];
            float mx = 0.0f;
#pragma unroll
            for (int ct = 0; ct < 8; ct++) {
                v[ct] = fmaxf(acc[ct][j], 0.0f) * sc;
                mx = fmaxf(mx, v[ct]);
            }
#pragma unroll
            for (int off = 1; off < 16; off <<= 1) mx = fmaxf(mx, __shfl_xor(mx, off));
            float qm = (mx > 0.0f) ? (240.0f / mx) : 0.0f;
            if (l15 == 0 && rr < N_NODES) mscale[rr] = mx * (1.0f / 240.0f);
#pragma unroll
            for (int ct = 0; ct < 8; ct++)
                lsb[(lrow + j) * 136 + ct * 16 + l15] = fp8enc(v[ct] * qm);
        }
    }
    __syncthreads();
#pragma unroll
    for (int p = 0; p < 4; p++) {
        int row = p * 4 + l4;
        unsigned long long v8;
        __builtin_memcpy(&v8, &lsb[row * 136 + l15 * 8], 8);
        int r = rows0 + row;
        if (r < N_NODES) *(unsigned long long*)(yb8 + (size_t)r * 128 + l15 * 8) = v8;
    }
}

// ------- gather v3: 2 edges per VMEM inst (two 32-lane halves), fp8 rows, + skip + LN -------
__global__ void __launch_bounds__(256) gather_ln_kernel(const int* __restrict__ rowptr,
                                                        const int* __restrict__ csr,
                                                        const unsigned int* __restrict__ mb32,
                                                        const float* __restrict__ mscale,
                                                        const float* __restrict__ invr,
                                                        unsigned int* __restrict__ hb2,
                                                        const float* __restrict__ lnsc,
                                                        const float* __restrict__ lnbi) {
    int node = (blockIdx.x * 256 + threadIdx.x) >> 6;
    int lane = threadIdx.x & 63;
    if (node >= N_NODES) return;
    int half = lane >> 5;  // 0/1: which edge of each pair
    int c = lane & 31;     // u32 column: feature cols 4c..4c+3

    int beg = rowptr[node];
    int end = rowptr[node + 1];

    float a0 = 0.0f, a1 = 0.0f, a2 = 0.0f, a3 = 0.0f;
    if (half == 0) {  // self edge (m already *inv_s)
        unsigned int v = mb32[(size_t)node * 32 + c];
        float k = mscale[node];
        a0 = fp8dec<0>(v) * k;
        a1 = fp8dec<1>(v) * k;
        a2 = fp8dec<2>(v) * k;
        a3 = fp8dec<3>(v) * k;
    }

    for (int base = beg; base < end; base += 64) {
        int cnt = min(64, end - base);
        int idx = (lane < cnt) ? __builtin_nontemporal_load(csr + base + lane) : 0;
        int nfull = cnt >> 1;
        int i = 0;
        for (; i + 3 < nfull; i += 4) {
            int j0 = 2 * i + half;
            int s0 = __shfl(idx, j0);
            int s1 = __shfl(idx, j0 + 2);
            int s2 = __shfl(idx, j0 + 4);
            int s3 = __shfl(idx, j0 + 6);
            unsigned int v0 = mb32[(size_t)s0 * 32 + c];
            unsigned int v1 = mb32[(size_t)s1 * 32 + c];
            unsigned int v2 = mb32[(size_t)s2 * 32 + c];
            unsigned int v3 = mb32[(size_t)s3 * 32 + c];
            float k0 = mscale[s0];
            float k1 = mscale[s1];
            float k2 = mscale[s2];
            float k3 = mscale[s3];
            a0 = fmaf(fp8dec<0>(v0), k0, a0);
            a1 = fmaf(fp8dec<1>(v0), k0, a1);
            a2 = fmaf(fp8dec<2>(v0), k0, a2);
            a3 = fmaf(fp8dec<3>(v0), k0, a3);
            a0 = fmaf(fp8dec<0>(v1), k1, a0);
            a1 = fmaf(fp8dec<1>(v1), k1, a1);
            a2 = fmaf(fp8dec<2>(v1), k1, a2);
            a3 = fmaf(fp8dec<3>(v1), k1, a3);
            a0 = fmaf(fp8dec<0>(v2), k2, a0);
            a1 = fmaf(fp8dec<1>(v2), k2, a1);
            a2 = fmaf(fp8dec<2>(v2), k2, a2);
            a3 = fmaf(fp8dec<3>(v2), k2, a3);
            a0 = fmaf(fp8dec<0>(v3), k3, a0);
            a1 = fmaf(fp8dec<1>(v3), k3, a1);
            a2 = fmaf(fp8dec<2>(v3), k3, a2);
            a3 = fmaf(fp8dec<3>(v3), k3, a3);
        }
        for (; i < nfull; ++i) {
            int s0 = __shfl(idx, 2 * i + half);
            unsigned int v0 = mb32[(size_t)s0 * 32 + c];
            float k0 = mscale[s0];
            a0 = fmaf(fp8dec<0>(v0), k0, a0);
            a1 = fmaf(fp8dec<1>(v0), k0, a1);
            a2 = fmaf(fp8dec<2>(v0), k0, a2);
            a3 = fmaf(fp8dec<3>(v0), k0, a3);
        }
        if ((cnt & 1) && half == 0) {
            int s0 = __shfl(idx, cnt - 1);
            unsigned int v0 = mb32[(size_t)s0 * 32 + c];
            float k0 = mscale[s0];
            a0 = fmaf(fp8dec<0>(v0), k0, a0);
            a1 = fmaf(fp8dec<1>(v0), k0, a1);
            a2 = fmaf(fp8dec<2>(v0), k0, a2);
            a3 = fmaf(fp8dec<3>(v0), k0, a3);
        }
    }

    a0 += __shfl_xor(a0, 32);
    a1 += __shfl_xor(a1, 32);
    a2 += __shfl_xor(a2, 32);
    a3 += __shfl_xor(a3, 32);

    float ir = invr[node];
    unsigned long long hu =
        *(const unsigned long long*)(hb2 + (size_t)node * 64 + 2 * c);
    unsigned int hlo = (unsigned int)hu;
    unsigned int hhi = (unsigned int)(hu >> 32);
    float t0 = a0 * ir + lof(hlo);
    float t1 = a1 * ir + hif(hlo);
    float t2 = a2 * ir + lof(hhi);
    float t3 = a3 * ir + hif(hhi);

    float s = t0 + t1 + t2 + t3;
    float s2 = t0 * t0 + t1 * t1 + t2 * t2 + t3 * t3;
#pragma unroll
    for (int o = 1; o < 32; o <<= 1) {
        s += __shfl_xor(s, o);
        s2 += __shfl_xor(s2, o);
    }
    float mu = s * (1.0f / 128.0f);
    float var = s2 * (1.0f / 128.0f) - mu * mu;
    float rstd = rsqrtf(var + LN_EPS);

    f32x4 sc = *(const f32x4*)(lnsc + 4 * c);
    f32x4 bi = *(const f32x4*)(lnbi + 4 * c);
    float o0 = (t0 - mu) * rstd * sc.x + bi.x;
    float o1 = (t1 - mu) * rstd * sc.y + bi.y;
    float o2 = (t2 - mu) * rstd * sc.z + bi.z;
    float o3 = (t3 - mu) * rstd * sc.w + bi.w;

    if (half == 0) {
        unsigned int p0 = (unsigned int)f2bfbits(o0) | ((unsigned int)f2bfbits(o1) << 16);
        unsigned int p1 = (unsigned int)f2bfbits(o2) | ((unsigned int)f2bfbits(o3) << 16);
        unsigned long long pk = (unsigned long long)p0 | ((unsigned long long)p1 << 32);
        __builtin_nontemporal_store(pk, (unsigned long long*)(hb2 + (size_t)node * 64 + 2 * c));
    }
}

// ---------------- pooling: run-length over sorted graph_ids (bf16 h) ----------------
__global__ void __launch_bounds__(128) pool_kernel(const unsigned short* __restrict__ hb,
                                                   const int* __restrict__ gid,
                                                   float* __restrict__ gsum,
                                                   float* __restrict__ gcnt) {
    int col = threadIdx.x;
    int n0 = blockIdx.x * 64;
    int nend = min(n0 + 64, N_NODES);
    if (n0 >= N_NODES) return;
    int cur = gid[n0];
    float acc = 0.0f, cacc = 0.0f;
    for (int n = n0; n < nend; ++n) {
        int g = gid[n];
        if (g != cur) {
            atomicAdd(&gsum[cur * LATENT + col], acc);
            if (col == 0) atomicAdd(&gcnt[cur], cacc);
            acc = 0.0f;
            cacc = 0.0f;
            cur = g;
        }
        acc += bf2f(hb[(size_t)n * LATENT + col]);
        cacc += 1.0f;
    }
    atomicAdd(&gsum[cur * LATENT + col], acc);
    if (col == 0) atomicAdd(&gcnt[cur], cacc);
}

// ---------------- decoder (dual-dtype output, inline flag) ----------------
__global__ void __launch_bounds__(640) dec_kernel(const float* __restrict__ gsum,
                                                  const float* __restrict__ gcnt,
                                                  const float* __restrict__ dW,
                                                  const float* __restrict__ db,
                                                  void* __restrict__ out,
                                                  const unsigned short* __restrict__ lns_raw) {
    int t = threadIdx.x;
    if (t >= NGRAPH * OUTG) return;
    int g = t / OUTG, o = t % OUTG;
    float inv = 1.0f / fmaxf(gcnt[g], 1.0f);
    float acc = 0.0f;
    for (int k = 0; k < LATENT; k++) acc += gsum[g * LATENT + k] * dW[k * OUTG + o];
    acc = acc * inv + db[o];
    if (lns_raw[0] == 0) ((float*)out)[t] = acc;
    else ((__hip_bfloat16*)out)[t] = __float2bfloat16(acc);
}

__global__ void diag_kernel(float* out, float val) {
    if (threadIdx.x == 0) out[0] = val;
}

extern "C" void kernel_launch(void* const* d_in, const int* in_sizes, int n_in,
                              void* d_out, int out_size, void* d_ws, size_t ws_size,
                              hipStream_t stream) {
    (void)in_sizes; (void)n_in; (void)out_size;
    const int* snd = (const int*)d_in[1];
    const int* rcv = (const int*)d_in[2];
    const int* gid = (const int*)d_in[3];

    if (ws_size < (size_t)WS_REQ_BYTES) {
        diag_kernel<<<1, 64, 0, stream>>>((float*)d_out, 1.0e6f + (float)(ws_size >> 20));
        return;
    }

    float* ws = (float*)d_ws;
    float* gsum = ws + WS_GSUM;
    float* invs = ws + WS_INVS;
    float* invr = ws + WS_INVR;
    float* mb = ws + WS_MB;
    float* lns = ws + WS_LNS;
    float* lnb = ws + WS_LNB;
    float* dW = ws + WS_DW;
    float* db = ws + WS_DB;
    unsigned short* Wf = (unsigned short*)(ws + WS_WF);
    unsigned int* part = (unsigned int*)(ws + WS_PART);
    unsigned short* hb = (unsigned short*)(ws + WS_HB);
    float* mscale = ws + WS_MSCALE;
    unsigned char* mbuf8 = (unsigned char*)(ws + WS_MBUF);
    int* ibase = (int*)(ws + WS_INT);
    int* rowptr = ibase + WI_ROWPTR;
    int* offc = ibase + WI_OFFC;
    int* off = ibase + WI_OFF;
    int* csr = ibase + WI_CSR;
    unsigned short* partS = (unsigned short*)(ibase + WI_PARTS);

    hipMemsetAsync(gsum, 0, (NGRAPH * LATENT + 64) * sizeof(float), stream);

    prologue_kernel<<<PRO_GRID, 256, 0, stream>>>(
        d_in[0], d_in[4], d_in[5], d_in[6], d_in[7], d_in[8], d_in[9], d_in[10], d_in[11],
        hb, Wf, mb, lns, lnb, dW, db);

    histA_kernel<<<NBLK_P, 1024, 0, stream>>>(snd, rcv, offc);
    scan_kernel<<<1, 1024, 0, stream>>>(offc, off, 2 * OFFN);
    partC_kernel<<<NBLK_P, 1024, 0, stream>>>(snd, rcv, off, part, partS);
    buildD_kernel<<<NBUCK, 1024, 0, stream>>>(part, off, rowptr, invr, csr);
    buildS_kernel<<<NBUCK, 1024, 0, stream>>>(partS, off, invs);

    for (int step = 0; step < STEPS; ++step) {
        const unsigned short* Wf0 = Wf + (size_t)(step * 2 + 0) * 16384;
        const unsigned short* Wf1 = Wf + (size_t)(step * 2 + 1) * 16384;
        const float* b0 = mb + (step * 2 + 0) * LATENT;
        const float* b1 = mb + (step * 2 + 1) * LATENT;
        fused_mlp_kernel<<<(N_NODES + 127) / 128, 512, 0, stream>>>(hb, Wf0, b0, Wf1, b1,
                                                                    mbuf8, mscale, invs);
        gather_ln_kernel<<<N_NODES / 4, 256, 0, stream>>>(rowptr, csr, (const unsigned int*)mbuf8,
                                                          mscale, invr, (unsigned int*)hb,
                                                          lns + step * LATENT,
                                                          lnb + step * LATENT);
    }

    pool_kernel<<<(N_NODES + 63) / 64, 128, 0, stream>>>(hb, gid, gsum, ws + WS_GCNT);
    dec_kernel<<<1, 640, 0, stream>>>(gsum, ws + WS_GCNT, dW, db, d_out,
                                      (const unsigned short*)d_in[8]);
}

// Round 14
// 422.647 us; speedup vs baseline: 1.2298x; 1.0008x over previous
//
#include <hip/hip_runtime.h>
#include <hip/hip_bf16.h>

#define N_NODES 100000
#define N_EDGES 1600000
#define NGRAPH 64
#define F_IN 16
#define LATENT 128
#define STEPS 3
#define OUTG 10
#define LN_EPS 1e-6f

// graph-build partition params
#define NBLK_P 256
#define CHUNK (N_EDGES / NBLK_P)  // 6250
#define NBUCK 98                  // ceil(100000/1024)
#define RPB 1024
#define OFFN (NBUCK * NBLK_P)     // 25088

typedef __attribute__((ext_vector_type(8))) short short8;
typedef __attribute__((ext_vector_type(4))) float f32x4;
typedef __attribute__((ext_vector_type(2))) float f32x2;

// ---- ws layout (float indices) ----
#define WS_GSUM 16
#define WS_GCNT (WS_GSUM + NGRAPH * LATENT)
#define WS_INVS (WS_GCNT + 64)
#define WS_INVR (WS_INVS + N_NODES)
#define WS_MB (WS_INVR + N_NODES)
#define WS_LNS (WS_MB + STEPS * 2 * LATENT)
#define WS_LNB (WS_LNS + STEPS * LATENT)
#define WS_DW (WS_LNB + STEPS * LATENT)
#define WS_DB (WS_DW + LATENT * OUTG)
#define WS_WF (WS_DB + 16)                           // 6*16384 bf16 = 49152 floats
#define WS_PART (WS_WF + 49152)                      // u32 x N_EDGES
#define WS_HB (WS_PART + N_EDGES)                    // bf16 h, N*64 floats
#define WS_MSCALE (WS_HB + (size_t)N_NODES * 64)     // N floats
#define WS_MBUF (WS_MSCALE + N_NODES)                // fp8 m, N*128 bytes = N*32 floats
#define WS_INT (WS_MBUF + (size_t)N_NODES * 32)
// ints (offsets within int region)
#define WI_ROWPTR 0
#define WI_OFFC (WI_ROWPTR + 100016)   // 2*OFFN = 50176 counts (rcv plane | snd plane)
#define WI_OFF (WI_OFFC + 50208)       // 2*OFFN+1 offsets
#define WI_CSR 400064
#define WI_PARTS (WI_CSR + N_EDGES)    // u16 x N_EDGES = 800000 ints
#define WI_END (WI_PARTS + 800000)
#define WS_REQ_BYTES (((size_t)WS_INT + WI_END) * 4)

// prologue block ranges
#define PRO_EMBED 6250
#define PRO_WF (PRO_EMBED + 48)
#define PRO_CVT_N 2826
#define PRO_GRID (PRO_WF + 12)

__device__ __forceinline__ float bf2f(unsigned short u) {
    unsigned int i = ((unsigned int)u) << 16;
    float f;
    __builtin_memcpy(&f, &i, 4);
    return f;
}
__device__ __forceinline__ unsigned short f2bfbits(float f) {
    __hip_bfloat16 b = __float2bfloat16(f);
    unsigned short u;
    __builtin_memcpy(&u, &b, 2);
    return u;
}
__device__ __forceinline__ float lof(unsigned int u) {
    unsigned int v = u << 16;
    float f;
    __builtin_memcpy(&f, &v, 4);
    return f;
}
__device__ __forceinline__ float hif(unsigned int u) {
    unsigned int v = u & 0xffff0000u;
    float f;
    __builtin_memcpy(&f, &v, 4);
    return f;
}
__device__ __forceinline__ float rawf(const void* p, size_t i, bool f32m) {
    return f32m ? ((const float*)p)[i] : bf2f(((const unsigned short*)p)[i]);
}

// ---- fp8 e4m3 (OCP) encode/decode, non-negative values only ----
template <int SEL>
__device__ __forceinline__ float fp8dec(unsigned int u) {
    unsigned int b = (u >> (SEL * 8)) & 0xff;
    if (b >= 8) {
        unsigned int fb = (b + 960u) << 20;
        float f;
        __builtin_memcpy(&f, &fb, 4);
        return f;
    }
    return (float)b * (1.0f / 512.0f);
}
// packed: bytes (0,1) for word=false, (2,3) for word=true
template <bool WORD>
__device__ __forceinline__ f32x2 fp8pk(unsigned int u) {
#if __has_builtin(__builtin_amdgcn_cvt_pk_f32_fp8)
    return __builtin_amdgcn_cvt_pk_f32_fp8(u, WORD);
#else
    f32x2 r;
    if (WORD) {
        r.x = fp8dec<2>(u);
        r.y = fp8dec<3>(u);
    } else {
        r.x = fp8dec<0>(u);
        r.y = fp8dec<1>(u);
    }
    return r;
#endif
}
__device__ __forceinline__ unsigned char fp8enc(float v) {  // v in [0, 240]
#if __has_builtin(__builtin_amdgcn_cvt_pk_fp8_f32)
    return (unsigned char)(__builtin_amdgcn_cvt_pk_fp8_f32(v, 0.0f, 0u, false) & 0xff);
#else
    if (v < 0.015625f) return (unsigned char)__float2int_rn(v * 512.0f);
    unsigned int u;
    __builtin_memcpy(&u, &v, 4);
    u += 0x7FFFFu + ((u >> 20) & 1u);
    return (unsigned char)((u >> 20) - 960u);
#endif
}

// ------- prologue: embed (raw inputs) | wfgen (raw mW) | cvt small params -------
__global__ void __launch_bounds__(256) prologue_kernel(
    const void* __restrict__ nodes_raw, const void* __restrict__ eW_raw,
    const void* __restrict__ eb_raw, const void* __restrict__ mW_raw,
    const void* __restrict__ mb_raw, const void* __restrict__ lns_raw,
    const void* __restrict__ lnb_raw, const void* __restrict__ dW_raw,
    const void* __restrict__ db_raw,
    unsigned short* __restrict__ hb, unsigned short* __restrict__ Wf,
    float* __restrict__ mb, float* __restrict__ lns, float* __restrict__ lnb,
    float* __restrict__ dW, float* __restrict__ db) {
    __shared__ float xs[16][F_IN];
    bool f32m = (((const unsigned short*)lns_raw)[0] == 0);
    int bid = blockIdx.x;
    int t = threadIdx.x;
    if (bid < PRO_EMBED) {
        int row0 = bid * 16;
        {
            int r = t >> 4, c = t & 15;
            xs[r][c] = rawf(nodes_raw, (size_t)(row0 + r) * F_IN + c, f32m);
        }
        __syncthreads();
        int col = t & 127;
        int rh = t >> 7;
        float acc[8];
        float bb = rawf(eb_raw, col, f32m);
#pragma unroll
        for (int j = 0; j < 8; j++) acc[j] = bb;
#pragma unroll
        for (int k = 0; k < F_IN; k++) {
            float w = rawf(eW_raw, k * LATENT + col, f32m);
#pragma unroll
            for (int j = 0; j < 8; j++) acc[j] += xs[rh * 8 + j][k] * w;
        }
        int rbase = row0 + rh * 8;
#pragma unroll
        for (int j = 0; j < 8; j++)
            hb[(size_t)(rbase + j) * LATENT + col] = f2bfbits(acc[j]);
    } else if (bid < PRO_WF) {
        int tid = (bid - PRO_EMBED) * 256 + t;
        int L = tid >> 11;
        int rem = tid & 2047;
        int ct = rem >> 8;
        int kt = (rem >> 6) & 3;
        int lane = rem & 63;
        size_t Wsoff = (size_t)L * 16384;
        int col = ct * 16 + (lane & 15);
        int k0 = kt * 32 + ((lane >> 4) << 3);
        short8 v;
#pragma unroll
        for (int i = 0; i < 8; i++)
            v[i] = (short)f2bfbits(rawf(mW_raw, Wsoff + (size_t)(k0 + i) * 128 + col, f32m));
        *(short8*)(Wf + (size_t)tid * 8) = v;
    } else {
        int i = (bid - PRO_WF) * 256 + t;
        if (i >= PRO_CVT_N) return;
        const void* src;
        float* dst;
        int j;
        if (i < 768) { src = mb_raw; dst = mb; j = i; }
        else if (i < 1152) { src = lns_raw; dst = lns; j = i - 768; }
        else if (i < 1536) { src = lnb_raw; dst = lnb; j = i - 1152; }
        else if (i < 2816) { src = dW_raw; dst = dW; j = i - 1536; }
        else { src = db_raw; dst = db; j = i - 2816; }
        dst[j] = rawf(src, j, f32m);
    }
}

// ------- phase A: dual LDS bucket histograms (rcv plane + snd plane) -------
__global__ void __launch_bounds__(1024) histA_kernel(const int* __restrict__ snd,
                                                     const int* __restrict__ rcv,
                                                     int* __restrict__ offc) {
    __shared__ int lh[NBUCK];
    __shared__ int lhS[NBUCK];
    for (int i = threadIdx.x; i < NBUCK; i += 1024) {
        lh[i] = 0;
        lhS[i] = 0;
    }
    __syncthreads();
    int base = blockIdx.x * CHUNK;
    for (int i = threadIdx.x; i < CHUNK; i += 1024) {
        int e = base + i;
        atomicAdd(&lhS[snd[e] >> 10], 1);
        atomicAdd(&lh[rcv[e] >> 10], 1);
    }
    __syncthreads();
    for (int i = threadIdx.x; i < NBUCK; i += 1024) {
        offc[i * NBLK_P + blockIdx.x] = lh[i];
        offc[OFFN + i * NBLK_P + blockIdx.x] = lhS[i];
    }
}

// ---------------- exclusive scan over both planes (n = 2*OFFN) ----------------
__global__ void __launch_bounds__(1024) scan_kernel(const int* __restrict__ src,
                                                    int* __restrict__ dst, int n) {
    __shared__ int wsum[16];
    __shared__ int chunk_total;
    int tid = threadIdx.x;
    int lane = tid & 63, wid = tid >> 6;
    int carry = 0;
    for (int base = 0; base < n; base += 4096) {
        int i0 = base + tid * 4;
        int v0 = (i0 + 0 < n) ? src[i0 + 0] : 0;
        int v1 = (i0 + 1 < n) ? src[i0 + 1] : 0;
        int v2 = (i0 + 2 < n) ? src[i0 + 2] : 0;
        int v3 = (i0 + 3 < n) ? src[i0 + 3] : 0;
        int s = v0 + v1 + v2 + v3;
        int sc = s;
#pragma unroll
        for (int off = 1; off < 64; off <<= 1) {
            int t = __shfl_up(sc, off);
            if (lane >= off) sc += t;
        }
        if (lane == 63) wsum[wid] = sc;
        __syncthreads();
        if (wid == 0) {
            int w = (lane < 16) ? wsum[lane] : 0;
#pragma unroll
            for (int off = 1; off < 16; off <<= 1) {
                int t = __shfl_up(w, off);
                if (lane >= off) w += t;
            }
            if (lane < 16) wsum[lane] = w;
            if (lane == 15) chunk_total = w;
        }
        __syncthreads();
        int waveoff = (wid == 0) ? 0 : wsum[wid - 1];
        int p0 = carry + waveoff + (sc - s);
        int p1 = p0 + v0, p2 = p1 + v1, p3 = p2 + v2;
        if (i0 + 0 < n) dst[i0 + 0] = p0;
        if (i0 + 1 < n) dst[i0 + 1] = p1;
        if (i0 + 2 < n) dst[i0 + 2] = p2;
        if (i0 + 3 < n) dst[i0 + 3] = p3;
        carry += chunk_total;
        __syncthreads();
    }
    if (tid == 0) dst[n] = carry;
}

// ------- phase C: dual partition — rcv-keyed u32 part + snd-keyed u16 partS -------
__global__ void __launch_bounds__(1024) partC_kernel(const int* __restrict__ snd,
                                                     const int* __restrict__ rcv,
                                                     const int* __restrict__ off,
                                                     unsigned int* __restrict__ part,
                                                     unsigned short* __restrict__ partS) {
    __shared__ int lcur[NBUCK];
    __shared__ int lcurS[NBUCK];
    for (int i = threadIdx.x; i < NBUCK; i += 1024) {
        lcur[i] = off[i * NBLK_P + blockIdx.x];
        lcurS[i] = off[OFFN + i * NBLK_P + blockIdx.x] - N_EDGES;
    }
    __syncthreads();
    int base = blockIdx.x * CHUNK;
    for (int i = threadIdx.x; i < CHUNK; i += 1024) {
        int e = base + i;
        int r = rcv[e];
        int s = snd[e];
        int pos = atomicAdd(&lcur[r >> 10], 1);
        part[pos] = ((unsigned int)s << 10) | (unsigned int)(r & 1023);
        int posS = atomicAdd(&lcurS[s >> 10], 1);
        partS[posS] = (unsigned short)(s & 1023);
    }
}

// ---------------- phase D: per-bucket CSR build (receiver side) ----------------
__global__ void __launch_bounds__(1024) buildD_kernel(const unsigned int* __restrict__ part,
                                                      const int* __restrict__ off,
                                                      int* __restrict__ rowptr,
                                                      float* __restrict__ invr,
                                                      int* __restrict__ csr) {
    __shared__ int lcnt[RPB];
    __shared__ int lscan[RPB];
    __shared__ int ltmp[RPB];
    int b = blockIdx.x;
    int tid = threadIdx.x;
    int beg = off[b * NBLK_P];
    int end = off[(b + 1) * NBLK_P];
    lcnt[tid] = 0;
    __syncthreads();
    for (int i = beg + tid; i < end; i += 1024) atomicAdd(&lcnt[part[i] & 1023], 1);
    __syncthreads();
    lscan[tid] = lcnt[tid];
    __syncthreads();
    int* sp = lscan;
    int* dp = ltmp;
    for (int st = 1; st < RPB; st <<= 1) {
        dp[tid] = sp[tid] + ((tid >= st) ? sp[tid - st] : 0);
        __syncthreads();
        int* t = sp; sp = dp; dp = t;
    }
    {
        int c = lcnt[tid];
        int cur = beg + sp[tid] - c;
        int gr = b * RPB + tid;
        if (gr < N_NODES) {
            rowptr[gr] = cur;
            invr[gr] = rsqrtf((float)c + 1.0f);
        }
        lcnt[tid] = cur;
    }
    __syncthreads();
    for (int i = beg + tid; i < end; i += 1024) {
        unsigned int e = part[i];
        int pos = atomicAdd(&lcnt[e & 1023], 1);
        csr[pos] = (int)(e >> 10);
    }
    if (b == NBUCK - 1 && tid == 0) rowptr[N_NODES] = N_EDGES;
}

// ------- phase S: per-bucket sender-degree count -> invs (LDS only) -------
__global__ void __launch_bounds__(1024) buildS_kernel(const unsigned short* __restrict__ partS,
                                                      const int* __restrict__ off,
                                                      float* __restrict__ invs) {
    __shared__ int lcnt[RPB];
    int b = blockIdx.x;
    int tid = threadIdx.x;
    int beg = off[OFFN + b * NBLK_P] - N_EDGES;
    int end = off[OFFN + (b + 1) * NBLK_P] - N_EDGES;
    lcnt[tid] = 0;
    __syncthreads();
    for (int i = beg + tid; i < end; i += 1024) atomicAdd(&lcnt[partS[i]], 1);
    __syncthreads();
    int gr = b * RPB + tid;
    if (gr < N_NODES) invs[gr] = rsqrtf((float)lcnt[tid] + 1.0f);
}

// ------- fused 2-layer MLP: 512 thr / 8 waves / 128 rows; fp8 output + per-row scale -------
#define LPAD 136
__global__ void __launch_bounds__(512) fused_mlp_kernel(const unsigned short* __restrict__ xb,
                                                        const unsigned short* __restrict__ Wf0,
                                                        const float* __restrict__ b0,
                                                        const unsigned short* __restrict__ Wf1,
                                                        const float* __restrict__ b1,
                                                        unsigned char* __restrict__ yb8,
                                                        float* __restrict__ mscale,
                                                        const float* __restrict__ scale) {
    __shared__ unsigned short ls[8][16][LPAD];
    int lane = threadIdx.x & 63;
    int wid = threadIdx.x >> 6;
    int rows0 = blockIdx.x * 128 + wid * 16;
    int l15 = lane & 15;
    int l4 = lane >> 4;

    f32x4 acc[8];
#pragma unroll
    for (int ct = 0; ct < 8; ct++) {
        float bb = b0[ct * 16 + l15];
        acc[ct] = (f32x4){bb, bb, bb, bb};
    }
    {
        int arow_c = min(rows0 + l15, N_NODES - 1);
        const short8* xrow = (const short8*)(xb + (size_t)arow_c * LATENT);
#pragma unroll
        for (int kt = 0; kt < 4; kt++) {
            short8 a = xrow[kt * 4 + l4];
#pragma unroll
            for (int ct = 0; ct < 8; ct++) {
                short8 bf = *(const short8*)(Wf0 + (size_t)(((ct * 4 + kt) * 64 + lane)) * 8);
                acc[ct] = __builtin_amdgcn_mfma_f32_16x16x32_bf16(a, bf, acc[ct], 0, 0, 0);
            }
        }
    }
    {
        int lrow = l4 << 2;
#pragma unroll
        for (int ct = 0; ct < 8; ct++)
#pragma unroll
            for (int j = 0; j < 4; j++)
                ls[wid][lrow + j][ct * 16 + l15] = f2bfbits(fmaxf(acc[ct][j], 0.0f));
    }
    __syncthreads();

#pragma unroll
    for (int ct = 0; ct < 8; ct++) {
        float bb = b1[ct * 16 + l15];
        acc[ct] = (f32x4){bb, bb, bb, bb};
    }
#pragma unroll
    for (int kt = 0; kt < 4; kt++) {
        short8 a = *(const short8*)&ls[wid][l15][kt * 32 + (l4 << 3)];
#pragma unroll
        for (int ct = 0; ct < 8; ct++) {
            short8 bf = *(const short8*)(Wf1 + (size_t)(((ct * 4 + kt) * 64 + lane)) * 8);
            acc[ct] = __builtin_amdgcn_mfma_f32_16x16x32_bf16(a, bf, acc[ct], 0, 0, 0);
        }
    }
    __syncthreads();
    unsigned char* lsb = (unsigned char*)&ls[wid][0][0];
    {
        int lrow = l4 << 2;
#pragma unroll
        for (int j = 0; j < 4; j++) {
            int rr = rows0 + lrow + j;
            int r = min(rr, N_NODES - 1);
            float sc = scale[r];
            float v[8];
            float mx = 0.0f;
#pragma unroll
            for (int ct = 0; ct < 8; ct++) {
                v[ct] = fmaxf(acc[ct][j], 0.0f) * sc;
                mx = fmaxf(mx, v[ct]);
            }
#pragma unroll
            for (int off = 1; off < 16; off <<= 1) mx = fmaxf(mx, __shfl_xor(mx, off));
            float qm = (mx > 0.0f) ? (240.0f / mx) : 0.0f;
            if (l15 == 0 && rr < N_NODES) mscale[rr] = mx * (1.0f / 240.0f);
#pragma unroll
            for (int ct = 0; ct < 8; ct++)
                lsb[(lrow + j) * 136 + ct * 16 + l15] = fp8enc(v[ct] * qm);
        }
    }
    __syncthreads();
#pragma unroll
    for (int p = 0; p < 4; p++) {
        int row = p * 4 + l4;
        unsigned long long v8;
        __builtin_memcpy(&v8, &lsb[row * 136 + l15 * 8], 8);
        int r = rows0 + row;
        if (r < N_NODES) *(unsigned long long*)(yb8 + (size_t)r * 128 + l15 * 8) = v8;
    }
}

// ------- gather v4: packed fp8 decode (cvt_pk + pk_fma), chunk-prefetched scales -------
__global__ void __launch_bounds__(256) gather_ln_kernel(const int* __restrict__ rowptr,
                                                        const int* __restrict__ csr,
                                                        const unsigned int* __restrict__ mb32,
                                                        const float* __restrict__ mscale,
                                                        const float* __restrict__ invr,
                                                        unsigned int* __restrict__ hb2,
                                                        const float* __restrict__ lnsc,
                                                        const float* __restrict__ lnbi) {
    int node = (blockIdx.x * 256 + threadIdx.x) >> 6;
    int lane = threadIdx.x & 63;
    if (node >= N_NODES) return;
    int half = lane >> 5;  // 0/1: which edge of each pair
    int c = lane & 31;     // u32 column: feature cols 4c..4c+3

    int beg = rowptr[node];
    int end = rowptr[node + 1];

    f32x2 a01 = {0.0f, 0.0f};
    f32x2 a23 = {0.0f, 0.0f};
    if (half == 0) {  // self edge (m already *inv_s)
        unsigned int v = mb32[(size_t)node * 32 + c];
        float k = mscale[node];
        f32x2 k2 = {k, k};
        a01 = fp8pk<false>(v) * k2;
        a23 = fp8pk<true>(v) * k2;
    }

    for (int base = beg; base < end; base += 64) {
        int cnt = min(64, end - base);
        int idx = 0;
        float kk = 0.0f;
        if (lane < cnt) {
            idx = __builtin_nontemporal_load(csr + base + lane);
            kk = mscale[idx];  // 1 VMEM per chunk, broadcast below via shfl
        }
        int nfull = cnt >> 1;
        int i = 0;
        for (; i + 3 < nfull; i += 4) {
            int j0 = 2 * i + half;
            int s0 = __shfl(idx, j0);
            int s1 = __shfl(idx, j0 + 2);
            int s2 = __shfl(idx, j0 + 4);
            int s3 = __shfl(idx, j0 + 6);
            float k0 = __shfl(kk, j0);
            float k1 = __shfl(kk, j0 + 2);
            float k2 = __shfl(kk, j0 + 4);
            float k3 = __shfl(kk, j0 + 6);
            unsigned int v0 = mb32[(size_t)s0 * 32 + c];
            unsigned int v1 = mb32[(size_t)s1 * 32 + c];
            unsigned int v2 = mb32[(size_t)s2 * 32 + c];
            unsigned int v3 = mb32[(size_t)s3 * 32 + c];
            f32x2 kk0 = {k0, k0};
            f32x2 kk1 = {k1, k1};
            f32x2 kk2 = {k2, k2};
            f32x2 kk3 = {k3, k3};
            a01 = fp8pk<false>(v0) * kk0 + a01;
            a23 = fp8pk<true>(v0) * kk0 + a23;
            a01 = fp8pk<false>(v1) * kk1 + a01;
            a23 = fp8pk<true>(v1) * kk1 + a23;
            a01 = fp8pk<false>(v2) * kk2 + a01;
            a23 = fp8pk<true>(v2) * kk2 + a23;
            a01 = fp8pk<false>(v3) * kk3 + a01;
            a23 = fp8pk<true>(v3) * kk3 + a23;
        }
        for (; i < nfull; ++i) {
            int j0 = 2 * i + half;
            int s0 = __shfl(idx, j0);
            float k0 = __shfl(kk, j0);
            unsigned int v0 = mb32[(size_t)s0 * 32 + c];
            f32x2 kk0 = {k0, k0};
            a01 = fp8pk<false>(v0) * kk0 + a01;
            a23 = fp8pk<true>(v0) * kk0 + a23;
        }
        if ((cnt & 1) && half == 0) {  // odd tail edge -> half 0
            int s0 = __shfl(idx, cnt - 1);
            float k0 = __shfl(kk, cnt - 1);
            unsigned int v0 = mb32[(size_t)s0 * 32 + c];
            f32x2 kk0 = {k0, k0};
            a01 = fp8pk<false>(v0) * kk0 + a01;
            a23 = fp8pk<true>(v0) * kk0 + a23;
        }
    }

    // combine halves (lanes differ in bit 5)
    float a0 = a01.x + __shfl_xor(a01.x, 32);
    float a1 = a01.y + __shfl_xor(a01.y, 32);
    float a2 = a23.x + __shfl_xor(a23.x, 32);
    float a3 = a23.y + __shfl_xor(a23.y, 32);

    float ir = invr[node];
    unsigned long long hu =
        *(const unsigned long long*)(hb2 + (size_t)node * 64 + 2 * c);
    unsigned int hlo = (unsigned int)hu;
    unsigned int hhi = (unsigned int)(hu >> 32);
    float t0 = a0 * ir + lof(hlo);
    float t1 = a1 * ir + hif(hlo);
    float t2 = a2 * ir + lof(hhi);
    float t3 = a3 * ir + hif(hhi);

    float s = t0 + t1 + t2 + t3;
    float s2 = t0 * t0 + t1 * t1 + t2 * t2 + t3 * t3;
#pragma unroll
    for (int o = 1; o < 32; o <<= 1) {
        s += __shfl_xor(s, o);
        s2 += __shfl_xor(s2, o);
    }
    float mu = s * (1.0f / 128.0f);
    float var = s2 * (1.0f / 128.0f) - mu * mu;
    float rstd = rsqrtf(var + LN_EPS);

    f32x4 sc = *(const f32x4*)(lnsc + 4 * c);
    f32x4 bi = *(const f32x4*)(lnbi + 4 * c);
    float o0 = (t0 - mu) * rstd * sc.x + bi.x;
    float o1 = (t1 - mu) * rstd * sc.y + bi.y;
    float o2 = (t2 - mu) * rstd * sc.z + bi.z;
    float o3 = (t3 - mu) * rstd * sc.w + bi.w;

    if (half == 0) {
        unsigned int p0 = (unsigned int)f2bfbits(o0) | ((unsigned int)f2bfbits(o1) << 16);
        unsigned int p1 = (unsigned int)f2bfbits(o2) | ((unsigned int)f2bfbits(o3) << 16);
        unsigned long long pk = (unsigned long long)p0 | ((unsigned long long)p1 << 32);
        __builtin_nontemporal_store(pk, (unsigned long long*)(hb2 + (size_t)node * 64 + 2 * c));
    }
}

// ---------------- pooling: run-length over sorted graph_ids (bf16 h) ----------------
__global__ void __launch_bounds__(128) pool_kernel(const unsigned short* __restrict__ hb,
                                                   const int* __restrict__ gid,
                                                   float* __restrict__ gsum,
                                                   float* __restrict__ gcnt) {
    int col = threadIdx.x;
    int n0 = blockIdx.x * 64;
    int nend = min(n0 + 64, N_NODES);
    if (n0 >= N_NODES) return;
    int cur = gid[n0];
    float acc = 0.0f, cacc = 0.0f;
    for (int n = n0; n < nend; ++n) {
        int g = gid[n];
        if (g != cur) {
            atomicAdd(&gsum[cur * LATENT + col], acc);
            if (col == 0) atomicAdd(&gcnt[cur], cacc);
            acc = 0.0f;
            cacc = 0.0f;
            cur = g;
        }
        acc += bf2f(hb[(size_t)n * LATENT + col]);
        cacc += 1.0f;
    }
    atomicAdd(&gsum[cur * LATENT + col], acc);
    if (col == 0) atomicAdd(&gcnt[cur], cacc);
}

// ---------------- decoder (dual-dtype output, inline flag) ----------------
__global__ void __launch_bounds__(640) dec_kernel(const float* __restrict__ gsum,
                                                  const float* __restrict__ gcnt,
                                                  const float* __restrict__ dW,
                                                  const float* __restrict__ db,
                                                  void* __restrict__ out,
                                                  const unsigned short* __restrict__ lns_raw) {
    int t = threadIdx.x;
    if (t >= NGRAPH * OUTG) return;
    int g = t / OUTG, o = t % OUTG;
    float inv = 1.0f / fmaxf(gcnt[g], 1.0f);
    float acc = 0.0f;
    for (int k = 0; k < LATENT; k++) acc += gsum[g * LATENT + k] * dW[k * OUTG + o];
    acc = acc * inv + db[o];
    if (lns_raw[0] == 0) ((float*)out)[t] = acc;
    else ((__hip_bfloat16*)out)[t] = __float2bfloat16(acc);
}

__global__ void diag_kernel(float* out, float val) {
    if (threadIdx.x == 0) out[0] = val;
}

extern "C" void kernel_launch(void* const* d_in, const int* in_sizes, int n_in,
                              void* d_out, int out_size, void* d_ws, size_t ws_size,
                              hipStream_t stream) {
    (void)in_sizes; (void)n_in; (void)out_size;
    const int* snd = (const int*)d_in[1];
    const int* rcv = (const int*)d_in[2];
    const int* gid = (const int*)d_in[3];

    if (ws_size < (size_t)WS_REQ_BYTES) {
        diag_kernel<<<1, 64, 0, stream>>>((float*)d_out, 1.0e6f + (float)(ws_size >> 20));
        return;
    }

    float* ws = (float*)d_ws;
    float* gsum = ws + WS_GSUM;
    float* invs = ws + WS_INVS;
    float* invr = ws + WS_INVR;
    float* mb = ws + WS_MB;
    float* lns = ws + WS_LNS;
    float* lnb = ws + WS_LNB;
    float* dW = ws + WS_DW;
    float* db = ws + WS_DB;
    unsigned short* Wf = (unsigned short*)(ws + WS_WF);
    unsigned int* part = (unsigned int*)(ws + WS_PART);
    unsigned short* hb = (unsigned short*)(ws + WS_HB);
    float* mscale = ws + WS_MSCALE;
    unsigned char* mbuf8 = (unsigned char*)(ws + WS_MBUF);
    int* ibase = (int*)(ws + WS_INT);
    int* rowptr = ibase + WI_ROWPTR;
    int* offc = ibase + WI_OFFC;
    int* off = ibase + WI_OFF;
    int* csr = ibase + WI_CSR;
    unsigned short* partS = (unsigned short*)(ibase + WI_PARTS);

    hipMemsetAsync(gsum, 0, (NGRAPH * LATENT + 64) * sizeof(float), stream);

    prologue_kernel<<<PRO_GRID, 256, 0, stream>>>(
        d_in[0], d_in[4], d_in[5], d_in[6], d_in[7], d_in[8], d_in[9], d_in[10], d_in[11],
        hb, Wf, mb, lns, lnb, dW, db);

    histA_kernel<<<NBLK_P, 1024, 0, stream>>>(snd, rcv, offc);
    scan_kernel<<<1, 1024, 0, stream>>>(offc, off, 2 * OFFN);
    partC_kernel<<<NBLK_P, 1024, 0, stream>>>(snd, rcv, off, part, partS);
    buildD_kernel<<<NBUCK, 1024, 0, stream>>>(part, off, rowptr, invr, csr);
    buildS_kernel<<<NBUCK, 1024, 0, stream>>>(partS, off, invs);

    for (int step = 0; step < STEPS; ++step) {
        const unsigned short* Wf0 = Wf + (size_t)(step * 2 + 0) * 16384;
        const unsigned short* Wf1 = Wf + (size_t)(step * 2 + 1) * 16384;
        const float* b0 = mb + (step * 2 + 0) * LATENT;
        const float* b1 = mb + (step * 2 + 1) * LATENT;
        fused_mlp_kernel<<<(N_NODES + 127) / 128, 512, 0, stream>>>(hb, Wf0, b0, Wf1, b1,
                                                                    mbuf8, mscale, invs);
        gather_ln_kernel<<<N_NODES / 4, 256, 0, stream>>>(rowptr, csr, (const unsigned int*)mbuf8,
                                                          mscale, invr, (unsigned int*)hb,
                                                          lns + step * LATENT,
                                                          lnb + step * LATENT);
    }

    pool_kernel<<<(N_NODES + 63) / 64, 128, 0, stream>>>(hb, gid, gsum, ws + WS_GCNT);
    dec_kernel<<<1, 640, 0, stream>>>(gsum, ws + WS_GCNT, dW, db, d_out,
                                      (const unsigned short*)d_in[8]);
}

// Round 16
// 420.968 us; speedup vs baseline: 1.2347x; 1.0040x over previous
//
#include <hip/hip_runtime.h>
#include <hip/hip_bf16.h>

#define N_NODES 100000
#define N_EDGES 1600000
#define NGRAPH 64
#define F_IN 16
#define LATENT 128
#define STEPS 3
#define OUTG 10
#define LN_EPS 1e-6f

// graph-build partition params
#define NBLK_P 256
#define CHUNK (N_EDGES / NBLK_P)  // 6250
#define NBUCK 98                  // ceil(100000/1024)
#define RPB 1024
#define OFFN (NBUCK * NBLK_P)     // 25088

typedef __attribute__((ext_vector_type(8))) short short8;
typedef __attribute__((ext_vector_type(4))) float f32x4;
typedef __attribute__((ext_vector_type(2))) float f32x2;

// ---- ws layout (float indices) ----
#define WS_GSUM 16
#define WS_GCNT (WS_GSUM + NGRAPH * LATENT)
#define WS_INVS (WS_GCNT + 64)
#define WS_INVR (WS_INVS + N_NODES)
#define WS_MB (WS_INVR + N_NODES)
#define WS_LNS (WS_MB + STEPS * 2 * LATENT)
#define WS_LNB (WS_LNS + STEPS * LATENT)
#define WS_DW (WS_LNB + STEPS * LATENT)
#define WS_DB (WS_DW + LATENT * OUTG)
#define WS_WF (WS_DB + 16)                           // 6*16384 bf16 = 49152 floats
#define WS_PART (WS_WF + 49152)                      // u32 x N_EDGES
#define WS_HB (WS_PART + N_EDGES)                    // bf16 h, N*64 floats
#define WS_MSCALE (WS_HB + (size_t)N_NODES * 64)     // N floats
#define WS_MBUF (WS_MSCALE + N_NODES)                // fp8 m, N*128 bytes = N*32 floats
#define WS_INT (WS_MBUF + (size_t)N_NODES * 32)
// ints (offsets within int region)
#define WI_ROWPTR 0
#define WI_OFFC (WI_ROWPTR + 100016)   // 2*OFFN = 50176 counts (rcv plane | snd plane)
#define WI_OFF (WI_OFFC + 50208)       // 2*OFFN+1 offsets
#define WI_CSR 400064
#define WI_PARTS (WI_CSR + N_EDGES)    // u16 x N_EDGES = 800000 ints
#define WI_END (WI_PARTS + 800000)
#define WS_REQ_BYTES (((size_t)WS_INT + WI_END) * 4)

// prologue block ranges
#define PRO_EMBED 6250
#define PRO_WF (PRO_EMBED + 48)
#define PRO_CVT_N 2826
#define PRO_CVT_END (PRO_WF + 12)
#define PRO_GRID (PRO_CVT_END + NBLK_P)  // + histA blocks

__device__ __forceinline__ float bf2f(unsigned short u) {
    unsigned int i = ((unsigned int)u) << 16;
    float f;
    __builtin_memcpy(&f, &i, 4);
    return f;
}
__device__ __forceinline__ unsigned short f2bfbits(float f) {
    __hip_bfloat16 b = __float2bfloat16(f);
    unsigned short u;
    __builtin_memcpy(&u, &b, 2);
    return u;
}
__device__ __forceinline__ float lof(unsigned int u) {
    unsigned int v = u << 16;
    float f;
    __builtin_memcpy(&f, &v, 4);
    return f;
}
__device__ __forceinline__ float hif(unsigned int u) {
    unsigned int v = u & 0xffff0000u;
    float f;
    __builtin_memcpy(&f, &v, 4);
    return f;
}
__device__ __forceinline__ float rawf(const void* p, size_t i, bool f32m) {
    return f32m ? ((const float*)p)[i] : bf2f(((const unsigned short*)p)[i]);
}

// ---- fp8 e4m3 (OCP) encode/decode, non-negative values only ----
template <int SEL>
__device__ __forceinline__ float fp8dec(unsigned int u) {
    unsigned int b = (u >> (SEL * 8)) & 0xff;
    if (b >= 8) {
        unsigned int fb = (b + 960u) << 20;
        float f;
        __builtin_memcpy(&f, &fb, 4);
        return f;
    }
    return (float)b * (1.0f / 512.0f);
}
template <bool WORD>
__device__ __forceinline__ f32x2 fp8pk(unsigned int u) {
#if __has_builtin(__builtin_amdgcn_cvt_pk_f32_fp8)
    return __builtin_amdgcn_cvt_pk_f32_fp8(u, WORD);
#else
    f32x2 r;
    if (WORD) {
        r.x = fp8dec<2>(u);
        r.y = fp8dec<3>(u);
    } else {
        r.x = fp8dec<0>(u);
        r.y = fp8dec<1>(u);
    }
    return r;
#endif
}
__device__ __forceinline__ unsigned char fp8enc(float v) {  // v in [0, 240]
#if __has_builtin(__builtin_amdgcn_cvt_pk_fp8_f32)
    return (unsigned char)(__builtin_amdgcn_cvt_pk_fp8_f32(v, 0.0f, 0u, false) & 0xff);
#else
    if (v < 0.015625f) return (unsigned char)__float2int_rn(v * 512.0f);
    unsigned int u;
    __builtin_memcpy(&u, &v, 4);
    u += 0x7FFFFu + ((u >> 20) & 1u);
    return (unsigned char)((u >> 20) - 960u);
#endif
}

// ------- prologue: embed | wfgen | cvt small | histA (dual LDS histograms) -------
__global__ void __launch_bounds__(256) prologue_kernel(
    const void* __restrict__ nodes_raw, const void* __restrict__ eW_raw,
    const void* __restrict__ eb_raw, const void* __restrict__ mW_raw,
    const void* __restrict__ mb_raw, const void* __restrict__ lns_raw,
    const void* __restrict__ lnb_raw, const void* __restrict__ dW_raw,
    const void* __restrict__ db_raw, const int* __restrict__ snd,
    const int* __restrict__ rcv,
    unsigned short* __restrict__ hb, unsigned short* __restrict__ Wf,
    float* __restrict__ mb, float* __restrict__ lns, float* __restrict__ lnb,
    float* __restrict__ dW, float* __restrict__ db, int* __restrict__ offc) {
    __shared__ float xs[16][F_IN];
    __shared__ int lh[NBUCK];
    __shared__ int lhS[NBUCK];
    bool f32m = (((const unsigned short*)lns_raw)[0] == 0);
    int bid = blockIdx.x;
    int t = threadIdx.x;
    if (bid < PRO_EMBED) {
        int row0 = bid * 16;
        {
            int r = t >> 4, c = t & 15;
            xs[r][c] = rawf(nodes_raw, (size_t)(row0 + r) * F_IN + c, f32m);
        }
        __syncthreads();
        int col = t & 127;
        int rh = t >> 7;
        float acc[8];
        float bb = rawf(eb_raw, col, f32m);
#pragma unroll
        for (int j = 0; j < 8; j++) acc[j] = bb;
#pragma unroll
        for (int k = 0; k < F_IN; k++) {
            float w = rawf(eW_raw, k * LATENT + col, f32m);
#pragma unroll
            for (int j = 0; j < 8; j++) acc[j] += xs[rh * 8 + j][k] * w;
        }
        int rbase = row0 + rh * 8;
#pragma unroll
        for (int j = 0; j < 8; j++)
            hb[(size_t)(rbase + j) * LATENT + col] = f2bfbits(acc[j]);
    } else if (bid < PRO_WF) {
        int tid = (bid - PRO_EMBED) * 256 + t;
        int L = tid >> 11;
        int rem = tid & 2047;
        int ct = rem >> 8;
        int kt = (rem >> 6) & 3;
        int lane = rem & 63;
        size_t Wsoff = (size_t)L * 16384;
        int col = ct * 16 + (lane & 15);
        int k0 = kt * 32 + ((lane >> 4) << 3);
        short8 v;
#pragma unroll
        for (int i = 0; i < 8; i++)
            v[i] = (short)f2bfbits(rawf(mW_raw, Wsoff + (size_t)(k0 + i) * 128 + col, f32m));
        *(short8*)(Wf + (size_t)tid * 8) = v;
    } else if (bid < PRO_CVT_END) {
        int i = (bid - PRO_WF) * 256 + t;
        if (i >= PRO_CVT_N) return;
        const void* src;
        float* dst;
        int j;
        if (i < 768) { src = mb_raw; dst = mb; j = i; }
        else if (i < 1152) { src = lns_raw; dst = lns; j = i - 768; }
        else if (i < 1536) { src = lnb_raw; dst = lnb; j = i - 1152; }
        else if (i < 2816) { src = dW_raw; dst = dW; j = i - 1536; }
        else { src = db_raw; dst = db; j = i - 2816; }
        dst[j] = rawf(src, j, f32m);
    } else {
        // ---- histA: dual bucket histograms, one CHUNK per block ----
        int hb_id = bid - PRO_CVT_END;
        for (int i = t; i < NBUCK; i += 256) {
            lh[i] = 0;
            lhS[i] = 0;
        }
        __syncthreads();
        int base = hb_id * CHUNK;
        for (int i = t; i < CHUNK; i += 256) {
            int e = base + i;
            atomicAdd(&lhS[snd[e] >> 10], 1);
            atomicAdd(&lh[rcv[e] >> 10], 1);
        }
        __syncthreads();
        for (int i = t; i < NBUCK; i += 256) {
            offc[i * NBLK_P + hb_id] = lh[i];
            offc[OFFN + i * NBLK_P + hb_id] = lhS[i];
        }
    }
}

// ---------------- exclusive scan over both planes (n = 2*OFFN) ----------------
__global__ void __launch_bounds__(1024) scan_kernel(const int* __restrict__ src,
                                                    int* __restrict__ dst, int n) {
    __shared__ int wsum[16];
    __shared__ int chunk_total;
    int tid = threadIdx.x;
    int lane = tid & 63, wid = tid >> 6;
    int carry = 0;
    for (int base = 0; base < n; base += 4096) {
        int i0 = base + tid * 4;
        int v0 = (i0 + 0 < n) ? src[i0 + 0] : 0;
        int v1 = (i0 + 1 < n) ? src[i0 + 1] : 0;
        int v2 = (i0 + 2 < n) ? src[i0 + 2] : 0;
        int v3 = (i0 + 3 < n) ? src[i0 + 3] : 0;
        int s = v0 + v1 + v2 + v3;
        int sc = s;
#pragma unroll
        for (int off = 1; off < 64; off <<= 1) {
            int t = __shfl_up(sc, off);
            if (lane >= off) sc += t;
        }
        if (lane == 63) wsum[wid] = sc;
        __syncthreads();
        if (wid == 0) {
            int w = (lane < 16) ? wsum[lane] : 0;
#pragma unroll
            for (int off = 1; off < 16; off <<= 1) {
                int t = __shfl_up(w, off);
                if (lane >= off) w += t;
            }
            if (lane < 16) wsum[lane] = w;
            if (lane == 15) chunk_total = w;
        }
        __syncthreads();
        int waveoff = (wid == 0) ? 0 : wsum[wid - 1];
        int p0 = carry + waveoff + (sc - s);
        int p1 = p0 + v0, p2 = p1 + v1, p3 = p2 + v2;
        if (i0 + 0 < n) dst[i0 + 0] = p0;
        if (i0 + 1 < n) dst[i0 + 1] = p1;
        if (i0 + 2 < n) dst[i0 + 2] = p2;
        if (i0 + 3 < n) dst[i0 + 3] = p3;
        carry += chunk_total;
        __syncthreads();
    }
    if (tid == 0) dst[n] = carry;
}

// ------- phase C: dual partition — rcv-keyed u32 part + snd-keyed u16 partS -------
__global__ void __launch_bounds__(1024) partC_kernel(const int* __restrict__ snd,
                                                     const int* __restrict__ rcv,
                                                     const int* __restrict__ off,
                                                     unsigned int* __restrict__ part,
                                                     unsigned short* __restrict__ partS) {
    __shared__ int lcur[NBUCK];
    __shared__ int lcurS[NBUCK];
    for (int i = threadIdx.x; i < NBUCK; i += 1024) {
        lcur[i] = off[i * NBLK_P + blockIdx.x];
        lcurS[i] = off[OFFN + i * NBLK_P + blockIdx.x] - N_EDGES;
    }
    __syncthreads();
    int base = blockIdx.x * CHUNK;
    for (int i = threadIdx.x; i < CHUNK; i += 1024) {
        int e = base + i;
        int r = rcv[e];
        int s = snd[e];
        int pos = atomicAdd(&lcur[r >> 10], 1);
        part[pos] = ((unsigned int)s << 10) | (unsigned int)(r & 1023);
        int posS = atomicAdd(&lcurS[s >> 10], 1);
        partS[posS] = (unsigned short)(s & 1023);
    }
}

// ------- merged phase D+S: blocks 0..97 build CSR (rcv), 98..195 build invs (snd) -------
__global__ void __launch_bounds__(1024) buildDS_kernel(const unsigned int* __restrict__ part,
                                                       const unsigned short* __restrict__ partS,
                                                       const int* __restrict__ off,
                                                       int* __restrict__ rowptr,
                                                       float* __restrict__ invr,
                                                       float* __restrict__ invs,
                                                       int* __restrict__ csr) {
    __shared__ int lcnt[RPB];
    __shared__ int lscan[RPB];
    __shared__ int ltmp[RPB];
    int tid = threadIdx.x;
    if (blockIdx.x < NBUCK) {
        int b = blockIdx.x;
        int beg = off[b * NBLK_P];
        int end = off[(b + 1) * NBLK_P];
        lcnt[tid] = 0;
        __syncthreads();
        for (int i = beg + tid; i < end; i += 1024) atomicAdd(&lcnt[part[i] & 1023], 1);
        __syncthreads();
        lscan[tid] = lcnt[tid];
        __syncthreads();
        int* sp = lscan;
        int* dp = ltmp;
        for (int st = 1; st < RPB; st <<= 1) {
            dp[tid] = sp[tid] + ((tid >= st) ? sp[tid - st] : 0);
            __syncthreads();
            int* t = sp; sp = dp; dp = t;
        }
        {
            int c = lcnt[tid];
            int cur = beg + sp[tid] - c;
            int gr = b * RPB + tid;
            if (gr < N_NODES) {
                rowptr[gr] = cur;
                invr[gr] = rsqrtf((float)c + 1.0f);
            }
            lcnt[tid] = cur;
        }
        __syncthreads();
        for (int i = beg + tid; i < end; i += 1024) {
            unsigned int e = part[i];
            int pos = atomicAdd(&lcnt[e & 1023], 1);
            csr[pos] = (int)(e >> 10);
        }
        if (b == NBUCK - 1 && tid == 0) rowptr[N_NODES] = N_EDGES;
    } else {
        int b = blockIdx.x - NBUCK;
        int beg = off[OFFN + b * NBLK_P] - N_EDGES;
        int end = off[OFFN + (b + 1) * NBLK_P] - N_EDGES;
        lcnt[tid] = 0;
        __syncthreads();
        for (int i = beg + tid; i < end; i += 1024) atomicAdd(&lcnt[partS[i]], 1);
        __syncthreads();
        int gr = b * RPB + tid;
        if (gr < N_NODES) invs[gr] = rsqrtf((float)lcnt[tid] + 1.0f);
    }
}

// ------- fused 2-layer MLP: 512 thr / 8 waves / 128 rows; fp8 output + per-row scale -------
#define LPAD 136
__global__ void __launch_bounds__(512) fused_mlp_kernel(const unsigned short* __restrict__ xb,
                                                        const unsigned short* __restrict__ Wf0,
                                                        const float* __restrict__ b0,
                                                        const unsigned short* __restrict__ Wf1,
                                                        const float* __restrict__ b1,
                                                        unsigned char* __restrict__ yb8,
                                                        float* __restrict__ mscale,
                                                        const float* __restrict__ scale) {
    __shared__ unsigned short ls[8][16][LPAD];
    int lane = threadIdx.x & 63;
    int wid = threadIdx.x >> 6;
    int rows0 = blockIdx.x * 128 + wid * 16;
    int l15 = lane & 15;
    int l4 = lane >> 4;

    f32x4 acc[8];
#pragma unroll
    for (int ct = 0; ct < 8; ct++) {
        float bb = b0[ct * 16 + l15];
        acc[ct] = (f32x4){bb, bb, bb, bb};
    }
    {
        int arow_c = min(rows0 + l15, N_NODES - 1);
        const short8* xrow = (const short8*)(xb + (size_t)arow_c * LATENT);
#pragma unroll
        for (int kt = 0; kt < 4; kt++) {
            short8 a = xrow[kt * 4 + l4];
#pragma unroll
            for (int ct = 0; ct < 8; ct++) {
                short8 bf = *(const short8*)(Wf0 + (size_t)(((ct * 4 + kt) * 64 + lane)) * 8);
                acc[ct] = __builtin_amdgcn_mfma_f32_16x16x32_bf16(a, bf, acc[ct], 0, 0, 0);
            }
        }
    }
    {
        int lrow = l4 << 2;
#pragma unroll
        for (int ct = 0; ct < 8; ct++)
#pragma unroll
            for (int j = 0; j < 4; j++)
                ls[wid][lrow + j][ct * 16 + l15] = f2bfbits(fmaxf(acc[ct][j], 0.0f));
    }
    __syncthreads();

#pragma unroll
    for (int ct = 0; ct < 8; ct++) {
        float bb = b1[ct * 16 + l15];
        acc[ct] = (f32x4){bb, bb, bb, bb};
    }
#pragma unroll
    for (int kt = 0; kt < 4; kt++) {
        short8 a = *(const short8*)&ls[wid][l15][kt * 32 + (l4 << 3)];
#pragma unroll
        for (int ct = 0; ct < 8; ct++) {
            short8 bf = *(const short8*)(Wf1 + (size_t)(((ct * 4 + kt) * 64 + lane)) * 8);
            acc[ct] = __builtin_amdgcn_mfma_f32_16x16x32_bf16(a, bf, acc[ct], 0, 0, 0);
        }
    }
    __syncthreads();
    unsigned char* lsb = (unsigned char*)&ls[wid][0][0];
    {
        int lrow = l4 << 2;
#pragma unroll
        for (int j = 0; j < 4; j++) {
            int rr = rows0 + lrow + j;
            int r = min(rr, N_NODES - 1);
            float sc = scale[r];
            float v[8];
            float mx = 0.0f;
#pragma unroll
            for (int ct = 0; ct < 8; ct++) {
                v[ct] = fmaxf(acc[ct][j], 0.0f) * sc;
                mx = fmaxf(mx, v[ct]);
            }
#pragma unroll
            for (int off = 1; off < 16; off <<= 1) mx = fmaxf(mx, __shfl_xor(mx, off));
            float qm = (mx > 0.0f) ? (240.0f / mx) : 0.0f;
            if (l15 == 0 && rr < N_NODES) mscale[rr] = mx * (1.0f / 240.0f);
#pragma unroll
            for (int ct = 0; ct < 8; ct++)
                lsb[(lrow + j) * 136 + ct * 16 + l15] = fp8enc(v[ct] * qm);
        }
    }
    __syncthreads();
#pragma unroll
    for (int p = 0; p < 4; p++) {
        int row = p * 4 + l4;
        unsigned long long v8;
        __builtin_memcpy(&v8, &lsb[row * 136 + l15 * 8], 8);
        int r = rows0 + row;
        if (r < N_NODES) *(unsigned long long*)(yb8 + (size_t)r * 128 + l15 * 8) = v8;
    }
}

// ------- gather v4 (known-good): packed fp8 decode, chunk-prefetched scales -------
__global__ void __launch_bounds__(256) gather_ln_kernel(const int* __restrict__ rowptr,
                                                        const int* __restrict__ csr,
                                                        const unsigned int* __restrict__ mb32,
                                                        const float* __restrict__ mscale,
                                                        const float* __restrict__ invr,
                                                        unsigned int* __restrict__ hb2,
                                                        const float* __restrict__ lnsc,
                                                        const float* __restrict__ lnbi) {
    int node = (blockIdx.x * 256 + threadIdx.x) >> 6;
    int lane = threadIdx.x & 63;
    if (node >= N_NODES) return;
    int half = lane >> 5;  // 0/1: which edge of each pair
    int c = lane & 31;     // u32 column: feature cols 4c..4c+3

    int beg = rowptr[node];
    int end = rowptr[node + 1];

    f32x2 a01 = {0.0f, 0.0f};
    f32x2 a23 = {0.0f, 0.0f};
    if (half == 0) {  // self edge (m already *inv_s)
        unsigned int v = mb32[(size_t)node * 32 + c];
        float k = mscale[node];
        f32x2 k2 = {k, k};
        a01 = fp8pk<false>(v) * k2;
        a23 = fp8pk<true>(v) * k2;
    }

    for (int base = beg; base < end; base += 64) {
        int cnt = min(64, end - base);
        int idx = 0;
        float kk = 0.0f;
        if (lane < cnt) {
            idx = __builtin_nontemporal_load(csr + base + lane);
            kk = mscale[idx];  // 1 VMEM per chunk, broadcast below via shfl
        }
        int nfull = cnt >> 1;
        int i = 0;
        for (; i + 3 < nfull; i += 4) {
            int j0 = 2 * i + half;
            int s0 = __shfl(idx, j0);
            int s1 = __shfl(idx, j0 + 2);
            int s2 = __shfl(idx, j0 + 4);
            int s3 = __shfl(idx, j0 + 6);
            float k0 = __shfl(kk, j0);
            float k1 = __shfl(kk, j0 + 2);
            float k2 = __shfl(kk, j0 + 4);
            float k3 = __shfl(kk, j0 + 6);
            unsigned int v0 = mb32[(size_t)s0 * 32 + c];
            unsigned int v1 = mb32[(size_t)s1 * 32 + c];
            unsigned int v2 = mb32[(size_t)s2 * 32 + c];
            unsigned int v3 = mb32[(size_t)s3 * 32 + c];
            f32x2 kk0 = {k0, k0};
            f32x2 kk1 = {k1, k1};
            f32x2 kk2 = {k2, k2};
            f32x2 kk3 = {k3, k3};
            a01 = fp8pk<false>(v0) * kk0 + a01;
            a23 = fp8pk<true>(v0) * kk0 + a23;
            a01 = fp8pk<false>(v1) * kk1 + a01;
            a23 = fp8pk<true>(v1) * kk1 + a23;
            a01 = fp8pk<false>(v2) * kk2 + a01;
            a23 = fp8pk<true>(v2) * kk2 + a23;
            a01 = fp8pk<false>(v3) * kk3 + a01;
            a23 = fp8pk<true>(v3) * kk3 + a23;
        }
        for (; i < nfull; ++i) {
            int j0 = 2 * i + half;
            int s0 = __shfl(idx, j0);
            float k0 = __shfl(kk, j0);
            unsigned int v0 = mb32[(size_t)s0 * 32 + c];
            f32x2 kk0 = {k0, k0};
            a01 = fp8pk<false>(v0) * kk0 + a01;
            a23 = fp8pk<true>(v0) * kk0 + a23;
        }
        if ((cnt & 1) && half == 0) {  // odd tail edge -> half 0
            int s0 = __shfl(idx, cnt - 1);
            float k0 = __shfl(kk, cnt - 1);
            unsigned int v0 = mb32[(size_t)s0 * 32 + c];
            f32x2 kk0 = {k0, k0};
            a01 = fp8pk<false>(v0) * kk0 + a01;
            a23 = fp8pk<true>(v0) * kk0 + a23;
        }
    }

    // combine halves (lanes differ in bit 5)
    float a0 = a01.x + __shfl_xor(a01.x, 32);
    float a1 = a01.y + __shfl_xor(a01.y, 32);
    float a2 = a23.x + __shfl_xor(a23.x, 32);
    float a3 = a23.y + __shfl_xor(a23.y, 32);

    float ir = invr[node];
    unsigned long long hu =
        *(const unsigned long long*)(hb2 + (size_t)node * 64 + 2 * c);
    unsigned int hlo = (unsigned int)hu;
    unsigned int hhi = (unsigned int)(hu >> 32);
    float t0 = a0 * ir + lof(hlo);
    float t1 = a1 * ir + hif(hlo);
    float t2 = a2 * ir + lof(hhi);
    float t3 = a3 * ir + hif(hhi);

    float s = t0 + t1 + t2 + t3;
    float s2 = t0 * t0 + t1 * t1 + t2 * t2 + t3 * t3;
#pragma unroll
    for (int o = 1; o < 32; o <<= 1) {
        s += __shfl_xor(s, o);
        s2 += __shfl_xor(s2, o);
    }
    float mu = s * (1.0f / 128.0f);
    float var = s2 * (1.0f / 128.0f) - mu * mu;
    float rstd = rsqrtf(var + LN_EPS);

    f32x4 sc = *(const f32x4*)(lnsc + 4 * c);
    f32x4 bi = *(const f32x4*)(lnbi + 4 * c);
    float o0 = (t0 - mu) * rstd * sc.x + bi.x;
    float o1 = (t1 - mu) * rstd * sc.y + bi.y;
    float o2 = (t2 - mu) * rstd * sc.z + bi.z;
    float o3 = (t3 - mu) * rstd * sc.w + bi.w;

    if (half == 0) {
        unsigned int p0 = (unsigned int)f2bfbits(o0) | ((unsigned int)f2bfbits(o1) << 16);
        unsigned int p1 = (unsigned int)f2bfbits(o2) | ((unsigned int)f2bfbits(o3) << 16);
        unsigned long long pk = (unsigned long long)p0 | ((unsigned long long)p1 << 32);
        __builtin_nontemporal_store(pk, (unsigned long long*)(hb2 + (size_t)node * 64 + 2 * c));
    }
}

// ---------------- pooling: run-length over sorted graph_ids (bf16 h) ----------------
__global__ void __launch_bounds__(128) pool_kernel(const unsigned short* __restrict__ hb,
                                                   const int* __restrict__ gid,
                                                   float* __restrict__ gsum,
                                                   float* __restrict__ gcnt) {
    int col = threadIdx.x;
    int n0 = blockIdx.x * 64;
    int nend = min(n0 + 64, N_NODES);
    if (n0 >= N_NODES) return;
    int cur = gid[n0];
    float acc = 0.0f, cacc = 0.0f;
    for (int n = n0; n < nend; ++n) {
        int g = gid[n];
        if (g != cur) {
            atomicAdd(&gsum[cur * LATENT + col], acc);
            if (col == 0) atomicAdd(&gcnt[cur], cacc);
            acc = 0.0f;
            cacc = 0.0f;
            cur = g;
        }
        acc += bf2f(hb[(size_t)n * LATENT + col]);
        cacc += 1.0f;
    }
    atomicAdd(&gsum[cur * LATENT + col], acc);
    if (col == 0) atomicAdd(&gcnt[cur], cacc);
}

// ---------------- decoder (dual-dtype output, inline flag) ----------------
__global__ void __launch_bounds__(640) dec_kernel(const float* __restrict__ gsum,
                                                  const float* __restrict__ gcnt,
                                                  const float* __restrict__ dW,
                                                  const float* __restrict__ db,
                                                  void* __restrict__ out,
                                                  const unsigned short* __restrict__ lns_raw) {
    int t = threadIdx.x;
    if (t >= NGRAPH * OUTG) return;
    int g = t / OUTG, o = t % OUTG;
    float inv = 1.0f / fmaxf(gcnt[g], 1.0f);
    float acc = 0.0f;
    for (int k = 0; k < LATENT; k++) acc += gsum[g * LATENT + k] * dW[k * OUTG + o];
    acc = acc * inv + db[o];
    if (lns_raw[0] == 0) ((float*)out)[t] = acc;
    else ((__hip_bfloat16*)out)[t] = __float2bfloat16(acc);
}

__global__ void diag_kernel(float* out, float val) {
    if (threadIdx.x == 0) out[0] = val;
}

extern "C" void kernel_launch(void* const* d_in, const int* in_sizes, int n_in,
                              void* d_out, int out_size, void* d_ws, size_t ws_size,
                              hipStream_t stream) {
    (void)in_sizes; (void)n_in; (void)out_size;
    const int* snd = (const int*)d_in[1];
    const int* rcv = (const int*)d_in[2];
    const int* gid = (const int*)d_in[3];

    if (ws_size < (size_t)WS_REQ_BYTES) {
        diag_kernel<<<1, 64, 0, stream>>>((float*)d_out, 1.0e6f + (float)(ws_size >> 20));
        return;
    }

    float* ws = (float*)d_ws;
    float* gsum = ws + WS_GSUM;
    float* invs = ws + WS_INVS;
    float* invr = ws + WS_INVR;
    float* mb = ws + WS_MB;
    float* lns = ws + WS_LNS;
    float* lnb = ws + WS_LNB;
    float* dW = ws + WS_DW;
    float* db = ws + WS_DB;
    unsigned short* Wf = (unsigned short*)(ws + WS_WF);
    unsigned int* part = (unsigned int*)(ws + WS_PART);
    unsigned short* hb = (unsigned short*)(ws + WS_HB);
    float* mscale = ws + WS_MSCALE;
    unsigned char* mbuf8 = (unsigned char*)(ws + WS_MBUF);
    int* ibase = (int*)(ws + WS_INT);
    int* rowptr = ibase + WI_ROWPTR;
    int* offc = ibase + WI_OFFC;
    int* off = ibase + WI_OFF;
    int* csr = ibase + WI_CSR;
    unsigned short* partS = (unsigned short*)(ibase + WI_PARTS);

    hipMemsetAsync(gsum, 0, (NGRAPH * LATENT + 64) * sizeof(float), stream);

    prologue_kernel<<<PRO_GRID, 256, 0, stream>>>(
        d_in[0], d_in[4], d_in[5], d_in[6], d_in[7], d_in[8], d_in[9], d_in[10], d_in[11],
        snd, rcv, hb, Wf, mb, lns, lnb, dW, db, offc);

    scan_kernel<<<1, 1024, 0, stream>>>(offc, off, 2 * OFFN);
    partC_kernel<<<NBLK_P, 1024, 0, stream>>>(snd, rcv, off, part, partS);
    buildDS_kernel<<<2 * NBUCK, 1024, 0, stream>>>(part, partS, off, rowptr, invr, invs, csr);

    for (int step = 0; step < STEPS; ++step) {
        const unsigned short* Wf0 = Wf + (size_t)(step * 2 + 0) * 16384;
        const unsigned short* Wf1 = Wf + (size_t)(step * 2 + 1) * 16384;
        const float* b0 = mb + (step * 2 + 0) * LATENT;
        const float* b1 = mb + (step * 2 + 1) * LATENT;
        fused_mlp_kernel<<<(N_NODES + 127) / 128, 512, 0, stream>>>(hb, Wf0, b0, Wf1, b1,
                                                                    mbuf8, mscale, invs);
        gather_ln_kernel<<<N_NODES / 4, 256, 0, stream>>>(rowptr, csr, (const unsigned int*)mbuf8,
                                                          mscale, invr, (unsigned int*)hb,
                                                          lns + step * LATENT,
                                                          lnb + step * LATENT);
    }

    pool_kernel<<<(N_NODES + 63) / 64, 128, 0, stream>>>(hb, gid, gsum, ws + WS_GCNT);
    dec_kernel<<<1, 640, 0, stream>>>(gsum, ws + WS_GCNT, dW, db, d_out,
                                      (const unsigned short*)d_in[8]);
}